// Round 2
// baseline (1153.122 us; speedup 1.0000x reference)
//
#include <hip/hip_runtime.h>

// ---------------------------------------------------------------------------
// Workspace layout (fp32 elements):
//   h1   @ 0          : 256*16*16*16*16 = 16777216   (conv1+pool out)
//   c2   @ 16777216   : 256*32*8*8*8    = 4194304    (conv2 raw out)
//   feat @ 20971520   : 256*2048        = 524288
//   An   @ 21495808   : 4*64*64         = 16384
//   t1   @ 21512192   : 256*1024        = 262144     (feat@Wg1, atomics)
//   t2   @ 21774336   : 256*512         = 131072
//   t3   @ 21905408   : 256*256         = 65536
//   g1   @ 21970944   : 256*1024        = 262144
//   g2   @ 22233088   : 256*512         = 131072
//   g3   @ 22364160   : 256*256         = 65536
// ---------------------------------------------------------------------------

// ---------------- K1: conv1 (1->16ch, 3x3x3, pad1) + maxpool3 s2 p1 --------
// grid 2048 = (bn, zg); block 256 = (ch 16, py 16). Each thread computes the
// pooled output row (ch, pz, py, px 0..15) for pz in {2zg, 2zg+1} directly:
// for each of 5 conv z-planes it builds its own 3 conv-y rows from global x
// (L1-hot; 16 ch-threads share the same input rows), x-pools, y-pools, and
// z-maxes into 2x16 register accumulators. No LDS, no barriers.
// Redundancy 1.5x (y) * 1.25x (z) vs unique conv work.
__global__ __launch_bounds__(256) void k_conv1_pool(
    const float* __restrict__ x, const float* __restrict__ wc,
    const float* __restrict__ bc, float* __restrict__ h1)
{
  const int bid = blockIdx.x;
  const int bn = bid >> 3, zg = bid & 7;
  const int t = threadIdx.x;
  const int ch = t & 15, py = t >> 4;
  float w[27];
#pragma unroll
  for (int k = 0; k < 27; ++k) w[k] = wc[ch * 27 + k];
  const float biasv = bc[ch];
  const float* xb = x + (size_t)bn * 32768;
  float acc0[16], acc1[16];
#pragma unroll
  for (int p = 0; p < 16; ++p) { acc0[p] = -1e30f; acc1[p] = -1e30f; }

#pragma unroll 1
  for (int s = 0; s < 5; ++s) {
    const int cz = 4 * zg - 1 + s;
    if (cz < 0) continue;                 // only zg=0,s=0
    float v[16];
#pragma unroll
    for (int p = 0; p < 16; ++p) v[p] = -1e30f;
#pragma unroll 1
    for (int dyy = 0; dyy < 3; ++dyy) {
      const int y = 2 * py - 1 + dyy;     // conv row index
      if ((unsigned)y >= 32u) continue;
      float a[32];
#pragma unroll
      for (int xx = 0; xx < 32; ++xx) a[xx] = 0.f;
#pragma unroll
      for (int dz = 0; dz < 3; ++dz) {
        const int z = cz - 1 + dz;
        if ((unsigned)z >= 32u) continue;
#pragma unroll
        for (int dy = 0; dy < 3; ++dy) {
          const int yy = y - 1 + dy;
          if ((unsigned)yy >= 32u) continue;
          const float* row = xb + (z << 10) + (yy << 5);
          float r[32];
#pragma unroll
          for (int q = 0; q < 8; ++q) {
            const float4 vv = ((const float4*)row)[q];
            r[4*q] = vv.x; r[4*q+1] = vv.y; r[4*q+2] = vv.z; r[4*q+3] = vv.w;
          }
          const int wi = dz * 9 + dy * 3;
          const float w0 = w[wi], w1 = w[wi + 1], w2v = w[wi + 2];
          a[0] += w1 * r[0] + w2v * r[1];
#pragma unroll
          for (int xx = 1; xx < 31; ++xx)
            a[xx] += w0 * r[xx-1] + w1 * r[xx] + w2v * r[xx+1];
          a[31] += w0 * r[30] + w1 * r[31];
        }
      }
      // x-pool (stride2, win3, pad) and merge into v
      v[0] = fmaxf(v[0], fmaxf(a[0], a[1]));
#pragma unroll
      for (int px = 1; px < 16; ++px)
        v[px] = fmaxf(v[px], fmaxf(fmaxf(a[2*px-1], a[2*px]), a[2*px+1]));
    }
    // z-pool: pz0=2zg uses s in {0,1,2}; pz1=2zg+1 uses s in {2,3,4}
    if (s <= 2) {
#pragma unroll
      for (int p = 0; p < 16; ++p) acc0[p] = fmaxf(acc0[p], v[p]);
    }
    if (s >= 2) {
#pragma unroll
      for (int p = 0; p < 16; ++p) acc1[p] = fmaxf(acc1[p], v[p]);
    }
  }
  // bias + relu commute past max; write two pooled rows
  float* o0 = h1 + (((size_t)(bn * 16 + ch) * 16 + 2 * zg) << 8) + (py << 4);
  float* o1 = o0 + 256;
#pragma unroll
  for (int qq = 0; qq < 4; ++qq) {
    float4 u0, u1;
    u0.x = fmaxf(acc0[4*qq+0] + biasv, 0.f);
    u0.y = fmaxf(acc0[4*qq+1] + biasv, 0.f);
    u0.z = fmaxf(acc0[4*qq+2] + biasv, 0.f);
    u0.w = fmaxf(acc0[4*qq+3] + biasv, 0.f);
    u1.x = fmaxf(acc1[4*qq+0] + biasv, 0.f);
    u1.y = fmaxf(acc1[4*qq+1] + biasv, 0.f);
    u1.z = fmaxf(acc1[4*qq+2] + biasv, 0.f);
    u1.w = fmaxf(acc1[4*qq+3] + biasv, 0.f);
    ((float4*)o0)[qq] = u0;
    ((float4*)o1)[qq] = u1;
  }
}

// ---------------- K2: conv2 (16->32ch, 3x3x3, stride2, pad1), raw out ------
// grid 2048 = (bn, oz); block 256 = (ch 32, oy 8); thread: 1 ch x 8 ox.
// Weights read per-ic straight from original [ch][ic][27] layout (L1 broadcast
// across the 8 oy-threads sharing a ch).
__global__ __launch_bounds__(256) void k_conv2(
    const float* __restrict__ h1, const float* __restrict__ w2, float* __restrict__ c2)
{
  const int bid = blockIdx.x;
  const int bn = bid >> 3, oz = bid & 7;
  const int t = threadIdx.x;
  const int ch = t >> 3, oy = t & 7;
  float acc[8];
#pragma unroll
  for (int o = 0; o < 8; ++o) acc[o] = 0.f;
  const float* hb = h1 + ((size_t)bn << 16);
  const float* wcb = w2 + ch * 432;
#pragma unroll 1
  for (int ic = 0; ic < 16; ++ic) {
    float w[27];
#pragma unroll
    for (int k = 0; k < 27; ++k) w[k] = wcb[ic * 27 + k];
    const float* plane = hb + (ic << 12);
#pragma unroll
    for (int dz = 0; dz < 3; ++dz) {
      const int iz = 2 * oz - 1 + dz;
      if ((unsigned)iz >= 16u) continue;
#pragma unroll
      for (int dy = 0; dy < 3; ++dy) {
        const int iy = 2 * oy - 1 + dy;
        if ((unsigned)iy >= 16u) continue;
        const float* row = plane + (iz << 8) + (iy << 4);
        float rr[17];
        rr[0] = 0.f;                       // ix = -1 pad
#pragma unroll
        for (int q = 0; q < 4; ++q) {
          const float4 v = ((const float4*)row)[q];
          rr[4*q+1] = v.x; rr[4*q+2] = v.y; rr[4*q+3] = v.z; rr[4*q+4] = v.w;
        }
#pragma unroll
        for (int dx = 0; dx < 3; ++dx) {
          const float wv = w[dz * 9 + dy * 3 + dx];
#pragma unroll
          for (int o = 0; o < 8; ++o)
            acc[o] += rr[2*o + dx] * wv;   // ix = 2*ox - 1 + dx
        }
      }
    }
  }
  float* dst = c2 + (((size_t)(bn * 32 + ch) * 8 + oz) << 6) + (oy << 3);
  *(float4*)dst       = make_float4(acc[0], acc[1], acc[2], acc[3]);
  *(float4*)(dst + 4) = make_float4(acc[4], acc[5], acc[6], acc[7]);
}

// ---------------- K2b: maxpool3 s2 p1 + bias + relu -> feat ----------------
__global__ void k_pool2(const float* __restrict__ c2, const float* __restrict__ bc2,
                        float* __restrict__ feat)
{
  const int tid = blockIdx.x * 256 + threadIdx.x;  // 524288
  const int bn = tid >> 11, f = tid & 2047;
  const int ch = f >> 6, pz = (f >> 4) & 3, py = (f >> 2) & 3, px = f & 3;
  const float* base = c2 + ((size_t)(bn * 32 + ch) << 9);
  float m = -1e30f;
#pragma unroll
  for (int dz = 0; dz < 3; ++dz) {
    const int oz = 2 * pz - 1 + dz;
    if ((unsigned)oz < 8u) {
#pragma unroll
      for (int dy = 0; dy < 3; ++dy) {
        const int oy = 2 * py - 1 + dy;
        if ((unsigned)oy < 8u) {
#pragma unroll
          for (int dx = 0; dx < 3; ++dx) {
            const int ox = 2 * px - 1 + dx;
            if ((unsigned)ox < 8u) m = fmaxf(m, base[(oz << 6) + (oy << 3) + ox]);
          }
        }
      }
    }
  }
  feat[tid] = fmaxf(m + bc2[ch], 0.f);
}

// ---------------- A_norm = D^-1/2 (A+I) D^-1/2 -----------------------------
__global__ __launch_bounds__(64) void k_gcn_norm(const int* __restrict__ adj, float* __restrict__ An)
{
  const int b = blockIdx.x, i = threadIdx.x;
  __shared__ float dinv[64];
  const int* ab = adj + b * 4096;
  int deg = 1;
  for (int j = 0; j < 64; ++j) deg += (ab[i * 64 + j] != 0) ? 1 : 0;
  dinv[i] = rsqrtf((float)deg);
  __syncthreads();
  const float di = dinv[i];
  for (int j = 0; j < 64; ++j) {
    const float a = (i == j) ? 1.f : ((ab[i * 64 + j] != 0) ? 1.f : 0.f);
    An[b * 4096 + i * 64 + j] = a * di * dinv[j];
  }
}

// ---------------- zero a region -------------------------------------------
__global__ void k_zero(float* __restrict__ p, int n)
{
  const int tid = blockIdx.x * 256 + threadIdx.x;
  if (tid < n) p[tid] = 0.f;
}

// ---------------- fp32 GEMM, 64x64 tile, K-split + atomicAdd ---------------
// grid (N/64, M/64, S); block 256; C must be zeroed.
__global__ __launch_bounds__(256) void k_gemm_ksplit(
    const float* __restrict__ A, const float* __restrict__ B, float* __restrict__ C,
    int M, int N, int K, int klen)
{
  (void)M;
  const int jb = blockIdx.x << 6;
  const int ib = blockIdx.y << 6;
  const int k0 = blockIdx.z * klen;
  __shared__ float As[16 * 64];
  __shared__ float Bs[16 * 64];
  const int t = threadIdx.x;
  const int ti = t & 15, tj = t >> 4;
  const int li = t >> 2, lk = t & 3;
  const int bk = t >> 4, bj = t & 15;
  float acc[4][4];
#pragma unroll
  for (int u = 0; u < 4; ++u)
#pragma unroll
    for (int v = 0; v < 4; ++v) acc[u][v] = 0.f;
#pragma unroll 1
  for (int kt = 0; kt < klen; kt += 16) {
    __syncthreads();
    {
      const float4 av = *(const float4*)&A[(size_t)(ib + li) * K + k0 + kt + 4 * lk];
      As[(4*lk+0)*64 + li] = av.x;
      As[(4*lk+1)*64 + li] = av.y;
      As[(4*lk+2)*64 + li] = av.z;
      As[(4*lk+3)*64 + li] = av.w;
      const float4 bv = *(const float4*)&B[(size_t)(k0 + kt + bk) * N + jb + 4 * bj];
      *(float4*)&Bs[bk * 64 + 4 * bj] = bv;
    }
    __syncthreads();
#pragma unroll
    for (int k = 0; k < 16; ++k) {
      const float4 a = *(const float4*)&As[k * 64 + 4 * ti];
      const float4 b = *(const float4*)&Bs[k * 64 + 4 * tj];
      acc[0][0] += a.x*b.x; acc[0][1] += a.x*b.y; acc[0][2] += a.x*b.z; acc[0][3] += a.x*b.w;
      acc[1][0] += a.y*b.x; acc[1][1] += a.y*b.y; acc[1][2] += a.y*b.z; acc[1][3] += a.y*b.w;
      acc[2][0] += a.z*b.x; acc[2][1] += a.z*b.y; acc[2][2] += a.z*b.z; acc[2][3] += a.z*b.w;
      acc[3][0] += a.w*b.x; acc[3][1] += a.w*b.y; acc[3][2] += a.w*b.z; acc[3][3] += a.w*b.w;
    }
  }
#pragma unroll
  for (int u = 0; u < 4; ++u) {
    float* crow = C + (size_t)(ib + 4 * ti + u) * N + jb + 4 * tj;
    atomicAdd(crow + 0, acc[u][0]);
    atomicAdd(crow + 1, acc[u][1]);
    atomicAdd(crow + 2, acc[u][2]);
    atomicAdd(crow + 3, acc[u][3]);
  }
}

// ---------------- G = (An_b @ T_b) + bias (+relu), per graph ---------------
// grid (F/64, 4); block 256.
__global__ __launch_bounds__(256) void k_graph_mm(
    const float* __restrict__ An, const float* __restrict__ T,
    const float* __restrict__ bias, float* __restrict__ G, int F, int relu)
{
  const int b = blockIdx.y;
  const int f0 = blockIdx.x << 6;
  __shared__ float Ans[64 * 65];
  __shared__ float Ts[64 * 64];
  const int t = threadIdx.x;
  for (int idx = t; idx < 4096; idx += 256)
    Ans[(idx >> 6) * 65 + (idx & 63)] = An[b * 4096 + idx];
  for (int idx = t; idx < 1024; idx += 256) {
    const int j = idx >> 4, q = idx & 15;
    *(float4*)&Ts[j * 64 + 4 * q] = *(const float4*)&T[(size_t)(b * 64 + j) * F + f0 + 4 * q];
  }
  __syncthreads();
  const int i = t >> 2, fq = t & 3;
  float acc[16];
#pragma unroll
  for (int u = 0; u < 16; ++u) acc[u] = 0.f;
#pragma unroll 1
  for (int j = 0; j < 64; ++j) {
    const float aij = Ans[i * 65 + j];
    const float* tr = &Ts[j * 64 + fq * 16];
#pragma unroll
    for (int u = 0; u < 16; ++u) acc[u] += aij * tr[u];
  }
  float* gr = G + (size_t)(b * 64 + i) * F + f0 + fq * 16;
  const float* br = bias + f0 + fq * 16;
#pragma unroll
  for (int u = 0; u < 16; ++u) {
    const float v = acc[u] + br[u];
    gr[u] = relu ? fmaxf(v, 0.f) : v;
  }
}

// ---------------- head: chunk-max + fc1 + relu + fc2 + softmax -------------
__global__ __launch_bounds__(256) void k_head(
    const float* __restrict__ g3, const float* __restrict__ w1, const float* __restrict__ b1,
    const float* __restrict__ w2, const float* __restrict__ b2, float* __restrict__ out)
{
  const int b = blockIdx.x, t = threadIdx.x;
  __shared__ float sp[256];
  __shared__ float sh[512];
  __shared__ float sl[4];
  {
    const int n = t >> 2, c = t & 3;
    const float* gr = g3 + (size_t)(b * 64 + n) * 256 + c * 64;
    float m = -1e30f;
    for (int f = 0; f < 64; ++f) m = fmaxf(m, gr[f]);
    sp[t] = m;   // pooled[b, n*4+c]
  }
  __syncthreads();
  for (int jj = t; jj < 512; jj += 256) {
    float s = b1[jj];
    for (int k = 0; k < 256; ++k) s += sp[k] * w1[k * 512 + jj];
    sh[jj] = fmaxf(s, 0.f);
  }
  __syncthreads();
  if (t < 4) {
    float s = b2[t];
    for (int k = 0; k < 512; ++k) s += sh[k] * w2[k * 4 + t];
    sl[t] = s;
  }
  __syncthreads();
  if (t == 0) {
    const float m = fmaxf(fmaxf(sl[0], sl[1]), fmaxf(sl[2], sl[3]));
    const float e0 = expf(sl[0] - m), e1 = expf(sl[1] - m);
    const float e2 = expf(sl[2] - m), e3 = expf(sl[3] - m);
    const float inv = 1.f / (e0 + e1 + e2 + e3);
    out[b * 4 + 0] = e0 * inv;
    out[b * 4 + 1] = e1 * inv;
    out[b * 4 + 2] = e2 * inv;
    out[b * 4 + 3] = e3 * inv;
  }
}

// ---------------------------------------------------------------------------
extern "C" void kernel_launch(void* const* d_in, const int* in_sizes, int n_in,
                              void* d_out, int out_size, void* d_ws, size_t ws_size,
                              hipStream_t stream)
{
  (void)in_sizes; (void)n_in; (void)out_size; (void)ws_size;
  const float* x   = (const float*)d_in[0];
  const int*   adj = (const int*)d_in[1];
  const float* wc1 = (const float*)d_in[3];
  const float* bc1 = (const float*)d_in[4];
  const float* wc2 = (const float*)d_in[5];
  const float* bc2 = (const float*)d_in[6];
  const float* wg1 = (const float*)d_in[7];
  const float* bg1 = (const float*)d_in[8];
  const float* wg2 = (const float*)d_in[9];
  const float* bg2 = (const float*)d_in[10];
  const float* wg3 = (const float*)d_in[11];
  const float* bg3 = (const float*)d_in[12];
  const float* wf1 = (const float*)d_in[13];
  const float* bf1 = (const float*)d_in[14];
  const float* wf2 = (const float*)d_in[15];
  const float* bf2 = (const float*)d_in[16];

  float* ws   = (float*)d_ws;
  float* h1   = ws;
  float* c2   = ws + 16777216;
  float* feat = ws + 20971520;
  float* An   = ws + 21495808;
  float* t1   = ws + 21512192;
  float* t2   = ws + 21774336;
  float* t3   = ws + 21905408;
  float* g1   = ws + 21970944;
  float* g2   = ws + 22233088;
  float* g3   = ws + 22364160;
  float* outp = (float*)d_out;

  hipLaunchKernelGGL(k_zero,        dim3(1792),    dim3(256), 0, stream, t1, 458752); // t1..t3
  hipLaunchKernelGGL(k_conv1_pool,  dim3(2048),    dim3(256), 0, stream, x, wc1, bc1, h1);
  hipLaunchKernelGGL(k_conv2,       dim3(2048),    dim3(256), 0, stream, h1, wc2, c2);
  hipLaunchKernelGGL(k_pool2,       dim3(2048),    dim3(256), 0, stream, c2, bc2, feat);
  hipLaunchKernelGGL(k_gcn_norm,    dim3(4),       dim3(64),  0, stream, adj, An);
  hipLaunchKernelGGL(k_gemm_ksplit, dim3(16,4,4),  dim3(256), 0, stream, feat, wg1, t1, 256, 1024, 2048, 512);
  hipLaunchKernelGGL(k_graph_mm,    dim3(16,4),    dim3(256), 0, stream, An, t1, bg1, g1, 1024, 1);
  hipLaunchKernelGGL(k_gemm_ksplit, dim3(8,4,8),   dim3(256), 0, stream, g1, wg2, t2, 256, 512, 1024, 128);
  hipLaunchKernelGGL(k_graph_mm,    dim3(8,4),     dim3(256), 0, stream, An, t2, bg2, g2, 512, 1);
  hipLaunchKernelGGL(k_gemm_ksplit, dim3(4,4,16),  dim3(256), 0, stream, g2, wg3, t3, 256, 256, 512, 32);
  hipLaunchKernelGGL(k_graph_mm,    dim3(4,4),     dim3(256), 0, stream, An, t3, bg3, g3, 256, 0);
  hipLaunchKernelGGL(k_head,        dim3(4),       dim3(256), 0, stream, g3, wf1, bf1, wf2, bf2, outp);
}

// Round 3
// 708.490 us; speedup vs baseline: 1.6276x; 1.6276x over previous
//
#include <hip/hip_runtime.h>

typedef unsigned short ushort_t;
typedef __attribute__((ext_vector_type(8))) short bf16x8;
typedef __attribute__((ext_vector_type(4))) float f32x4;

static __device__ __forceinline__ unsigned short f2bf(float f) {
  unsigned u = __float_as_uint(f);
  u = (u + 0x7FFFu + ((u >> 16) & 1u)) >> 16;
  return (unsigned short)u;
}

// ---------------------------------------------------------------------------
// Workspace layout (fp32-element offsets; h1 region reused as bf16/ushort):
//   h1   @ 0          : 16777216 ushorts (256*16*16*16*16 bf16)  [uses half the old span]
//   c2   @ 16777216   : 256*32*8*8*8 = 4194304 floats (conv2 raw out)
//   feat @ 20971520   : 256*2048
//   An   @ 21495808   : 4*64*64
//   t1   @ 21512192   : 256*1024  (atomics)
//   t2   @ 21774336   : 256*512
//   t3   @ 21905408   : 256*256
//   g1   @ 21970944   : 256*1024
//   g2   @ 22233088   : 256*512
//   g3   @ 22364160   : 256*256
// ---------------------------------------------------------------------------

// ---------------- K1: conv1 (1->16ch, 3x3x3, pad1) + maxpool3 s2 p1 --------
// grid 2048 = (bn, zg); block 256 = (ch 16, py 16). Unchanged from R2 except
// the pooled output is stored as bf16 (h1 is now ushort).
__global__ __launch_bounds__(256) void k_conv1_pool(
    const float* __restrict__ x, const float* __restrict__ wc,
    const float* __restrict__ bc, ushort_t* __restrict__ h1)
{
  const int bid = blockIdx.x;
  const int bn = bid >> 3, zg = bid & 7;
  const int t = threadIdx.x;
  const int ch = t & 15, py = t >> 4;
  float w[27];
#pragma unroll
  for (int k = 0; k < 27; ++k) w[k] = wc[ch * 27 + k];
  const float biasv = bc[ch];
  const float* xb = x + (size_t)bn * 32768;
  float acc0[16], acc1[16];
#pragma unroll
  for (int p = 0; p < 16; ++p) { acc0[p] = -1e30f; acc1[p] = -1e30f; }

#pragma unroll 1
  for (int s = 0; s < 5; ++s) {
    const int cz = 4 * zg - 1 + s;
    if (cz < 0) continue;
    float v[16];
#pragma unroll
    for (int p = 0; p < 16; ++p) v[p] = -1e30f;
#pragma unroll 1
    for (int dyy = 0; dyy < 3; ++dyy) {
      const int y = 2 * py - 1 + dyy;
      if ((unsigned)y >= 32u) continue;
      float a[32];
#pragma unroll
      for (int xx = 0; xx < 32; ++xx) a[xx] = 0.f;
#pragma unroll
      for (int dz = 0; dz < 3; ++dz) {
        const int z = cz - 1 + dz;
        if ((unsigned)z >= 32u) continue;
#pragma unroll
        for (int dy = 0; dy < 3; ++dy) {
          const int yy = y - 1 + dy;
          if ((unsigned)yy >= 32u) continue;
          const float* row = xb + (z << 10) + (yy << 5);
          float r[32];
#pragma unroll
          for (int q = 0; q < 8; ++q) {
            const float4 vv = ((const float4*)row)[q];
            r[4*q] = vv.x; r[4*q+1] = vv.y; r[4*q+2] = vv.z; r[4*q+3] = vv.w;
          }
          const int wi = dz * 9 + dy * 3;
          const float w0 = w[wi], w1 = w[wi + 1], w2v = w[wi + 2];
          a[0] += w1 * r[0] + w2v * r[1];
#pragma unroll
          for (int xx = 1; xx < 31; ++xx)
            a[xx] += w0 * r[xx-1] + w1 * r[xx] + w2v * r[xx+1];
          a[31] += w0 * r[30] + w1 * r[31];
        }
      }
      v[0] = fmaxf(v[0], fmaxf(a[0], a[1]));
#pragma unroll
      for (int px = 1; px < 16; ++px)
        v[px] = fmaxf(v[px], fmaxf(fmaxf(a[2*px-1], a[2*px]), a[2*px+1]));
    }
    if (s <= 2) {
#pragma unroll
      for (int p = 0; p < 16; ++p) acc0[p] = fmaxf(acc0[p], v[p]);
    }
    if (s >= 2) {
#pragma unroll
      for (int p = 0; p < 16; ++p) acc1[p] = fmaxf(acc1[p], v[p]);
    }
  }
  // bias + relu commute past max; pack 16 bf16 per row, two rows
  ushort_t* o0 = h1 + (((size_t)(bn * 16 + ch) * 16 + 2 * zg) << 8) + (py << 4);
  ushort_t* o1 = o0 + 256;
  unsigned pk0[8], pk1[8];
#pragma unroll
  for (int i = 0; i < 8; ++i) {
    const unsigned a0lo = f2bf(fmaxf(acc0[2*i]   + biasv, 0.f));
    const unsigned a0hi = f2bf(fmaxf(acc0[2*i+1] + biasv, 0.f));
    const unsigned a1lo = f2bf(fmaxf(acc1[2*i]   + biasv, 0.f));
    const unsigned a1hi = f2bf(fmaxf(acc1[2*i+1] + biasv, 0.f));
    pk0[i] = a0lo | (a0hi << 16);
    pk1[i] = a1lo | (a1hi << 16);
  }
  ((uint4*)o0)[0] = make_uint4(pk0[0], pk0[1], pk0[2], pk0[3]);
  ((uint4*)o0)[1] = make_uint4(pk0[4], pk0[5], pk0[6], pk0[7]);
  ((uint4*)o1)[0] = make_uint4(pk1[0], pk1[1], pk1[2], pk1[3]);
  ((uint4*)o1)[1] = make_uint4(pk1[4], pk1[5], pk1[6], pk1[7]);
}

// ---------------- K2: conv2 as bf16 MFMA implicit GEMM ---------------------
// grid 2048 = (bn, oz); block 256 (4 waves). Per oz-plane half (32 positions):
// im2col patches As[32][448+pad] bf16 in LDS, weights Bs[32][448+pad] (B^T),
// B-fragments preloaded to registers, 14 x mfma_f32_16x16x32_bf16 per wave.
// K-order: k = ic*27 + dz*9 + dy*3 + dx, padded 432->448 with zeros.
// LDS row stride 456 (=228 words, mod 32 = 4) -> b128 frag reads are 2-way
// bank-aliased only (free).
__global__ __launch_bounds__(256) void k_conv2(
    const ushort_t* __restrict__ h1, const float* __restrict__ w2,
    float* __restrict__ c2)
{
  __shared__ ushort_t As[32 * 456];
  __shared__ ushort_t Bs[32 * 456];
  const int bn = blockIdx.x >> 3, oz = blockIdx.x & 7;
  const int t = threadIdx.x;
  const ushort_t* hb = h1 + ((size_t)bn << 16);

  // ---- B build (weights -> bf16, B^T layout) + K-pad zeroing ----
  for (int idx = t; idx < 13824; idx += 256) {      // 32*432
    const int n = idx / 432, k = idx - n * 432;
    Bs[n * 456 + k] = f2bf(w2[n * 432 + k]);
  }
  for (int idx = t; idx < 512; idx += 256) {        // k in [432,448) pads
    const int r = idx >> 4, k = 432 + (idx & 15);
    Bs[r * 456 + k] = 0;
    As[r * 456 + k] = 0;                            // persists across halves
  }
  __syncthreads();

  // ---- per-wave B-fragment preload ----
  const int w = t >> 6, l = t & 63;
  const int ntile = w >> 1, mtile = w & 1;
  bf16x8 bfr[14];
  {
    const ushort_t* brow = &Bs[(ntile * 16 + (l & 15)) * 456 + ((l >> 4) << 3)];
#pragma unroll
    for (int kk = 0; kk < 14; ++kk)
      bfr[kk] = *(const bf16x8*)(const void*)&brow[kk * 32];
  }

  const int m = t >> 3;        // 0..31 (position within half-plane)
  const int sub = t & 7;       // ic-pair group
  const int ox = m & 7;

#pragma unroll 1
  for (int h = 0; h < 2; ++h) {
    if (h) __syncthreads();    // previous half's As reads complete
    // ---- im2col build: this thread fills As[m][sub*54 .. sub*54+54) ----
    const int oy = h * 4 + (m >> 3);
    ushort_t tv[54];
    int j = 0;
#pragma unroll
    for (int ic2 = 0; ic2 < 2; ++ic2) {
      const ushort_t* icp = hb + ((sub * 2 + ic2) << 12);
#pragma unroll
      for (int dz = 0; dz < 3; ++dz) {
        const int iz = 2 * oz - 1 + dz;
        const bool zok = (unsigned)iz < 16u;
        const ushort_t* zp = icp + (iz << 8);
#pragma unroll
        for (int dy = 0; dy < 3; ++dy) {
          const int iy = 2 * oy - 1 + dy;
          const bool yok = zok && ((unsigned)iy < 16u);
          const ushort_t* yp = zp + (iy << 4);
#pragma unroll
          for (int dx = 0; dx < 3; ++dx) {
            const int ix = 2 * ox - 1 + dx;
            tv[j++] = (yok && (unsigned)ix < 16u) ? yp[ix] : (ushort_t)0;
          }
        }
      }
    }
    {
      unsigned* Aw = (unsigned*)As;
      const int wbase = m * 228 + sub * 27;
#pragma unroll
      for (int p = 0; p < 27; ++p)
        Aw[wbase + p] = (unsigned)tv[2 * p] | ((unsigned)tv[2 * p + 1] << 16);
    }
    __syncthreads();
    // ---- MFMA: wave w computes D[mtile][ntile], 16x16 out tile ----
    f32x4 acc = {0.f, 0.f, 0.f, 0.f};
    const ushort_t* arow = &As[(mtile * 16 + (l & 15)) * 456 + ((l >> 4) << 3)];
#pragma unroll
    for (int kk = 0; kk < 14; ++kk) {
      const bf16x8 af = *(const bf16x8*)(const void*)&arow[kk * 32];
      acc = __builtin_amdgcn_mfma_f32_16x16x32_bf16(af, bfr[kk], acc, 0, 0, 0);
    }
    // ---- epilogue: D[row=m', col=n], m' = mtile*16 + (lane>>4)*4 + r ----
    const int n = ntile * 16 + (l & 15);
    const int m0 = mtile * 16 + ((l >> 4) << 2);
    float* cb = c2 + (((size_t)(bn * 32 + n) * 8) + oz) * 64;
#pragma unroll
    for (int r = 0; r < 4; ++r) {
      const int mm = m0 + r;
      cb[(h * 4 + (mm >> 3)) * 8 + (mm & 7)] = acc[r];
    }
  }
}

// ---------------- K2b: maxpool3 s2 p1 + bias + relu -> feat ----------------
__global__ void k_pool2(const float* __restrict__ c2, const float* __restrict__ bc2,
                        float* __restrict__ feat)
{
  const int tid = blockIdx.x * 256 + threadIdx.x;  // 524288
  const int bn = tid >> 11, f = tid & 2047;
  const int ch = f >> 6, pz = (f >> 4) & 3, py = (f >> 2) & 3, px = f & 3;
  const float* base = c2 + ((size_t)(bn * 32 + ch) << 9);
  float m = -1e30f;
#pragma unroll
  for (int dz = 0; dz < 3; ++dz) {
    const int oz = 2 * pz - 1 + dz;
    if ((unsigned)oz < 8u) {
#pragma unroll
      for (int dy = 0; dy < 3; ++dy) {
        const int oy = 2 * py - 1 + dy;
        if ((unsigned)oy < 8u) {
#pragma unroll
          for (int dx = 0; dx < 3; ++dx) {
            const int ox = 2 * px - 1 + dx;
            if ((unsigned)ox < 8u) m = fmaxf(m, base[(oz << 6) + (oy << 3) + ox]);
          }
        }
      }
    }
  }
  feat[tid] = fmaxf(m + bc2[ch], 0.f);
}

// ---------------- A_norm = D^-1/2 (A+I) D^-1/2 -----------------------------
__global__ __launch_bounds__(64) void k_gcn_norm(const int* __restrict__ adj, float* __restrict__ An)
{
  const int b = blockIdx.x, i = threadIdx.x;
  __shared__ float dinv[64];
  const int* ab = adj + b * 4096;
  int deg = 1;
  for (int j = 0; j < 64; ++j) deg += (ab[i * 64 + j] != 0) ? 1 : 0;
  dinv[i] = rsqrtf((float)deg);
  __syncthreads();
  const float di = dinv[i];
  for (int j = 0; j < 64; ++j) {
    const float a = (i == j) ? 1.f : ((ab[i * 64 + j] != 0) ? 1.f : 0.f);
    An[b * 4096 + i * 64 + j] = a * di * dinv[j];
  }
}

// ---------------- zero a region -------------------------------------------
__global__ void k_zero(float* __restrict__ p, int n)
{
  const int tid = blockIdx.x * 256 + threadIdx.x;
  if (tid < n) p[tid] = 0.f;
}

// ---------------- fp32 GEMM, 64x64 tile, K-split + atomicAdd ---------------
__global__ __launch_bounds__(256) void k_gemm_ksplit(
    const float* __restrict__ A, const float* __restrict__ B, float* __restrict__ C,
    int M, int N, int K, int klen)
{
  (void)M;
  const int jb = blockIdx.x << 6;
  const int ib = blockIdx.y << 6;
  const int k0 = blockIdx.z * klen;
  __shared__ float As[16 * 64];
  __shared__ float Bs[16 * 64];
  const int t = threadIdx.x;
  const int ti = t & 15, tj = t >> 4;
  const int li = t >> 2, lk = t & 3;
  const int bk = t >> 4, bj = t & 15;
  float acc[4][4];
#pragma unroll
  for (int u = 0; u < 4; ++u)
#pragma unroll
    for (int v = 0; v < 4; ++v) acc[u][v] = 0.f;
#pragma unroll 1
  for (int kt = 0; kt < klen; kt += 16) {
    __syncthreads();
    {
      const float4 av = *(const float4*)&A[(size_t)(ib + li) * K + k0 + kt + 4 * lk];
      As[(4*lk+0)*64 + li] = av.x;
      As[(4*lk+1)*64 + li] = av.y;
      As[(4*lk+2)*64 + li] = av.z;
      As[(4*lk+3)*64 + li] = av.w;
      const float4 bv = *(const float4*)&B[(size_t)(k0 + kt + bk) * N + jb + 4 * bj];
      *(float4*)&Bs[bk * 64 + 4 * bj] = bv;
    }
    __syncthreads();
#pragma unroll
    for (int k = 0; k < 16; ++k) {
      const float4 a = *(const float4*)&As[k * 64 + 4 * ti];
      const float4 b = *(const float4*)&Bs[k * 64 + 4 * tj];
      acc[0][0] += a.x*b.x; acc[0][1] += a.x*b.y; acc[0][2] += a.x*b.z; acc[0][3] += a.x*b.w;
      acc[1][0] += a.y*b.x; acc[1][1] += a.y*b.y; acc[1][2] += a.y*b.z; acc[1][3] += a.y*b.w;
      acc[2][0] += a.z*b.x; acc[2][1] += a.z*b.y; acc[2][2] += a.z*b.z; acc[2][3] += a.z*b.w;
      acc[3][0] += a.w*b.x; acc[3][1] += a.w*b.y; acc[3][2] += a.w*b.z; acc[3][3] += a.w*b.w;
    }
  }
#pragma unroll
  for (int u = 0; u < 4; ++u) {
    float* crow = C + (size_t)(ib + 4 * ti + u) * N + jb + 4 * tj;
    atomicAdd(crow + 0, acc[u][0]);
    atomicAdd(crow + 1, acc[u][1]);
    atomicAdd(crow + 2, acc[u][2]);
    atomicAdd(crow + 3, acc[u][3]);
  }
}

// ---------------- G = (An_b @ T_b) + bias (+relu), per graph ---------------
__global__ __launch_bounds__(256) void k_graph_mm(
    const float* __restrict__ An, const float* __restrict__ T,
    const float* __restrict__ bias, float* __restrict__ G, int F, int relu)
{
  const int b = blockIdx.y;
  const int f0 = blockIdx.x << 6;
  __shared__ float Ans[64 * 65];
  __shared__ float Ts[64 * 64];
  const int t = threadIdx.x;
  for (int idx = t; idx < 4096; idx += 256)
    Ans[(idx >> 6) * 65 + (idx & 63)] = An[b * 4096 + idx];
  for (int idx = t; idx < 1024; idx += 256) {
    const int j = idx >> 4, q = idx & 15;
    *(float4*)&Ts[j * 64 + 4 * q] = *(const float4*)&T[(size_t)(b * 64 + j) * F + f0 + 4 * q];
  }
  __syncthreads();
  const int i = t >> 2, fq = t & 3;
  float acc[16];
#pragma unroll
  for (int u = 0; u < 16; ++u) acc[u] = 0.f;
#pragma unroll 1
  for (int j = 0; j < 64; ++j) {
    const float aij = Ans[i * 65 + j];
    const float* tr = &Ts[j * 64 + fq * 16];
#pragma unroll
    for (int u = 0; u < 16; ++u) acc[u] += aij * tr[u];
  }
  float* gr = G + (size_t)(b * 64 + i) * F + f0 + fq * 16;
  const float* br = bias + f0 + fq * 16;
#pragma unroll
  for (int u = 0; u < 16; ++u) {
    const float v = acc[u] + br[u];
    gr[u] = relu ? fmaxf(v, 0.f) : v;
  }
}

// ---------------- head: chunk-max + fc1 + relu + fc2 + softmax -------------
__global__ __launch_bounds__(256) void k_head(
    const float* __restrict__ g3, const float* __restrict__ w1, const float* __restrict__ b1,
    const float* __restrict__ w2, const float* __restrict__ b2, float* __restrict__ out)
{
  const int b = blockIdx.x, t = threadIdx.x;
  __shared__ float sp[256];
  __shared__ float sh[512];
  __shared__ float sl[4];
  {
    const int n = t >> 2, c = t & 3;
    const float* gr = g3 + (size_t)(b * 64 + n) * 256 + c * 64;
    float m = -1e30f;
    for (int f = 0; f < 64; ++f) m = fmaxf(m, gr[f]);
    sp[t] = m;
  }
  __syncthreads();
  for (int jj = t; jj < 512; jj += 256) {
    float s = b1[jj];
    for (int k = 0; k < 256; ++k) s += sp[k] * w1[k * 512 + jj];
    sh[jj] = fmaxf(s, 0.f);
  }
  __syncthreads();
  if (t < 4) {
    float s = b2[t];
    for (int k = 0; k < 512; ++k) s += sh[k] * w2[k * 4 + t];
    sl[t] = s;
  }
  __syncthreads();
  if (t == 0) {
    const float m = fmaxf(fmaxf(sl[0], sl[1]), fmaxf(sl[2], sl[3]));
    const float e0 = expf(sl[0] - m), e1 = expf(sl[1] - m);
    const float e2 = expf(sl[2] - m), e3 = expf(sl[3] - m);
    const float inv = 1.f / (e0 + e1 + e2 + e3);
    out[b * 4 + 0] = e0 * inv;
    out[b * 4 + 1] = e1 * inv;
    out[b * 4 + 2] = e2 * inv;
    out[b * 4 + 3] = e3 * inv;
  }
}

// ---------------------------------------------------------------------------
extern "C" void kernel_launch(void* const* d_in, const int* in_sizes, int n_in,
                              void* d_out, int out_size, void* d_ws, size_t ws_size,
                              hipStream_t stream)
{
  (void)in_sizes; (void)n_in; (void)out_size; (void)ws_size;
  const float* x   = (const float*)d_in[0];
  const int*   adj = (const int*)d_in[1];
  const float* wc1 = (const float*)d_in[3];
  const float* bc1 = (const float*)d_in[4];
  const float* wc2 = (const float*)d_in[5];
  const float* bc2 = (const float*)d_in[6];
  const float* wg1 = (const float*)d_in[7];
  const float* bg1 = (const float*)d_in[8];
  const float* wg2 = (const float*)d_in[9];
  const float* bg2 = (const float*)d_in[10];
  const float* wg3 = (const float*)d_in[11];
  const float* bg3 = (const float*)d_in[12];
  const float* wf1 = (const float*)d_in[13];
  const float* bf1 = (const float*)d_in[14];
  const float* wf2 = (const float*)d_in[15];
  const float* bf2 = (const float*)d_in[16];

  float* ws   = (float*)d_ws;
  ushort_t* h1 = (ushort_t*)d_ws;
  float* c2   = ws + 16777216;
  float* feat = ws + 20971520;
  float* An   = ws + 21495808;
  float* t1   = ws + 21512192;
  float* t2   = ws + 21774336;
  float* t3   = ws + 21905408;
  float* g1   = ws + 21970944;
  float* g2   = ws + 22233088;
  float* g3   = ws + 22364160;
  float* outp = (float*)d_out;

  hipLaunchKernelGGL(k_zero,        dim3(1792),    dim3(256), 0, stream, t1, 458752); // t1..t3
  hipLaunchKernelGGL(k_conv1_pool,  dim3(2048),    dim3(256), 0, stream, x, wc1, bc1, h1);
  hipLaunchKernelGGL(k_conv2,       dim3(2048),    dim3(256), 0, stream, h1, wc2, c2);
  hipLaunchKernelGGL(k_pool2,       dim3(2048),    dim3(256), 0, stream, c2, bc2, feat);
  hipLaunchKernelGGL(k_gcn_norm,    dim3(4),       dim3(64),  0, stream, adj, An);
  hipLaunchKernelGGL(k_gemm_ksplit, dim3(16,4,4),  dim3(256), 0, stream, feat, wg1, t1, 256, 1024, 2048, 512);
  hipLaunchKernelGGL(k_graph_mm,    dim3(16,4),    dim3(256), 0, stream, An, t1, bg1, g1, 1024, 1);
  hipLaunchKernelGGL(k_gemm_ksplit, dim3(8,4,8),   dim3(256), 0, stream, g1, wg2, t2, 256, 512, 1024, 128);
  hipLaunchKernelGGL(k_graph_mm,    dim3(8,4),     dim3(256), 0, stream, An, t2, bg2, g2, 512, 1);
  hipLaunchKernelGGL(k_gemm_ksplit, dim3(4,4,16),  dim3(256), 0, stream, g2, wg3, t3, 256, 256, 512, 32);
  hipLaunchKernelGGL(k_graph_mm,    dim3(4,4),     dim3(256), 0, stream, An, t3, bg3, g3, 256, 0);
  hipLaunchKernelGGL(k_head,        dim3(4),       dim3(256), 0, stream, g3, wf1, bf1, wf2, bf2, outp);
}

// Round 4
// 430.064 us; speedup vs baseline: 2.6813x; 1.6474x over previous
//
#include <hip/hip_runtime.h>

typedef unsigned short ushort_t;
typedef __attribute__((ext_vector_type(8))) short bf16x8;
typedef __attribute__((ext_vector_type(4))) float f32x4;

static __device__ __forceinline__ unsigned short f2bf(float f) {
  unsigned u = __float_as_uint(f);
  u = (u + 0x7FFFu + ((u >> 16) & 1u)) >> 16;
  return (unsigned short)u;
}

static __device__ __forceinline__ f32x4 max4(f32x4 a, f32x4 b) {
  f32x4 r;
  r[0] = fmaxf(a[0], b[0]); r[1] = fmaxf(a[1], b[1]);
  r[2] = fmaxf(a[2], b[2]); r[3] = fmaxf(a[3], b[3]);
  return r;
}

// ---------------------------------------------------------------------------
// Workspace layout (fp32-element offsets; h1 region is bf16/ushort):
//   h1   @ 0          : 16777216 ushorts (256*16*16*16*16 bf16)
//   c2   @ 16777216   : 256*32*8*8*8 = 4194304 floats
//   feat @ 20971520   : 256*2048
//   An   @ 21495808   : 4*64*64
//   t1   @ 21512192   : 256*1024  (atomics)
//   t2   @ 21774336   : 256*512
//   t3   @ 21905408   : 256*256
//   g1   @ 21970944   : 256*1024
//   g2   @ 22233088   : 256*512
//   g3   @ 22364160   : 256*256
// ---------------------------------------------------------------------------

// ---------------- K1: conv1 + maxpool3 as bf16 MFMA "pooled-direct" --------
// grid 2048 = (bn, zg); block 256 (4 waves, wave w owns py 4w..4w+3).
// LDS: per-cz staging of z-quad (cz-1,cz,cz+1,pad) bf16 per (y,x), split into
// even/odd x-parity copies (19 quads * 8B per row, 34 rows) so all b64 frag
// reads are bank-uniform. Per conv row y and x-pool shift s: 2 chained MFMAs
// (dy0+dy1 in k0-11/k16-27; dy2 in k0-11 of second) give conv at 16 pooled-x
// positions x 16 ch. max over s = x-pool (registers). y-pool via parity accs
// over the wave's 9-row sweep; z-pool via ci-parity accs across 5 cz planes.
// bias+relu after all maxes (monotone), bf16 pack to h1[bn][ch][z][y][x].
__global__ __launch_bounds__(256) void k_conv1_mfma(
    const float* __restrict__ x, const float* __restrict__ wc,
    const float* __restrict__ bc, ushort_t* __restrict__ h1)
{
  __shared__ ushort_t L[2 * 34 * 76];   // 2 parity copies, 34 rows x 19 quads x 4 shorts
  char* Lb = (char*)L;
  const int bn = blockIdx.x >> 3, zg = blockIdx.x & 7;
  const int t = threadIdx.x;
  const int w = t >> 6, l = t & 63;
  const int grp = l >> 4, m = l & 15, ch = l & 15;
  const float NINF = -1e30f;

  // ---- B fragments (weights): B[n=ch][k], lane n=l&15, k=grp*8+j ----
  // k-map MFMA_A: k in [0,12): dy=0, dx=k>>2, dz=k&3 (dz==3 -> pad 0)
  //               k in [16,28): dy=1, dx=(k-16)>>2, dz=(k-16)&3
  // k-map MFMA_B: k in [0,12): dy=2; all else 0.
  union { short s[8]; bf16x8 v; } uA, uB;
#pragma unroll
  for (int j = 0; j < 8; ++j) {
    const int k = grp * 8 + j;
    float wA = 0.f, wB = 0.f;
    if (k < 12) {
      const int dx = k >> 2, dz = k & 3;
      if (dz < 3) { wA = wc[ch*27 + dz*9 + 0 + dx]; wB = wc[ch*27 + dz*9 + 6 + dx]; }
    } else if (k >= 16 && k < 28) {
      const int kk = k - 16, dx = kk >> 2, dz = kk & 3;
      if (dz < 3) wA = wc[ch*27 + dz*9 + 3 + dx];
    }
    uA.s[j] = (short)f2bf(wA);
    uB.s[j] = (short)f2bf(wB);
  }

  // ---- per-lane x-component of frag addresses, per s (quad Q = x+2) ----
  int aX1[3], aX2[3];
#pragma unroll
  for (int s = 0; s < 3; ++s) {
    const int Q1 = 2*m + s + 2*(grp & 1);   // first quad this lane reads
    const int Q2 = Q1 + 1;
    aX1[s] = (Q1 & 1) * 5168 + (Q1 >> 1) * 8;
    aX2[s] = (Q2 & 1) * 5168 + (Q2 >> 1) * 8;
  }
  const int rsel = (grp >> 1) * 152;        // dy row-select for MFMA_A

  f32x4 accZ[4][2];
#pragma unroll
  for (int j = 0; j < 4; ++j)
#pragma unroll
    for (int p = 0; p < 2; ++p) accZ[j][p] = (f32x4){NINF, NINF, NINF, NINF};

  const float* xb = x + (size_t)bn * 32768;

#pragma unroll 1
  for (int ci = 0; ci < 5; ++ci) {
    const int cz = 4*zg - 1 + ci;
    if (cz < 0) continue;                   // block-uniform (zg==0, ci==0)
    // ---- stage z-quad (cz-1, cz, cz+1, 0) for rows y_in -1..32, x_in -2..33
    {
      const int z0 = cz - 1, z2 = cz + 1;
#pragma unroll 1
      for (int u = t; u < 1224; u += 256) { // 34 rows * 36 quads
        const int r = u / 36, Q = u - r * 36;
        const int yi = r - 1, xi = Q - 2;
        float v0 = 0.f, v1 = 0.f, v2 = 0.f;
        if ((unsigned)yi < 32u && (unsigned)xi < 32u) {
          const int o = yi * 32 + xi;
          if (z0 >= 0) v0 = xb[z0 * 1024 + o];
          v1 = xb[cz * 1024 + o];
          if (z2 < 32) v2 = xb[z2 * 1024 + o];
        }
        const unsigned lo = (unsigned)f2bf(v0) | ((unsigned)f2bf(v1) << 16);
        const unsigned hi = (unsigned)f2bf(v2);
        *(unsigned long long*)(Lb + (Q & 1) * 5168 + r * 152 + (Q >> 1) * 8) =
            (unsigned long long)lo | ((unsigned long long)hi << 32);
      }
    }
    __syncthreads();
    // ---- compute: sweep conv rows y = 8w-1 .. 8w+7 ----
    f32x4 accP0 = (f32x4){NINF, NINF, NINF, NINF};   // even-parity py slot
    f32x4 accP1 = (f32x4){NINF, NINF, NINF, NINF};   // odd-parity py slot
#pragma unroll
    for (int yy = 0; yy < 9; ++yy) {
      if (yy == 0 && w == 0) continue;      // y = -1: pool pad, skip (uniform)
      const int y = 8 * w - 1 + yy;
      const int rbA = y * 152 + rsel;       // rows y+dy (dy = grp>>1)
      const int rbB = (y + 2) * 152;        // row y+1 (dy = 2)
      f32x4 Cy;
#pragma unroll
      for (int s = 0; s < 3; ++s) {
        union { unsigned long long u[2]; bf16x8 v; } fA, fB;
        fA.u[0] = *(const unsigned long long*)(Lb + aX1[s] + rbA);
        fA.u[1] = *(const unsigned long long*)(Lb + aX2[s] + rbA);
        fB.u[0] = *(const unsigned long long*)(Lb + aX1[s] + rbB);
        fB.u[1] = *(const unsigned long long*)(Lb + aX2[s] + rbB);
        f32x4 acc = (f32x4){0.f, 0.f, 0.f, 0.f};
        acc = __builtin_amdgcn_mfma_f32_16x16x32_bf16(fA.v, uA.v, acc, 0, 0, 0);
        acc = __builtin_amdgcn_mfma_f32_16x16x32_bf16(fB.v, uB.v, acc, 0, 0, 0);
        if (s == 0) acc[0] = (l < 16) ? NINF : acc[0];  // conv-x=-1 at px0
        Cy = (s == 0) ? acc : max4(Cy, acc);
      }
      // ---- py-parity pooling (indices constant after unroll; 4w parity even)
      if (yy & 1) {
        // y even: single py = 4w + (yy-1)/2
        const int c = (yy - 1) / 2;
        if ((c & 1) == 0) accP0 = max4(accP0, Cy); else accP1 = max4(accP1, Cy);
      } else {
        const int cl = yy / 2 - 1;          // closing py (if >= 0)
        const int chh = yy / 2;             // opening/continuing py (if <= 3)
        if (cl >= 0) {
          if ((cl & 1) == 0) {
            accP0 = max4(accP0, Cy);
            if (ci <= 2) accZ[cl][0] = max4(accZ[cl][0], accP0);
            if (ci >= 2) accZ[cl][1] = max4(accZ[cl][1], accP0);
            accP0 = (f32x4){NINF, NINF, NINF, NINF};
          } else {
            accP1 = max4(accP1, Cy);
            if (ci <= 2) accZ[cl][0] = max4(accZ[cl][0], accP1);
            if (ci >= 2) accZ[cl][1] = max4(accZ[cl][1], accP1);
            accP1 = (f32x4){NINF, NINF, NINF, NINF};
          }
        }
        if (chh <= 3) {
          if ((chh & 1) == 0) accP0 = max4(accP0, Cy); else accP1 = max4(accP1, Cy);
        }
      }
    }
    __syncthreads();                        // L consumed before next stage
  }

  // ---- epilogue: bias + relu + bf16, h1[bn][ch][pz][py][px] ----
  const float biasv = bc[ch];
#pragma unroll
  for (int j = 0; j < 4; ++j) {
    const int py = 4 * w + j;
#pragma unroll
    for (int p = 0; p < 2; ++p) {
      const int pz = 2 * zg + p;
      const f32x4 v = accZ[j][p];
      const unsigned lo = (unsigned)f2bf(fmaxf(v[0] + biasv, 0.f)) |
                          ((unsigned)f2bf(fmaxf(v[1] + biasv, 0.f)) << 16);
      const unsigned hi = (unsigned)f2bf(fmaxf(v[2] + biasv, 0.f)) |
                          ((unsigned)f2bf(fmaxf(v[3] + biasv, 0.f)) << 16);
      ushort_t* dst = h1 + (((size_t)(bn * 16 + ch) * 16 + pz) << 8) + py * 16 + grp * 4;
      *(uint2*)dst = make_uint2(lo, hi);
    }
  }
}

// ---------------- K2: conv2 as bf16 MFMA implicit GEMM (unchanged) ---------
__global__ __launch_bounds__(256) void k_conv2(
    const ushort_t* __restrict__ h1, const float* __restrict__ w2,
    float* __restrict__ c2)
{
  __shared__ ushort_t As[32 * 456];
  __shared__ ushort_t Bs[32 * 456];
  const int bn = blockIdx.x >> 3, oz = blockIdx.x & 7;
  const int t = threadIdx.x;
  const ushort_t* hb = h1 + ((size_t)bn << 16);

  for (int idx = t; idx < 13824; idx += 256) {
    const int n = idx / 432, k = idx - n * 432;
    Bs[n * 456 + k] = f2bf(w2[n * 432 + k]);
  }
  for (int idx = t; idx < 512; idx += 256) {
    const int r = idx >> 4, k = 432 + (idx & 15);
    Bs[r * 456 + k] = 0;
    As[r * 456 + k] = 0;
  }
  __syncthreads();

  const int w = t >> 6, l = t & 63;
  const int ntile = w >> 1, mtile = w & 1;
  bf16x8 bfr[14];
  {
    const ushort_t* brow = &Bs[(ntile * 16 + (l & 15)) * 456 + ((l >> 4) << 3)];
#pragma unroll
    for (int kk = 0; kk < 14; ++kk)
      bfr[kk] = *(const bf16x8*)(const void*)&brow[kk * 32];
  }

  const int m = t >> 3;
  const int sub = t & 7;
  const int ox = m & 7;

#pragma unroll 1
  for (int h = 0; h < 2; ++h) {
    if (h) __syncthreads();
    const int oy = h * 4 + (m >> 3);
    ushort_t tv[54];
    int j = 0;
#pragma unroll
    for (int ic2 = 0; ic2 < 2; ++ic2) {
      const ushort_t* icp = hb + ((sub * 2 + ic2) << 12);
#pragma unroll
      for (int dz = 0; dz < 3; ++dz) {
        const int iz = 2 * oz - 1 + dz;
        const bool zok = (unsigned)iz < 16u;
        const ushort_t* zp = icp + (iz << 8);
#pragma unroll
        for (int dy = 0; dy < 3; ++dy) {
          const int iy = 2 * oy - 1 + dy;
          const bool yok = zok && ((unsigned)iy < 16u);
          const ushort_t* yp = zp + (iy << 4);
#pragma unroll
          for (int dx = 0; dx < 3; ++dx) {
            const int ix = 2 * ox - 1 + dx;
            tv[j++] = (yok && (unsigned)ix < 16u) ? yp[ix] : (ushort_t)0;
          }
        }
      }
    }
    {
      unsigned* Aw = (unsigned*)As;
      const int wbase = m * 228 + sub * 27;
#pragma unroll
      for (int p = 0; p < 27; ++p)
        Aw[wbase + p] = (unsigned)tv[2 * p] | ((unsigned)tv[2 * p + 1] << 16);
    }
    __syncthreads();
    f32x4 acc = {0.f, 0.f, 0.f, 0.f};
    const ushort_t* arow = &As[(mtile * 16 + (l & 15)) * 456 + ((l >> 4) << 3)];
#pragma unroll
    for (int kk = 0; kk < 14; ++kk) {
      const bf16x8 af = *(const bf16x8*)(const void*)&arow[kk * 32];
      acc = __builtin_amdgcn_mfma_f32_16x16x32_bf16(af, bfr[kk], acc, 0, 0, 0);
    }
    const int n = ntile * 16 + (l & 15);
    const int m0 = mtile * 16 + ((l >> 4) << 2);
    float* cb = c2 + (((size_t)(bn * 32 + n) * 8) + oz) * 64;
#pragma unroll
    for (int r = 0; r < 4; ++r) {
      const int mm = m0 + r;
      cb[(h * 4 + (mm >> 3)) * 8 + (mm & 7)] = acc[r];
    }
  }
}

// ---------------- K2b: maxpool3 s2 p1 + bias + relu -> feat ----------------
__global__ void k_pool2(const float* __restrict__ c2, const float* __restrict__ bc2,
                        float* __restrict__ feat)
{
  const int tid = blockIdx.x * 256 + threadIdx.x;  // 524288
  const int bn = tid >> 11, f = tid & 2047;
  const int ch = f >> 6, pz = (f >> 4) & 3, py = (f >> 2) & 3, px = f & 3;
  const float* base = c2 + ((size_t)(bn * 32 + ch) << 9);
  float mx = -1e30f;
#pragma unroll
  for (int dz = 0; dz < 3; ++dz) {
    const int oz = 2 * pz - 1 + dz;
    if ((unsigned)oz < 8u) {
#pragma unroll
      for (int dy = 0; dy < 3; ++dy) {
        const int oy = 2 * py - 1 + dy;
        if ((unsigned)oy < 8u) {
#pragma unroll
          for (int dx = 0; dx < 3; ++dx) {
            const int ox = 2 * px - 1 + dx;
            if ((unsigned)ox < 8u) mx = fmaxf(mx, base[(oz << 6) + (oy << 3) + ox]);
          }
        }
      }
    }
  }
  feat[tid] = fmaxf(mx + bc2[ch], 0.f);
}

// ---------------- A_norm = D^-1/2 (A+I) D^-1/2 -----------------------------
__global__ __launch_bounds__(64) void k_gcn_norm(const int* __restrict__ adj, float* __restrict__ An)
{
  const int b = blockIdx.x, i = threadIdx.x;
  __shared__ float dinv[64];
  const int* ab = adj + b * 4096;
  int deg = 1;
  for (int j = 0; j < 64; ++j) deg += (ab[i * 64 + j] != 0) ? 1 : 0;
  dinv[i] = rsqrtf((float)deg);
  __syncthreads();
  const float di = dinv[i];
  for (int j = 0; j < 64; ++j) {
    const float a = (i == j) ? 1.f : ((ab[i * 64 + j] != 0) ? 1.f : 0.f);
    An[b * 4096 + i * 64 + j] = a * di * dinv[j];
  }
}

// ---------------- zero a region -------------------------------------------
__global__ void k_zero(float* __restrict__ p, int n)
{
  const int tid = blockIdx.x * 256 + threadIdx.x;
  if (tid < n) p[tid] = 0.f;
}

// ---------------- fp32 GEMM, 64x64 tile, K-split + atomicAdd ---------------
__global__ __launch_bounds__(256) void k_gemm_ksplit(
    const float* __restrict__ A, const float* __restrict__ B, float* __restrict__ C,
    int M, int N, int K, int klen)
{
  (void)M;
  const int jb = blockIdx.x << 6;
  const int ib = blockIdx.y << 6;
  const int k0 = blockIdx.z * klen;
  __shared__ float As[16 * 64];
  __shared__ float Bs[16 * 64];
  const int t = threadIdx.x;
  const int ti = t & 15, tj = t >> 4;
  const int li = t >> 2, lk = t & 3;
  const int bk = t >> 4, bj = t & 15;
  float acc[4][4];
#pragma unroll
  for (int u = 0; u < 4; ++u)
#pragma unroll
    for (int v = 0; v < 4; ++v) acc[u][v] = 0.f;
#pragma unroll 1
  for (int kt = 0; kt < klen; kt += 16) {
    __syncthreads();
    {
      const float4 av = *(const float4*)&A[(size_t)(ib + li) * K + k0 + kt + 4 * lk];
      As[(4*lk+0)*64 + li] = av.x;
      As[(4*lk+1)*64 + li] = av.y;
      As[(4*lk+2)*64 + li] = av.z;
      As[(4*lk+3)*64 + li] = av.w;
      const float4 bv = *(const float4*)&B[(size_t)(k0 + kt + bk) * N + jb + 4 * bj];
      *(float4*)&Bs[bk * 64 + 4 * bj] = bv;
    }
    __syncthreads();
#pragma unroll
    for (int k = 0; k < 16; ++k) {
      const float4 a = *(const float4*)&As[k * 64 + 4 * ti];
      const float4 b = *(const float4*)&Bs[k * 64 + 4 * tj];
      acc[0][0] += a.x*b.x; acc[0][1] += a.x*b.y; acc[0][2] += a.x*b.z; acc[0][3] += a.x*b.w;
      acc[1][0] += a.y*b.x; acc[1][1] += a.y*b.y; acc[1][2] += a.y*b.z; acc[1][3] += a.y*b.w;
      acc[2][0] += a.z*b.x; acc[2][1] += a.z*b.y; acc[2][2] += a.z*b.z; acc[2][3] += a.z*b.w;
      acc[3][0] += a.w*b.x; acc[3][1] += a.w*b.y; acc[3][2] += a.w*b.z; acc[3][3] += a.w*b.w;
    }
  }
#pragma unroll
  for (int u = 0; u < 4; ++u) {
    float* crow = C + (size_t)(ib + 4 * ti + u) * N + jb + 4 * tj;
    atomicAdd(crow + 0, acc[u][0]);
    atomicAdd(crow + 1, acc[u][1]);
    atomicAdd(crow + 2, acc[u][2]);
    atomicAdd(crow + 3, acc[u][3]);
  }
}

// ---------------- G = (An_b @ T_b) + bias (+relu), per graph ---------------
__global__ __launch_bounds__(256) void k_graph_mm(
    const float* __restrict__ An, const float* __restrict__ T,
    const float* __restrict__ bias, float* __restrict__ G, int F, int relu)
{
  const int b = blockIdx.y;
  const int f0 = blockIdx.x << 6;
  __shared__ float Ans[64 * 65];
  __shared__ float Ts[64 * 64];
  const int t = threadIdx.x;
  for (int idx = t; idx < 4096; idx += 256)
    Ans[(idx >> 6) * 65 + (idx & 63)] = An[b * 4096 + idx];
  for (int idx = t; idx < 1024; idx += 256) {
    const int j = idx >> 4, q = idx & 15;
    *(float4*)&Ts[j * 64 + 4 * q] = *(const float4*)&T[(size_t)(b * 64 + j) * F + f0 + 4 * q];
  }
  __syncthreads();
  const int i = t >> 2, fq = t & 3;
  float acc[16];
#pragma unroll
  for (int u = 0; u < 16; ++u) acc[u] = 0.f;
#pragma unroll 1
  for (int j = 0; j < 64; ++j) {
    const float aij = Ans[i * 65 + j];
    const float* tr = &Ts[j * 64 + fq * 16];
#pragma unroll
    for (int u = 0; u < 16; ++u) acc[u] += aij * tr[u];
  }
  float* gr = G + (size_t)(b * 64 + i) * F + f0 + fq * 16;
  const float* br = bias + f0 + fq * 16;
#pragma unroll
  for (int u = 0; u < 16; ++u) {
    const float v = acc[u] + br[u];
    gr[u] = relu ? fmaxf(v, 0.f) : v;
  }
}

// ---------------- head: chunk-max + fc1 + relu + fc2 + softmax -------------
__global__ __launch_bounds__(256) void k_head(
    const float* __restrict__ g3, const float* __restrict__ w1, const float* __restrict__ b1,
    const float* __restrict__ w2, const float* __restrict__ b2, float* __restrict__ out)
{
  const int b = blockIdx.x, t = threadIdx.x;
  __shared__ float sp[256];
  __shared__ float sh[512];
  __shared__ float sl[4];
  {
    const int n = t >> 2, c = t & 3;
    const float* gr = g3 + (size_t)(b * 64 + n) * 256 + c * 64;
    float mx = -1e30f;
    for (int f = 0; f < 64; ++f) mx = fmaxf(mx, gr[f]);
    sp[t] = mx;
  }
  __syncthreads();
  for (int jj = t; jj < 512; jj += 256) {
    float s = b1[jj];
    for (int k = 0; k < 256; ++k) s += sp[k] * w1[k * 512 + jj];
    sh[jj] = fmaxf(s, 0.f);
  }
  __syncthreads();
  if (t < 4) {
    float s = b2[t];
    for (int k = 0; k < 512; ++k) s += sh[k] * w2[k * 4 + t];
    sl[t] = s;
  }
  __syncthreads();
  if (t == 0) {
    const float mm = fmaxf(fmaxf(sl[0], sl[1]), fmaxf(sl[2], sl[3]));
    const float e0 = expf(sl[0] - mm), e1 = expf(sl[1] - mm);
    const float e2 = expf(sl[2] - mm), e3 = expf(sl[3] - mm);
    const float inv = 1.f / (e0 + e1 + e2 + e3);
    out[b * 4 + 0] = e0 * inv;
    out[b * 4 + 1] = e1 * inv;
    out[b * 4 + 2] = e2 * inv;
    out[b * 4 + 3] = e3 * inv;
  }
}

// ---------------------------------------------------------------------------
extern "C" void kernel_launch(void* const* d_in, const int* in_sizes, int n_in,
                              void* d_out, int out_size, void* d_ws, size_t ws_size,
                              hipStream_t stream)
{
  (void)in_sizes; (void)n_in; (void)out_size; (void)ws_size;
  const float* x   = (const float*)d_in[0];
  const int*   adj = (const int*)d_in[1];
  const float* wc1 = (const float*)d_in[3];
  const float* bc1 = (const float*)d_in[4];
  const float* wc2 = (const float*)d_in[5];
  const float* bc2 = (const float*)d_in[6];
  const float* wg1 = (const float*)d_in[7];
  const float* bg1 = (const float*)d_in[8];
  const float* wg2 = (const float*)d_in[9];
  const float* bg2 = (const float*)d_in[10];
  const float* wg3 = (const float*)d_in[11];
  const float* bg3 = (const float*)d_in[12];
  const float* wf1 = (const float*)d_in[13];
  const float* bf1 = (const float*)d_in[14];
  const float* wf2 = (const float*)d_in[15];
  const float* bf2 = (const float*)d_in[16];

  float* ws   = (float*)d_ws;
  ushort_t* h1 = (ushort_t*)d_ws;
  float* c2   = ws + 16777216;
  float* feat = ws + 20971520;
  float* An   = ws + 21495808;
  float* t1   = ws + 21512192;
  float* t2   = ws + 21774336;
  float* t3   = ws + 21905408;
  float* g1   = ws + 21970944;
  float* g2   = ws + 22233088;
  float* g3   = ws + 22364160;
  float* outp = (float*)d_out;

  hipLaunchKernelGGL(k_zero,        dim3(1792),    dim3(256), 0, stream, t1, 458752); // t1..t3
  hipLaunchKernelGGL(k_conv1_mfma,  dim3(2048),    dim3(256), 0, stream, x, wc1, bc1, h1);
  hipLaunchKernelGGL(k_conv2,       dim3(2048),    dim3(256), 0, stream, h1, wc2, c2);
  hipLaunchKernelGGL(k_pool2,       dim3(2048),    dim3(256), 0, stream, c2, bc2, feat);
  hipLaunchKernelGGL(k_gcn_norm,    dim3(4),       dim3(64),  0, stream, adj, An);
  hipLaunchKernelGGL(k_gemm_ksplit, dim3(16,4,4),  dim3(256), 0, stream, feat, wg1, t1, 256, 1024, 2048, 512);
  hipLaunchKernelGGL(k_graph_mm,    dim3(16,4),    dim3(256), 0, stream, An, t1, bg1, g1, 1024, 1);
  hipLaunchKernelGGL(k_gemm_ksplit, dim3(8,4,8),   dim3(256), 0, stream, g1, wg2, t2, 256, 512, 1024, 128);
  hipLaunchKernelGGL(k_graph_mm,    dim3(8,4),     dim3(256), 0, stream, An, t2, bg2, g2, 512, 1);
  hipLaunchKernelGGL(k_gemm_ksplit, dim3(4,4,16),  dim3(256), 0, stream, g2, wg3, t3, 256, 256, 512, 32);
  hipLaunchKernelGGL(k_graph_mm,    dim3(4,4),     dim3(256), 0, stream, An, t3, bg3, g3, 256, 0);
  hipLaunchKernelGGL(k_head,        dim3(4),       dim3(256), 0, stream, g3, wf1, bf1, wf2, bf2, outp);
}

// Round 5
// 361.135 us; speedup vs baseline: 3.1931x; 1.1909x over previous
//
#include <hip/hip_runtime.h>

typedef unsigned short ushort_t;
typedef __attribute__((ext_vector_type(8))) short bf16x8;
typedef __attribute__((ext_vector_type(4))) float f32x4;

static __device__ __forceinline__ unsigned short f2bf(float f) {
  unsigned u = __float_as_uint(f);
  u = (u + 0x7FFFu + ((u >> 16) & 1u)) >> 16;
  return (unsigned short)u;
}

static __device__ __forceinline__ f32x4 max4(f32x4 a, f32x4 b) {
  f32x4 r;
  r[0] = fmaxf(a[0], b[0]); r[1] = fmaxf(a[1], b[1]);
  r[2] = fmaxf(a[2], b[2]); r[3] = fmaxf(a[3], b[3]);
  return r;
}

// ---------------------------------------------------------------------------
// Workspace layout (fp32-element offsets):
//   h1    @ 0          : 16777216 ushorts = 8388608 fp32 span [0, 8388608)
//   -- free half of old h1 span: [8388608, 16777216) --
//   w2f   @ 8388608    : 14336 ushorts (conv2 weight frags)
//   wg1Tb @ 8395776    : 1024x2048 ushorts (1048576 fp32)
//   wg2Tb @ 9444352    : 512x1024 ushorts  (262144 fp32)
//   wg3Tb @ 9706496    : 256x512 ushorts   (65536 fp32)
//   featb @ 9772032    : 256x2048 ushorts  (262144 fp32)
//   g1b   @ 10034176   : 256x1024 ushorts  (131072 fp32)
//   g2b   @ 10165248   : 256x512 ushorts   (65536 fp32)
//   c2    @ 16777216   : 4194304 floats
//   An    @ 21495808   : 4*64*64
//   t1    @ 21512192   : 256*1024 (atomics, zeroed)
//   t2    @ 21774336   : 256*512
//   t3    @ 21905408   : 256*256
//   g3    @ 22364160   : 256*256
// ---------------------------------------------------------------------------

// ---------------- K1: conv1 + maxpool3 as bf16 MFMA "pooled-direct" --------
__global__ __launch_bounds__(256) void k_conv1_mfma(
    const float* __restrict__ x, const float* __restrict__ wc,
    const float* __restrict__ bc, ushort_t* __restrict__ h1)
{
  __shared__ ushort_t L[2 * 34 * 76];
  char* Lb = (char*)L;
  const int bn = blockIdx.x >> 3, zg = blockIdx.x & 7;
  const int t = threadIdx.x;
  const int w = t >> 6, l = t & 63;
  const int grp = l >> 4, m = l & 15, ch = l & 15;
  const float NINF = -1e30f;

  union { short s[8]; bf16x8 v; } uA, uB;
#pragma unroll
  for (int j = 0; j < 8; ++j) {
    const int k = grp * 8 + j;
    float wA = 0.f, wB = 0.f;
    if (k < 12) {
      const int dx = k >> 2, dz = k & 3;
      if (dz < 3) { wA = wc[ch*27 + dz*9 + 0 + dx]; wB = wc[ch*27 + dz*9 + 6 + dx]; }
    } else if (k >= 16 && k < 28) {
      const int kk = k - 16, dx = kk >> 2, dz = kk & 3;
      if (dz < 3) wA = wc[ch*27 + dz*9 + 3 + dx];
    }
    uA.s[j] = (short)f2bf(wA);
    uB.s[j] = (short)f2bf(wB);
  }

  int aX1[3], aX2[3];
#pragma unroll
  for (int s = 0; s < 3; ++s) {
    const int Q1 = 2*m + s + 2*(grp & 1);
    const int Q2 = Q1 + 1;
    aX1[s] = (Q1 & 1) * 5168 + (Q1 >> 1) * 8;
    aX2[s] = (Q2 & 1) * 5168 + (Q2 >> 1) * 8;
  }
  const int rsel = (grp >> 1) * 152;

  f32x4 accZ[4][2];
#pragma unroll
  for (int j = 0; j < 4; ++j)
#pragma unroll
    for (int p = 0; p < 2; ++p) accZ[j][p] = (f32x4){NINF, NINF, NINF, NINF};

  const float* xb = x + (size_t)bn * 32768;

#pragma unroll 1
  for (int ci = 0; ci < 5; ++ci) {
    const int cz = 4*zg - 1 + ci;
    if (cz < 0) continue;
    {
      const int z0 = cz - 1, z2 = cz + 1;
#pragma unroll 1
      for (int u = t; u < 1224; u += 256) {
        const int r = u / 36, Q = u - r * 36;
        const int yi = r - 1, xi = Q - 2;
        float v0 = 0.f, v1 = 0.f, v2 = 0.f;
        if ((unsigned)yi < 32u && (unsigned)xi < 32u) {
          const int o = yi * 32 + xi;
          if (z0 >= 0) v0 = xb[z0 * 1024 + o];
          v1 = xb[cz * 1024 + o];
          if (z2 < 32) v2 = xb[z2 * 1024 + o];
        }
        const unsigned lo = (unsigned)f2bf(v0) | ((unsigned)f2bf(v1) << 16);
        const unsigned hi = (unsigned)f2bf(v2);
        *(unsigned long long*)(Lb + (Q & 1) * 5168 + r * 152 + (Q >> 1) * 8) =
            (unsigned long long)lo | ((unsigned long long)hi << 32);
      }
    }
    __syncthreads();
    f32x4 accP0 = (f32x4){NINF, NINF, NINF, NINF};
    f32x4 accP1 = (f32x4){NINF, NINF, NINF, NINF};
#pragma unroll
    for (int yy = 0; yy < 9; ++yy) {
      if (yy == 0 && w == 0) continue;
      const int y = 8 * w - 1 + yy;
      const int rbA = y * 152 + rsel;
      const int rbB = (y + 2) * 152;
      f32x4 Cy;
#pragma unroll
      for (int s = 0; s < 3; ++s) {
        union { unsigned long long u[2]; bf16x8 v; } fA, fB;
        fA.u[0] = *(const unsigned long long*)(Lb + aX1[s] + rbA);
        fA.u[1] = *(const unsigned long long*)(Lb + aX2[s] + rbA);
        fB.u[0] = *(const unsigned long long*)(Lb + aX1[s] + rbB);
        fB.u[1] = *(const unsigned long long*)(Lb + aX2[s] + rbB);
        f32x4 acc = (f32x4){0.f, 0.f, 0.f, 0.f};
        acc = __builtin_amdgcn_mfma_f32_16x16x32_bf16(fA.v, uA.v, acc, 0, 0, 0);
        acc = __builtin_amdgcn_mfma_f32_16x16x32_bf16(fB.v, uB.v, acc, 0, 0, 0);
        if (s == 0) acc[0] = (l < 16) ? NINF : acc[0];
        Cy = (s == 0) ? acc : max4(Cy, acc);
      }
      if (yy & 1) {
        const int c = (yy - 1) / 2;
        if ((c & 1) == 0) accP0 = max4(accP0, Cy); else accP1 = max4(accP1, Cy);
      } else {
        const int cl = yy / 2 - 1;
        const int chh = yy / 2;
        if (cl >= 0) {
          if ((cl & 1) == 0) {
            accP0 = max4(accP0, Cy);
            if (ci <= 2) accZ[cl][0] = max4(accZ[cl][0], accP0);
            if (ci >= 2) accZ[cl][1] = max4(accZ[cl][1], accP0);
            accP0 = (f32x4){NINF, NINF, NINF, NINF};
          } else {
            accP1 = max4(accP1, Cy);
            if (ci <= 2) accZ[cl][0] = max4(accZ[cl][0], accP1);
            if (ci >= 2) accZ[cl][1] = max4(accZ[cl][1], accP1);
            accP1 = (f32x4){NINF, NINF, NINF, NINF};
          }
        }
        if (chh <= 3) {
          if ((chh & 1) == 0) accP0 = max4(accP0, Cy); else accP1 = max4(accP1, Cy);
        }
      }
    }
    __syncthreads();
  }

  const float biasv = bc[ch];
#pragma unroll
  for (int j = 0; j < 4; ++j) {
    const int py = 4 * w + j;
#pragma unroll
    for (int p = 0; p < 2; ++p) {
      const int pz = 2 * zg + p;
      const f32x4 v = accZ[j][p];
      const unsigned lo = (unsigned)f2bf(fmaxf(v[0] + biasv, 0.f)) |
                          ((unsigned)f2bf(fmaxf(v[1] + biasv, 0.f)) << 16);
      const unsigned hi = (unsigned)f2bf(fmaxf(v[2] + biasv, 0.f)) |
                          ((unsigned)f2bf(fmaxf(v[3] + biasv, 0.f)) << 16);
      ushort_t* dst = h1 + (((size_t)(bn * 16 + ch) * 16 + pz) << 8) + py * 16 + grp * 4;
      *(uint2*)dst = make_uint2(lo, hi);
    }
  }
}

// ---------------- conv2 weight-fragment prep: w2f[((nt*14+kk)*64+l)*8+j] ----
__global__ void k_prep_w2f(const float* __restrict__ w2, ushort_t* __restrict__ w2f)
{
  const int tid = blockIdx.x * 256 + threadIdx.x;   // 14336
  if (tid >= 14336) return;
  const int nt = tid / 7168, rem = tid % 7168;
  const int kk = rem / 512, rem2 = rem % 512;
  const int l = rem2 >> 3, j = rem2 & 7;
  const int n = nt * 16 + (l & 15);
  const int k = (l >> 4) * 8 + kk * 32 + j;
  float v = 0.f;
  if (k < 432) v = w2[n * 432 + k];
  w2f[tid] = f2bf(v);
}

// ---------------- tiled transpose + bf16: out[n][k] = bf(W[k][n]) ----------
// W is K x N fp32; grid (N/32, K/32); block 256.
__global__ __launch_bounds__(256) void k_transpose_bf(
    const float* __restrict__ W, ushort_t* __restrict__ out, int K, int N)
{
  __shared__ float tile[32][33];
  const int t = threadIdx.x;
  const int tx = t & 31, ty = t >> 5;
  const int n0 = blockIdx.x << 5, k0 = blockIdx.y << 5;
#pragma unroll
  for (int i = 0; i < 4; ++i) {
    const int k = k0 + ty + i * 8;
    tile[ty + i * 8][tx] = W[(size_t)k * N + n0 + tx];
  }
  __syncthreads();
#pragma unroll
  for (int i = 0; i < 4; ++i) {
    const int n = n0 + ty + i * 8;
    out[(size_t)n * K + k0 + tx] = f2bf(tile[tx][ty + i * 8]);
  }
}

// ---------------- K2: conv2 as bf16 MFMA implicit GEMM ---------------------
// grid 2048 = (bn, oz); block 256. B-fragments preloaded from w2f (global,
// L2-hot, exact per-lane layout). LDS only holds As (29 KB) -> 5 blocks/CU.
__global__ __launch_bounds__(256) void k_conv2(
    const ushort_t* __restrict__ h1, const ushort_t* __restrict__ w2f,
    float* __restrict__ c2)
{
  __shared__ ushort_t As[32 * 456];
  const int bn = blockIdx.x >> 3, oz = blockIdx.x & 7;
  const int t = threadIdx.x;
  const ushort_t* hb = h1 + ((size_t)bn << 16);

  const int w = t >> 6, l = t & 63;
  const int ntile = w >> 1, mtile = w & 1;
  bf16x8 bfr[14];
#pragma unroll
  for (int kk = 0; kk < 14; ++kk)
    bfr[kk] = *(const bf16x8*)(const void*)&w2f[(((ntile * 14) + kk) * 64 + l) * 8];

  // zero the K-pad [432,448) once
  for (int idx = t; idx < 512; idx += 256) {
    const int r = idx >> 4, k = 432 + (idx & 15);
    As[r * 456 + k] = 0;
  }

  const int m = t >> 3;
  const int sub = t & 7;
  const int ox = m & 7;

#pragma unroll 1
  for (int h = 0; h < 2; ++h) {
    if (h) __syncthreads();
    const int oy = h * 4 + (m >> 3);
    ushort_t tv[54];
    int j = 0;
#pragma unroll
    for (int ic2 = 0; ic2 < 2; ++ic2) {
      const ushort_t* icp = hb + ((sub * 2 + ic2) << 12);
#pragma unroll
      for (int dz = 0; dz < 3; ++dz) {
        const int iz = 2 * oz - 1 + dz;
        const bool zok = (unsigned)iz < 16u;
        const ushort_t* zp = icp + (iz << 8);
#pragma unroll
        for (int dy = 0; dy < 3; ++dy) {
          const int iy = 2 * oy - 1 + dy;
          const bool yok = zok && ((unsigned)iy < 16u);
          const ushort_t* yp = zp + (iy << 4);
#pragma unroll
          for (int dx = 0; dx < 3; ++dx) {
            const int ix = 2 * ox - 1 + dx;
            tv[j++] = (yok && (unsigned)ix < 16u) ? yp[ix] : (ushort_t)0;
          }
        }
      }
    }
    {
      unsigned* Aw = (unsigned*)As;
      const int wbase = m * 228 + sub * 27;
#pragma unroll
      for (int p = 0; p < 27; ++p)
        Aw[wbase + p] = (unsigned)tv[2 * p] | ((unsigned)tv[2 * p + 1] << 16);
    }
    __syncthreads();
    f32x4 acc = {0.f, 0.f, 0.f, 0.f};
    const ushort_t* arow = &As[(mtile * 16 + (l & 15)) * 456 + ((l >> 4) << 3)];
#pragma unroll
    for (int kk = 0; kk < 14; ++kk) {
      const bf16x8 af = *(const bf16x8*)(const void*)&arow[kk * 32];
      acc = __builtin_amdgcn_mfma_f32_16x16x32_bf16(af, bfr[kk], acc, 0, 0, 0);
    }
    const int n = ntile * 16 + (l & 15);
    const int m0 = mtile * 16 + ((l >> 4) << 2);
    float* cb = c2 + (((size_t)(bn * 32 + n) * 8) + oz) * 64;
#pragma unroll
    for (int r = 0; r < 4; ++r) {
      const int mm = m0 + r;
      cb[(h * 4 + (mm >> 3)) * 8 + (mm & 7)] = acc[r];
    }
  }
}

// ---------------- K2b: maxpool3 s2 p1 + bias + relu -> feat (bf16) ---------
__global__ void k_pool2(const float* __restrict__ c2, const float* __restrict__ bc2,
                        ushort_t* __restrict__ featb)
{
  const int tid = blockIdx.x * 256 + threadIdx.x;  // 524288
  const int bn = tid >> 11, f = tid & 2047;
  const int ch = f >> 6, pz = (f >> 4) & 3, py = (f >> 2) & 3, px = f & 3;
  const float* base = c2 + ((size_t)(bn * 32 + ch) << 9);
  float mx = -1e30f;
#pragma unroll
  for (int dz = 0; dz < 3; ++dz) {
    const int oz = 2 * pz - 1 + dz;
    if ((unsigned)oz < 8u) {
#pragma unroll
      for (int dy = 0; dy < 3; ++dy) {
        const int oy = 2 * py - 1 + dy;
        if ((unsigned)oy < 8u) {
#pragma unroll
          for (int dx = 0; dx < 3; ++dx) {
            const int ox = 2 * px - 1 + dx;
            if ((unsigned)ox < 8u) mx = fmaxf(mx, base[(oz << 6) + (oy << 3) + ox]);
          }
        }
      }
    }
  }
  featb[tid] = f2bf(fmaxf(mx + bc2[ch], 0.f));
}

// ---------------- A_norm = D^-1/2 (A+I) D^-1/2 -----------------------------
__global__ __launch_bounds__(64) void k_gcn_norm(const int* __restrict__ adj, float* __restrict__ An)
{
  const int b = blockIdx.x, i = threadIdx.x;
  __shared__ float dinv[64];
  const int* ab = adj + b * 4096;
  int deg = 1;
  for (int j = 0; j < 64; ++j) deg += (ab[i * 64 + j] != 0) ? 1 : 0;
  dinv[i] = rsqrtf((float)deg);
  __syncthreads();
  const float di = dinv[i];
  for (int j = 0; j < 64; ++j) {
    const float a = (i == j) ? 1.f : ((ab[i * 64 + j] != 0) ? 1.f : 0.f);
    An[b * 4096 + i * 64 + j] = a * di * dinv[j];
  }
}

// ---------------- zero a region -------------------------------------------
__global__ void k_zero(float* __restrict__ p, int n)
{
  const int tid = blockIdx.x * 256 + threadIdx.x;
  if (tid < n) p[tid] = 0.f;
}

// ---------------- bf16 MFMA GEMM, 64x64 tile, K-split + fp32 atomics -------
// A: M x K bf16 row-major. BT: N x K bf16 row-major (pre-transposed weights).
// C: M x N fp32, pre-zeroed, atomicAdd. grid (N/64, M/64, K/klen), block 256.
__global__ __launch_bounds__(256) void k_gemm_bf16(
    const ushort_t* __restrict__ A, const ushort_t* __restrict__ BT,
    float* __restrict__ C, int M, int N, int K, int klen)
{
  (void)M;
  __shared__ ushort_t As[64 * 72];
  __shared__ ushort_t Bs[64 * 72];
  const int jb = blockIdx.x << 6, ib = blockIdx.y << 6;
  const int k0 = blockIdx.z * klen;
  const int t = threadIdx.x, w = t >> 6, l = t & 63;
  const int r0 = t >> 3, kc0 = t & 7;
  f32x4 acc[4];
#pragma unroll
  for (int nt = 0; nt < 4; ++nt) acc[nt] = (f32x4){0.f, 0.f, 0.f, 0.f};

#pragma unroll 1
  for (int kt = 0; kt < klen; kt += 64) {
    __syncthreads();
#pragma unroll
    for (int h = 0; h < 2; ++h) {
      const int row = r0 + h * 32;
      const uint4 va = *(const uint4*)&A[(size_t)(ib + row) * K + k0 + kt + kc0 * 8];
      *(uint4*)&As[row * 72 + kc0 * 8] = va;
      const uint4 vb = *(const uint4*)&BT[(size_t)(jb + row) * K + k0 + kt + kc0 * 8];
      *(uint4*)&Bs[row * 72 + kc0 * 8] = vb;
    }
    __syncthreads();
#pragma unroll
    for (int ks = 0; ks < 2; ++ks) {
      const bf16x8 af = *(const bf16x8*)(const void*)
          &As[(16 * w + (l & 15)) * 72 + ks * 32 + ((l >> 4) << 3)];
#pragma unroll
      for (int nt = 0; nt < 4; ++nt) {
        const bf16x8 bf = *(const bf16x8*)(const void*)
            &Bs[(nt * 16 + (l & 15)) * 72 + ks * 32 + ((l >> 4) << 3)];
        acc[nt] = __builtin_amdgcn_mfma_f32_16x16x32_bf16(af, bf, acc[nt], 0, 0, 0);
      }
    }
  }
  const int mrow = ib + 16 * w + ((l >> 4) << 2);
#pragma unroll
  for (int nt = 0; nt < 4; ++nt) {
    const int col = jb + nt * 16 + (l & 15);
#pragma unroll
    for (int r = 0; r < 4; ++r)
      atomicAdd(&C[(size_t)(mrow + r) * N + col], acc[nt][r]);
  }
}

// ---------------- G = (An_b @ T_b) + bias; bf16 out if Gb, else fp32 -------
__global__ __launch_bounds__(256) void k_graph_mm(
    const float* __restrict__ An, const float* __restrict__ T,
    const float* __restrict__ bias, float* __restrict__ Gf,
    ushort_t* __restrict__ Gb, int F, int relu)
{
  const int b = blockIdx.y;
  const int f0 = blockIdx.x << 6;
  __shared__ float Ans[64 * 65];
  __shared__ float Ts[64 * 64];
  const int t = threadIdx.x;
  for (int idx = t; idx < 4096; idx += 256)
    Ans[(idx >> 6) * 65 + (idx & 63)] = An[b * 4096 + idx];
  for (int idx = t; idx < 1024; idx += 256) {
    const int j = idx >> 4, q = idx & 15;
    *(float4*)&Ts[j * 64 + 4 * q] = *(const float4*)&T[(size_t)(b * 64 + j) * F + f0 + 4 * q];
  }
  __syncthreads();
  const int i = t >> 2, fq = t & 3;
  float acc[16];
#pragma unroll
  for (int u = 0; u < 16; ++u) acc[u] = 0.f;
#pragma unroll 1
  for (int j = 0; j < 64; ++j) {
    const float aij = Ans[i * 65 + j];
    const float* tr = &Ts[j * 64 + fq * 16];
#pragma unroll
    for (int u = 0; u < 16; ++u) acc[u] += aij * tr[u];
  }
  const float* br = bias + f0 + fq * 16;
  if (Gb) {
    ushort_t* gr = Gb + (size_t)(b * 64 + i) * F + f0 + fq * 16;
#pragma unroll
    for (int u = 0; u < 16; ++u) {
      float v = acc[u] + br[u];
      if (relu) v = fmaxf(v, 0.f);
      gr[u] = f2bf(v);
    }
  } else {
    float* gr = Gf + (size_t)(b * 64 + i) * F + f0 + fq * 16;
#pragma unroll
    for (int u = 0; u < 16; ++u) {
      float v = acc[u] + br[u];
      if (relu) v = fmaxf(v, 0.f);
      gr[u] = v;
    }
  }
}

// ---------------- head: chunk-max + fc1 + relu + fc2 + softmax -------------
__global__ __launch_bounds__(256) void k_head(
    const float* __restrict__ g3, const float* __restrict__ w1, const float* __restrict__ b1,
    const float* __restrict__ w2, const float* __restrict__ b2, float* __restrict__ out)
{
  const int b = blockIdx.x, t = threadIdx.x;
  __shared__ float sp[256];
  __shared__ float sh[512];
  __shared__ float sl[4];
  {
    const int n = t >> 2, c = t & 3;
    const float* gr = g3 + (size_t)(b * 64 + n) * 256 + c * 64;
    float mx = -1e30f;
    for (int f = 0; f < 64; ++f) mx = fmaxf(mx, gr[f]);
    sp[t] = mx;
  }
  __syncthreads();
  for (int jj = t; jj < 512; jj += 256) {
    float s = b1[jj];
    for (int k = 0; k < 256; ++k) s += sp[k] * w1[k * 512 + jj];
    sh[jj] = fmaxf(s, 0.f);
  }
  __syncthreads();
  if (t < 4) {
    float s = b2[t];
    for (int k = 0; k < 512; ++k) s += sh[k] * w2[k * 4 + t];
    sl[t] = s;
  }
  __syncthreads();
  if (t == 0) {
    const float mm = fmaxf(fmaxf(sl[0], sl[1]), fmaxf(sl[2], sl[3]));
    const float e0 = expf(sl[0] - mm), e1 = expf(sl[1] - mm);
    const float e2 = expf(sl[2] - mm), e3 = expf(sl[3] - mm);
    const float inv = 1.f / (e0 + e1 + e2 + e3);
    out[b * 4 + 0] = e0 * inv;
    out[b * 4 + 1] = e1 * inv;
    out[b * 4 + 2] = e2 * inv;
    out[b * 4 + 3] = e3 * inv;
  }
}

// ---------------------------------------------------------------------------
extern "C" void kernel_launch(void* const* d_in, const int* in_sizes, int n_in,
                              void* d_out, int out_size, void* d_ws, size_t ws_size,
                              hipStream_t stream)
{
  (void)in_sizes; (void)n_in; (void)out_size; (void)ws_size;
  const float* x   = (const float*)d_in[0];
  const int*   adj = (const int*)d_in[1];
  const float* wc1 = (const float*)d_in[3];
  const float* bc1 = (const float*)d_in[4];
  const float* wc2 = (const float*)d_in[5];
  const float* bc2 = (const float*)d_in[6];
  const float* wg1 = (const float*)d_in[7];
  const float* bg1 = (const float*)d_in[8];
  const float* wg2 = (const float*)d_in[9];
  const float* bg2 = (const float*)d_in[10];
  const float* wg3 = (const float*)d_in[11];
  const float* bg3 = (const float*)d_in[12];
  const float* wf1 = (const float*)d_in[13];
  const float* bf1 = (const float*)d_in[14];
  const float* wf2 = (const float*)d_in[15];
  const float* bf2 = (const float*)d_in[16];

  float* ws    = (float*)d_ws;
  ushort_t* h1 = (ushort_t*)d_ws;
  ushort_t* w2f   = (ushort_t*)(ws + 8388608);
  ushort_t* wg1Tb = (ushort_t*)(ws + 8395776);
  ushort_t* wg2Tb = (ushort_t*)(ws + 9444352);
  ushort_t* wg3Tb = (ushort_t*)(ws + 9706496);
  ushort_t* featb = (ushort_t*)(ws + 9772032);
  ushort_t* g1b   = (ushort_t*)(ws + 10034176);
  ushort_t* g2b   = (ushort_t*)(ws + 10165248);
  float* c2   = ws + 16777216;
  float* An   = ws + 21495808;
  float* t1   = ws + 21512192;
  float* t2   = ws + 21774336;
  float* t3   = ws + 21905408;
  float* g3   = ws + 22364160;
  float* outp = (float*)d_out;

  hipLaunchKernelGGL(k_zero,         dim3(1792),     dim3(256), 0, stream, t1, 458752); // t1..t3
  hipLaunchKernelGGL(k_prep_w2f,     dim3(56),       dim3(256), 0, stream, wc2, w2f);
  hipLaunchKernelGGL(k_transpose_bf, dim3(32, 64),   dim3(256), 0, stream, wg1, wg1Tb, 2048, 1024);
  hipLaunchKernelGGL(k_transpose_bf, dim3(16, 32),   dim3(256), 0, stream, wg2, wg2Tb, 1024, 512);
  hipLaunchKernelGGL(k_transpose_bf, dim3(8, 16),    dim3(256), 0, stream, wg3, wg3Tb, 512, 256);
  hipLaunchKernelGGL(k_conv1_mfma,   dim3(2048),     dim3(256), 0, stream, x, wc1, bc1, h1);
  hipLaunchKernelGGL(k_conv2,        dim3(2048),     dim3(256), 0, stream, h1, w2f, c2);
  hipLaunchKernelGGL(k_pool2,        dim3(2048),     dim3(256), 0, stream, c2, bc2, featb);
  hipLaunchKernelGGL(k_gcn_norm,     dim3(4),        dim3(64),  0, stream, adj, An);
  hipLaunchKernelGGL(k_gemm_bf16,    dim3(16,4,4),   dim3(256), 0, stream, featb, wg1Tb, t1, 256, 1024, 2048, 512);
  hipLaunchKernelGGL(k_graph_mm,     dim3(16,4),     dim3(256), 0, stream, An, t1, bg1, (float*)nullptr, g1b, 1024, 1);
  hipLaunchKernelGGL(k_gemm_bf16,    dim3(8,4,4),    dim3(256), 0, stream, g1b, wg2Tb, t2, 256, 512, 1024, 256);
  hipLaunchKernelGGL(k_graph_mm,     dim3(8,4),      dim3(256), 0, stream, An, t2, bg2, (float*)nullptr, g2b, 512, 1);
  hipLaunchKernelGGL(k_gemm_bf16,    dim3(4,4,4),    dim3(256), 0, stream, g2b, wg3Tb, t3, 256, 256, 512, 128);
  hipLaunchKernelGGL(k_graph_mm,     dim3(4,4),      dim3(256), 0, stream, An, t3, bg3, g3, (ushort_t*)nullptr, 256, 0);
  hipLaunchKernelGGL(k_head,         dim3(4),        dim3(256), 0, stream, g3, wf1, bf1, wf2, bf2, outp);
}

// Round 6
// 334.770 us; speedup vs baseline: 3.4445x; 1.0788x over previous
//
#include <hip/hip_runtime.h>

typedef unsigned short ushort_t;
typedef __attribute__((ext_vector_type(8))) short bf16x8;
typedef __attribute__((ext_vector_type(4))) float f32x4;

static __device__ __forceinline__ unsigned short f2bf(float f) {
  unsigned u = __float_as_uint(f);
  u = (u + 0x7FFFu + ((u >> 16) & 1u)) >> 16;
  return (unsigned short)u;
}

static __device__ __forceinline__ f32x4 max4(f32x4 a, f32x4 b) {
  f32x4 r;
  r[0] = fmaxf(a[0], b[0]); r[1] = fmaxf(a[1], b[1]);
  r[2] = fmaxf(a[2], b[2]); r[3] = fmaxf(a[3], b[3]);
  return r;
}

// ---------------------------------------------------------------------------
// Workspace layout (fp32-element offsets):
//   h1    @ 0          : 16777216 ushorts
//   w2f   @ 8388608    : 14336 ushorts (conv2 weight frags)
//   wg1Tb @ 8395776    : 1024x2048 ushorts
//   wg2Tb @ 9444352    : 512x1024 ushorts
//   wg3Tb @ 9706496    : 256x512 ushorts
//   featb @ 9772032    : 256x2048 ushorts
//   g1b   @ 10034176   : 256x1024 ushorts
//   g2b   @ 10165248   : 256x512 ushorts
//   c2    @ 16777216   : 4194304 floats   (ALIASED: xb16 = 8388608 ushorts,
//                        consumed by conv1 BEFORE conv2 writes c2)
//   An    @ 21495808   : 4*64*64
//   t1    @ 21512192   : 256*1024 (atomics, zeroed)
//   t2    @ 21774336   : 256*512
//   t3    @ 21905408   : 256*256
//   g3    @ 22364160   : 256*256
// ---------------------------------------------------------------------------

// ---------------- x -> bf16 once (streaming) -------------------------------
__global__ void k_x2bf(const float* __restrict__ x, ushort_t* __restrict__ xb16)
{
  const int tid = blockIdx.x * 256 + threadIdx.x;   // 2097152 float4s
  const float4 v = ((const float4*)x)[tid];
  const unsigned lo = (unsigned)f2bf(v.x) | ((unsigned)f2bf(v.y) << 16);
  const unsigned hi = (unsigned)f2bf(v.z) | ((unsigned)f2bf(v.w) << 16);
  ((uint2*)xb16)[tid] = make_uint2(lo, hi);
}

// ---------------- K1: conv1 + maxpool3 as bf16 MFMA "pooled-direct" --------
// grid 2048 = (bn, zg); block 256 (4 waves). Staging now reads pre-converted
// bf16 x: borders of L zeroed once; interior staged per-ci by 128 threads as
// 3x uint4 loads + bit-interleave + 8x ds_write_b64 (no div/f2bf/scalar ld).
__global__ __launch_bounds__(256) void k_conv1_mfma(
    const ushort_t* __restrict__ xb16, const float* __restrict__ wc,
    const float* __restrict__ bc, ushort_t* __restrict__ h1)
{
  __shared__ ushort_t L[2 * 34 * 76];
  char* Lb = (char*)L;
  const int bn = blockIdx.x >> 3, zg = blockIdx.x & 7;
  const int t = threadIdx.x;
  const int w = t >> 6, l = t & 63;
  const int grp = l >> 4, m = l & 15, ch = l & 15;
  const float NINF = -1e30f;

  union { short s[8]; bf16x8 v; } uA, uB;
#pragma unroll
  for (int j = 0; j < 8; ++j) {
    const int k = grp * 8 + j;
    float wA = 0.f, wB = 0.f;
    if (k < 12) {
      const int dx = k >> 2, dz = k & 3;
      if (dz < 3) { wA = wc[ch*27 + dz*9 + 0 + dx]; wB = wc[ch*27 + dz*9 + 6 + dx]; }
    } else if (k >= 16 && k < 28) {
      const int kk = k - 16, dx = kk >> 2, dz = kk & 3;
      if (dz < 3) wA = wc[ch*27 + dz*9 + 3 + dx];
    }
    uA.s[j] = (short)f2bf(wA);
    uB.s[j] = (short)f2bf(wB);
  }

  int aX1[3], aX2[3];
#pragma unroll
  for (int s = 0; s < 3; ++s) {
    const int Q1 = 2*m + s + 2*(grp & 1);
    const int Q2 = Q1 + 1;
    aX1[s] = (Q1 & 1) * 5168 + (Q1 >> 1) * 8;
    aX2[s] = (Q2 & 1) * 5168 + (Q2 >> 1) * 8;
  }
  const int rsel = (grp >> 1) * 152;

  // ---- border zeros (rows 0,33 slots 0..17; rows 1..32 slots {0,17}) ----
  for (int u = t; u < 200; u += 256) {
    int addr;
    if (u < 72) {
      const int rr = (u < 36) ? 0 : 33;
      const int s = (u < 36) ? u : u - 36;
      const int pp = s / 18, slot = s - pp * 18;
      addr = pp * 5168 + rr * 152 + slot * 8;
    } else {
      const int v = u - 72;
      const int rr = 1 + (v >> 2);
      const int pp = (v >> 1) & 1;
      const int slot = (v & 1) * 17;
      addr = pp * 5168 + rr * 152 + slot * 8;
    }
    *(unsigned long long*)(Lb + addr) = 0ull;
  }

  f32x4 accZ[4][2];
#pragma unroll
  for (int j = 0; j < 4; ++j)
#pragma unroll
    for (int p = 0; p < 2; ++p) accZ[j][p] = (f32x4){NINF, NINF, NINF, NINF};

  const ushort_t* xb = xb16 + (size_t)bn * 32768;

#pragma unroll 1
  for (int ci = 0; ci < 5; ++ci) {
    const int cz = 4*zg - 1 + ci;
    if (cz < 0) continue;
    // ---- interior staging: 128 threads, rows yi 0..31, x-groups of 8 ----
    if (t < 128) {
      const int r = 1 + (t >> 2), g = t & 3;
      const ushort_t* xrow = xb + (r - 1) * 32 + g * 8;
      uint4 u0 = make_uint4(0u, 0u, 0u, 0u), u2 = make_uint4(0u, 0u, 0u, 0u);
      if (cz > 0)  u0 = *(const uint4*)(xrow + (cz - 1) * 1024);
      const uint4 u1 = *(const uint4*)(xrow + cz * 1024);
      if (cz < 31) u2 = *(const uint4*)(xrow + (cz + 1) * 1024);
      char* b0 = Lb + r * 152 + (4 * g + 1) * 8;          // parity0 slots 4g+1..4g+4
      char* b1 = Lb + 5168 + r * 152 + (4 * g + 1) * 8;   // parity1
      const unsigned* p0 = (const unsigned*)&u0;
      const unsigned* p1 = (const unsigned*)&u1;
      const unsigned* p2 = (const unsigned*)&u2;
#pragma unroll
      for (int e = 0; e < 4; ++e) {
        const unsigned w0 = p0[e], w1 = p1[e], w2v = p2[e];
        const unsigned lo_e = (w0 & 0xFFFFu) | (w1 << 16);
        const unsigned hi_e = (w2v & 0xFFFFu);
        const unsigned lo_o = (w0 >> 16) | (w1 & 0xFFFF0000u);
        const unsigned hi_o = (w2v >> 16);
        *(unsigned long long*)(b0 + e * 8) =
            (unsigned long long)lo_e | ((unsigned long long)hi_e << 32);
        *(unsigned long long*)(b1 + e * 8) =
            (unsigned long long)lo_o | ((unsigned long long)hi_o << 32);
      }
    }
    __syncthreads();
    f32x4 accP0 = (f32x4){NINF, NINF, NINF, NINF};
    f32x4 accP1 = (f32x4){NINF, NINF, NINF, NINF};
#pragma unroll
    for (int yy = 0; yy < 9; ++yy) {
      if (yy == 0 && w == 0) continue;
      const int y = 8 * w - 1 + yy;
      const int rbA = y * 152 + rsel;
      const int rbB = (y + 2) * 152;
      f32x4 Cy;
#pragma unroll
      for (int s = 0; s < 3; ++s) {
        union { unsigned long long u[2]; bf16x8 v; } fA, fB;
        fA.u[0] = *(const unsigned long long*)(Lb + aX1[s] + rbA);
        fA.u[1] = *(const unsigned long long*)(Lb + aX2[s] + rbA);
        fB.u[0] = *(const unsigned long long*)(Lb + aX1[s] + rbB);
        fB.u[1] = *(const unsigned long long*)(Lb + aX2[s] + rbB);
        f32x4 acc = (f32x4){0.f, 0.f, 0.f, 0.f};
        acc = __builtin_amdgcn_mfma_f32_16x16x32_bf16(fA.v, uA.v, acc, 0, 0, 0);
        acc = __builtin_amdgcn_mfma_f32_16x16x32_bf16(fB.v, uB.v, acc, 0, 0, 0);
        if (s == 0) acc[0] = (l < 16) ? NINF : acc[0];
        Cy = (s == 0) ? acc : max4(Cy, acc);
      }
      if (yy & 1) {
        const int c = (yy - 1) / 2;
        if ((c & 1) == 0) accP0 = max4(accP0, Cy); else accP1 = max4(accP1, Cy);
      } else {
        const int cl = yy / 2 - 1;
        const int chh = yy / 2;
        if (cl >= 0) {
          if ((cl & 1) == 0) {
            accP0 = max4(accP0, Cy);
            if (ci <= 2) accZ[cl][0] = max4(accZ[cl][0], accP0);
            if (ci >= 2) accZ[cl][1] = max4(accZ[cl][1], accP0);
            accP0 = (f32x4){NINF, NINF, NINF, NINF};
          } else {
            accP1 = max4(accP1, Cy);
            if (ci <= 2) accZ[cl][0] = max4(accZ[cl][0], accP1);
            if (ci >= 2) accZ[cl][1] = max4(accZ[cl][1], accP1);
            accP1 = (f32x4){NINF, NINF, NINF, NINF};
          }
        }
        if (chh <= 3) {
          if ((chh & 1) == 0) accP0 = max4(accP0, Cy); else accP1 = max4(accP1, Cy);
        }
      }
    }
    __syncthreads();
  }

  const float biasv = bc[ch];
#pragma unroll
  for (int j = 0; j < 4; ++j) {
    const int py = 4 * w + j;
#pragma unroll
    for (int p = 0; p < 2; ++p) {
      const int pz = 2 * zg + p;
      const f32x4 v = accZ[j][p];
      const unsigned lo = (unsigned)f2bf(fmaxf(v[0] + biasv, 0.f)) |
                          ((unsigned)f2bf(fmaxf(v[1] + biasv, 0.f)) << 16);
      const unsigned hi = (unsigned)f2bf(fmaxf(v[2] + biasv, 0.f)) |
                          ((unsigned)f2bf(fmaxf(v[3] + biasv, 0.f)) << 16);
      ushort_t* dst = h1 + (((size_t)(bn * 16 + ch) * 16 + pz) << 8) + py * 16 + grp * 4;
      *(uint2*)dst = make_uint2(lo, hi);
    }
  }
}

// ---------------- conv2 weight-fragment prep -------------------------------
__global__ void k_prep_w2f(const float* __restrict__ w2, ushort_t* __restrict__ w2f)
{
  const int tid = blockIdx.x * 256 + threadIdx.x;   // 14336
  if (tid >= 14336) return;
  const int nt = tid / 7168, rem = tid % 7168;
  const int kk = rem / 512, rem2 = rem % 512;
  const int l = rem2 >> 3, j = rem2 & 7;
  const int n = nt * 16 + (l & 15);
  const int k = (l >> 4) * 8 + kk * 32 + j;
  float v = 0.f;
  if (k < 432) v = w2[n * 432 + k];
  w2f[tid] = f2bf(v);
}

// ---------------- tiled transpose + bf16: out[n][k] = bf(W[k][n]) ----------
__global__ __launch_bounds__(256) void k_transpose_bf(
    const float* __restrict__ W, ushort_t* __restrict__ out, int K, int N)
{
  __shared__ float tile[32][33];
  const int t = threadIdx.x;
  const int tx = t & 31, ty = t >> 5;
  const int n0 = blockIdx.x << 5, k0 = blockIdx.y << 5;
#pragma unroll
  for (int i = 0; i < 4; ++i) {
    const int k = k0 + ty + i * 8;
    tile[ty + i * 8][tx] = W[(size_t)k * N + n0 + tx];
  }
  __syncthreads();
#pragma unroll
  for (int i = 0; i < 4; ++i) {
    const int n = n0 + ty + i * 8;
    out[(size_t)n * K + k0 + tx] = f2bf(tile[tx][ty + i * 8]);
  }
}

// ---------------- K2: conv2 as bf16 MFMA implicit GEMM ---------------------
__global__ __launch_bounds__(256) void k_conv2(
    const ushort_t* __restrict__ h1, const ushort_t* __restrict__ w2f,
    float* __restrict__ c2)
{
  __shared__ ushort_t As[32 * 456];
  const int bn = blockIdx.x >> 3, oz = blockIdx.x & 7;
  const int t = threadIdx.x;
  const ushort_t* hb = h1 + ((size_t)bn << 16);

  const int w = t >> 6, l = t & 63;
  const int ntile = w >> 1, mtile = w & 1;
  bf16x8 bfr[14];
#pragma unroll
  for (int kk = 0; kk < 14; ++kk)
    bfr[kk] = *(const bf16x8*)(const void*)&w2f[(((ntile * 14) + kk) * 64 + l) * 8];

  for (int idx = t; idx < 512; idx += 256) {
    const int r = idx >> 4, k = 432 + (idx & 15);
    As[r * 456 + k] = 0;
  }

  const int m = t >> 3;
  const int sub = t & 7;
  const int ox = m & 7;

#pragma unroll 1
  for (int h = 0; h < 2; ++h) {
    if (h) __syncthreads();
    const int oy = h * 4 + (m >> 3);
    ushort_t tv[54];
    int j = 0;
#pragma unroll
    for (int ic2 = 0; ic2 < 2; ++ic2) {
      const ushort_t* icp = hb + ((sub * 2 + ic2) << 12);
#pragma unroll
      for (int dz = 0; dz < 3; ++dz) {
        const int iz = 2 * oz - 1 + dz;
        const bool zok = (unsigned)iz < 16u;
        const ushort_t* zp = icp + (iz << 8);
#pragma unroll
        for (int dy = 0; dy < 3; ++dy) {
          const int iy = 2 * oy - 1 + dy;
          const bool yok = zok && ((unsigned)iy < 16u);
          const ushort_t* yp = zp + (iy << 4);
#pragma unroll
          for (int dx = 0; dx < 3; ++dx) {
            const int ix = 2 * ox - 1 + dx;
            tv[j++] = (yok && (unsigned)ix < 16u) ? yp[ix] : (ushort_t)0;
          }
        }
      }
    }
    {
      unsigned* Aw = (unsigned*)As;
      const int wbase = m * 228 + sub * 27;
#pragma unroll
      for (int p = 0; p < 27; ++p)
        Aw[wbase + p] = (unsigned)tv[2 * p] | ((unsigned)tv[2 * p + 1] << 16);
    }
    __syncthreads();
    f32x4 acc = {0.f, 0.f, 0.f, 0.f};
    const ushort_t* arow = &As[(mtile * 16 + (l & 15)) * 456 + ((l >> 4) << 3)];
#pragma unroll
    for (int kk = 0; kk < 14; ++kk) {
      const bf16x8 af = *(const bf16x8*)(const void*)&arow[kk * 32];
      acc = __builtin_amdgcn_mfma_f32_16x16x32_bf16(af, bfr[kk], acc, 0, 0, 0);
    }
    const int n = ntile * 16 + (l & 15);
    const int m0 = mtile * 16 + ((l >> 4) << 2);
    float* cb = c2 + (((size_t)(bn * 32 + n) * 8) + oz) * 64;
#pragma unroll
    for (int r = 0; r < 4; ++r) {
      const int mm = m0 + r;
      cb[(h * 4 + (mm >> 3)) * 8 + (mm & 7)] = acc[r];
    }
  }
}

// ---------------- K2b: maxpool3 s2 p1 + bias + relu -> feat (bf16) ---------
// grid 512; thread computes 4 px outputs from float4 row loads.
__global__ __launch_bounds__(256) void k_pool2(
    const float* __restrict__ c2, const float* __restrict__ bc2,
    ushort_t* __restrict__ featb)
{
  const int tid = blockIdx.x * 256 + threadIdx.x;  // 131072
  const int bn = tid >> 9, r = tid & 511;
  const int ch = r >> 4, pz = (r >> 2) & 3, py = r & 3;
  const float* base = c2 + ((size_t)(bn * 32 + ch) << 9);
  float m0 = -1e30f, m1 = -1e30f, m2 = -1e30f, m3 = -1e30f;
#pragma unroll
  for (int dz = 0; dz < 3; ++dz) {
    const int oz = 2 * pz - 1 + dz;
    if ((unsigned)oz >= 8u) continue;
#pragma unroll
    for (int dy = 0; dy < 3; ++dy) {
      const int oy = 2 * py - 1 + dy;
      if ((unsigned)oy >= 8u) continue;
      const float* row = base + (oz << 6) + (oy << 3);
      const float4 a = ((const float4*)row)[0];
      const float4 b = ((const float4*)row)[1];
      m0 = fmaxf(m0, fmaxf(a.x, a.y));
      m1 = fmaxf(m1, fmaxf(a.y, fmaxf(a.z, a.w)));
      m2 = fmaxf(m2, fmaxf(a.w, fmaxf(b.x, b.y)));
      m3 = fmaxf(m3, fmaxf(b.y, fmaxf(b.z, b.w)));
    }
  }
  const float bb = bc2[ch];
  const unsigned lo = (unsigned)f2bf(fmaxf(m0 + bb, 0.f)) |
                      ((unsigned)f2bf(fmaxf(m1 + bb, 0.f)) << 16);
  const unsigned hi = (unsigned)f2bf(fmaxf(m2 + bb, 0.f)) |
                      ((unsigned)f2bf(fmaxf(m3 + bb, 0.f)) << 16);
  *(uint2*)(featb + (size_t)bn * 2048 + r * 4) = make_uint2(lo, hi);
}

// ---------------- A_norm = D^-1/2 (A+I) D^-1/2 -----------------------------
__global__ __launch_bounds__(256) void k_gcn_norm(const int* __restrict__ adj, float* __restrict__ An)
{
  const int b = blockIdx.x, t = threadIdx.x;
  __shared__ float dinv[64];
  __shared__ int part[256];
  const int i = t >> 2, q = t & 3;
  const int* ab = adj + b * 4096 + i * 64 + q * 16;
  int d = 0;
#pragma unroll
  for (int j = 0; j < 16; ++j) d += (ab[j] != 0) ? 1 : 0;
  part[t] = d;
  __syncthreads();
  if (q == 0)
    dinv[i] = rsqrtf((float)(1 + part[t] + part[t + 1] + part[t + 2] + part[t + 3]));
  __syncthreads();
  for (int idx = t; idx < 4096; idx += 256) {
    const int ii = idx >> 6, jj = idx & 63;
    const float a = (ii == jj) ? 1.f : ((adj[b * 4096 + idx] != 0) ? 1.f : 0.f);
    An[b * 4096 + idx] = a * dinv[ii] * dinv[jj];
  }
}

// ---------------- zero a region -------------------------------------------
__global__ void k_zero(float* __restrict__ p, int n)
{
  const int tid = blockIdx.x * 256 + threadIdx.x;
  if (tid < n) p[tid] = 0.f;
}

// ---------------- bf16 MFMA GEMM, 64x64 tile, K-split + fp32 atomics -------
__global__ __launch_bounds__(256) void k_gemm_bf16(
    const ushort_t* __restrict__ A, const ushort_t* __restrict__ BT,
    float* __restrict__ C, int M, int N, int K, int klen)
{
  (void)M;
  __shared__ ushort_t As[64 * 72];
  __shared__ ushort_t Bs[64 * 72];
  const int jb = blockIdx.x << 6, ib = blockIdx.y << 6;
  const int k0 = blockIdx.z * klen;
  const int t = threadIdx.x, w = t >> 6, l = t & 63;
  const int r0 = t >> 3, kc0 = t & 7;
  f32x4 acc[4];
#pragma unroll
  for (int nt = 0; nt < 4; ++nt) acc[nt] = (f32x4){0.f, 0.f, 0.f, 0.f};

#pragma unroll 1
  for (int kt = 0; kt < klen; kt += 64) {
    __syncthreads();
#pragma unroll
    for (int h = 0; h < 2; ++h) {
      const int row = r0 + h * 32;
      const uint4 va = *(const uint4*)&A[(size_t)(ib + row) * K + k0 + kt + kc0 * 8];
      *(uint4*)&As[row * 72 + kc0 * 8] = va;
      const uint4 vb = *(const uint4*)&BT[(size_t)(jb + row) * K + k0 + kt + kc0 * 8];
      *(uint4*)&Bs[row * 72 + kc0 * 8] = vb;
    }
    __syncthreads();
#pragma unroll
    for (int ks = 0; ks < 2; ++ks) {
      const bf16x8 af = *(const bf16x8*)(const void*)
          &As[(16 * w + (l & 15)) * 72 + ks * 32 + ((l >> 4) << 3)];
#pragma unroll
      for (int nt = 0; nt < 4; ++nt) {
        const bf16x8 bf = *(const bf16x8*)(const void*)
            &Bs[(nt * 16 + (l & 15)) * 72 + ks * 32 + ((l >> 4) << 3)];
        acc[nt] = __builtin_amdgcn_mfma_f32_16x16x32_bf16(af, bf, acc[nt], 0, 0, 0);
      }
    }
  }
  const int mrow = ib + 16 * w + ((l >> 4) << 2);
#pragma unroll
  for (int nt = 0; nt < 4; ++nt) {
    const int col = jb + nt * 16 + (l & 15);
#pragma unroll
    for (int r = 0; r < 4; ++r)
      atomicAdd(&C[(size_t)(mrow + r) * N + col], acc[nt][r]);
  }
}

// ---------------- G = (An_b @ T_b) + bias; bf16 out if Gb, else fp32 -------
__global__ __launch_bounds__(256) void k_graph_mm(
    const float* __restrict__ An, const float* __restrict__ T,
    const float* __restrict__ bias, float* __restrict__ Gf,
    ushort_t* __restrict__ Gb, int F, int relu)
{
  const int b = blockIdx.y;
  const int f0 = blockIdx.x << 6;
  __shared__ float Ans[64 * 65];
  __shared__ float Ts[64 * 64];
  const int t = threadIdx.x;
  for (int idx = t; idx < 4096; idx += 256)
    Ans[(idx >> 6) * 65 + (idx & 63)] = An[b * 4096 + idx];
  for (int idx = t; idx < 1024; idx += 256) {
    const int j = idx >> 4, q = idx & 15;
    *(float4*)&Ts[j * 64 + 4 * q] = *(const float4*)&T[(size_t)(b * 64 + j) * F + f0 + 4 * q];
  }
  __syncthreads();
  const int i = t >> 2, fq = t & 3;
  float4 a0 = {0,0,0,0}, a1 = {0,0,0,0}, a2 = {0,0,0,0}, a3 = {0,0,0,0};
#pragma unroll 1
  for (int j = 0; j < 64; ++j) {
    const float aij = Ans[i * 65 + j];
    const float4* tr = (const float4*)&Ts[j * 64 + fq * 16];
    const float4 v0 = tr[0], v1 = tr[1], v2 = tr[2], v3 = tr[3];
    a0.x += aij * v0.x; a0.y += aij * v0.y; a0.z += aij * v0.z; a0.w += aij * v0.w;
    a1.x += aij * v1.x; a1.y += aij * v1.y; a1.z += aij * v1.z; a1.w += aij * v1.w;
    a2.x += aij * v2.x; a2.y += aij * v2.y; a2.z += aij * v2.z; a2.w += aij * v2.w;
    a3.x += aij * v3.x; a3.y += aij * v3.y; a3.z += aij * v3.z; a3.w += aij * v3.w;
  }
  float acc[16];
  *(float4*)&acc[0] = a0; *(float4*)&acc[4] = a1;
  *(float4*)&acc[8] = a2; *(float4*)&acc[12] = a3;
  const float* br = bias + f0 + fq * 16;
  if (Gb) {
    ushort_t* gr = Gb + (size_t)(b * 64 + i) * F + f0 + fq * 16;
#pragma unroll
    for (int u = 0; u < 16; ++u) {
      float v = acc[u] + br[u];
      if (relu) v = fmaxf(v, 0.f);
      gr[u] = f2bf(v);
    }
  } else {
    float* gr = Gf + (size_t)(b * 64 + i) * F + f0 + fq * 16;
#pragma unroll
    for (int u = 0; u < 16; ++u) {
      float v = acc[u] + br[u];
      if (relu) v = fmaxf(v, 0.f);
      gr[u] = v;
    }
  }
}

// ---------------- head: chunk-max + fc1 + relu + fc2 + softmax -------------
__global__ __launch_bounds__(256) void k_head(
    const float* __restrict__ g3, const float* __restrict__ w1, const float* __restrict__ b1,
    const float* __restrict__ w2, const float* __restrict__ b2, float* __restrict__ out)
{
  const int b = blockIdx.x, t = threadIdx.x;
  __shared__ float sp[256];
  __shared__ float sh[512];
  __shared__ float sl[4];
  {
    const int n = t >> 2, c = t & 3;
    const float* gr = g3 + (size_t)(b * 64 + n) * 256 + c * 64;
    float mx = -1e30f;
    for (int f = 0; f < 64; ++f) mx = fmaxf(mx, gr[f]);
    sp[t] = mx;
  }
  __syncthreads();
  for (int jj = t; jj < 512; jj += 256) {
    float s = b1[jj];
    for (int k = 0; k < 256; ++k) s += sp[k] * w1[k * 512 + jj];
    sh[jj] = fmaxf(s, 0.f);
  }
  __syncthreads();
  if (t < 4) {
    float s = b2[t];
    for (int k = 0; k < 512; ++k) s += sh[k] * w2[k * 4 + t];
    sl[t] = s;
  }
  __syncthreads();
  if (t == 0) {
    const float mm = fmaxf(fmaxf(sl[0], sl[1]), fmaxf(sl[2], sl[3]));
    const float e0 = expf(sl[0] - mm), e1 = expf(sl[1] - mm);
    const float e2 = expf(sl[2] - mm), e3 = expf(sl[3] - mm);
    const float inv = 1.f / (e0 + e1 + e2 + e3);
    out[b * 4 + 0] = e0 * inv;
    out[b * 4 + 1] = e1 * inv;
    out[b * 4 + 2] = e2 * inv;
    out[b * 4 + 3] = e3 * inv;
  }
}

// ---------------------------------------------------------------------------
extern "C" void kernel_launch(void* const* d_in, const int* in_sizes, int n_in,
                              void* d_out, int out_size, void* d_ws, size_t ws_size,
                              hipStream_t stream)
{
  (void)in_sizes; (void)n_in; (void)out_size; (void)ws_size;
  const float* x   = (const float*)d_in[0];
  const int*   adj = (const int*)d_in[1];
  const float* wc1 = (const float*)d_in[3];
  const float* bc1 = (const float*)d_in[4];
  const float* wc2 = (const float*)d_in[5];
  const float* bc2 = (const float*)d_in[6];
  const float* wg1 = (const float*)d_in[7];
  const float* bg1 = (const float*)d_in[8];
  const float* wg2 = (const float*)d_in[9];
  const float* bg2 = (const float*)d_in[10];
  const float* wg3 = (const float*)d_in[11];
  const float* bg3 = (const float*)d_in[12];
  const float* wf1 = (const float*)d_in[13];
  const float* bf1 = (const float*)d_in[14];
  const float* wf2 = (const float*)d_in[15];
  const float* bf2 = (const float*)d_in[16];

  float* ws    = (float*)d_ws;
  ushort_t* h1 = (ushort_t*)d_ws;
  ushort_t* w2f   = (ushort_t*)(ws + 8388608);
  ushort_t* wg1Tb = (ushort_t*)(ws + 8395776);
  ushort_t* wg2Tb = (ushort_t*)(ws + 9444352);
  ushort_t* wg3Tb = (ushort_t*)(ws + 9706496);
  ushort_t* featb = (ushort_t*)(ws + 9772032);
  ushort_t* g1b   = (ushort_t*)(ws + 10034176);
  ushort_t* g2b   = (ushort_t*)(ws + 10165248);
  float* c2    = ws + 16777216;
  ushort_t* xb16 = (ushort_t*)(ws + 16777216);   // aliases c2 (consumed pre-conv2)
  float* An   = ws + 21495808;
  float* t1   = ws + 21512192;
  float* t2   = ws + 21774336;
  float* t3   = ws + 21905408;
  float* g3   = ws + 22364160;
  float* outp = (float*)d_out;

  hipLaunchKernelGGL(k_x2bf,         dim3(8192),     dim3(256), 0, stream, x, xb16);
  hipLaunchKernelGGL(k_zero,         dim3(1792),     dim3(256), 0, stream, t1, 458752); // t1..t3
  hipLaunchKernelGGL(k_prep_w2f,     dim3(56),       dim3(256), 0, stream, wc2, w2f);
  hipLaunchKernelGGL(k_transpose_bf, dim3(32, 64),   dim3(256), 0, stream, wg1, wg1Tb, 2048, 1024);
  hipLaunchKernelGGL(k_transpose_bf, dim3(16, 32),   dim3(256), 0, stream, wg2, wg2Tb, 1024, 512);
  hipLaunchKernelGGL(k_transpose_bf, dim3(8, 16),    dim3(256), 0, stream, wg3, wg3Tb, 512, 256);
  hipLaunchKernelGGL(k_conv1_mfma,   dim3(2048),     dim3(256), 0, stream, xb16, wc1, bc1, h1);
  hipLaunchKernelGGL(k_conv2,        dim3(2048),     dim3(256), 0, stream, h1, w2f, c2);
  hipLaunchKernelGGL(k_pool2,        dim3(512),      dim3(256), 0, stream, c2, bc2, featb);
  hipLaunchKernelGGL(k_gcn_norm,     dim3(4),        dim3(256), 0, stream, adj, An);
  hipLaunchKernelGGL(k_gemm_bf16,    dim3(16,4,4),   dim3(256), 0, stream, featb, wg1Tb, t1, 256, 1024, 2048, 512);
  hipLaunchKernelGGL(k_graph_mm,     dim3(16,4),     dim3(256), 0, stream, An, t1, bg1, (float*)nullptr, g1b, 1024, 1);
  hipLaunchKernelGGL(k_gemm_bf16,    dim3(8,4,4),    dim3(256), 0, stream, g1b, wg2Tb, t2, 256, 512, 1024, 256);
  hipLaunchKernelGGL(k_graph_mm,     dim3(8,4),      dim3(256), 0, stream, An, t2, bg2, (float*)nullptr, g2b, 512, 1);
  hipLaunchKernelGGL(k_gemm_bf16,    dim3(4,4,4),    dim3(256), 0, stream, g2b, wg3Tb, t3, 256, 256, 512, 128);
  hipLaunchKernelGGL(k_graph_mm,     dim3(4,4),      dim3(256), 0, stream, An, t3, bg3, g3, (ushort_t*)nullptr, 256, 0);
  hipLaunchKernelGGL(k_head,         dim3(4),        dim3(256), 0, stream, g3, wf1, bf1, wf2, bf2, outp);
}

// Round 7
// 308.225 us; speedup vs baseline: 3.7412x; 1.0861x over previous
//
#include <hip/hip_runtime.h>

typedef unsigned short ushort_t;
typedef __attribute__((ext_vector_type(8))) short bf16x8;
typedef __attribute__((ext_vector_type(4))) float f32x4;

static __device__ __forceinline__ unsigned short f2bf(float f) {
  unsigned u = __float_as_uint(f);
  u = (u + 0x7FFFu + ((u >> 16) & 1u)) >> 16;
  return (unsigned short)u;
}

static __device__ __forceinline__ f32x4 max4(f32x4 a, f32x4 b) {
  f32x4 r;
  r[0] = fmaxf(a[0], b[0]); r[1] = fmaxf(a[1], b[1]);
  r[2] = fmaxf(a[2], b[2]); r[3] = fmaxf(a[3], b[3]);
  return r;
}

// ---------------------------------------------------------------------------
// Workspace layout (fp32-element offsets):
//   h1    @ 0          : 16777216 ushorts
//   w2f   @ 8388608    : 14336 ushorts (conv2 weight frags)
//   wg1Tb @ 8395776    : 1024x2048 ushorts
//   wg2Tb @ 9444352    : 512x1024 ushorts
//   wg3Tb @ 9706496    : 256x512 ushorts
//   featb @ 9772032    : 256x2048 ushorts
//   g1b   @ 10034176   : 256x1024 ushorts
//   g2b   @ 10165248   : 256x512 ushorts
//   c2    @ 16777216   : 4194304 floats   (ALIASED: xb16, consumed pre-conv2)
//   An    @ 21495808   : 4*64*64
//   t1    @ 21512192   : 256*1024 (atomics, zeroed)
//   t2    @ 21774336   : 256*512
//   t3    @ 21905408   : 256*256
//   g3    @ 22364160   : 256*256
// ---------------------------------------------------------------------------

// ---------------- fused prep: x2bf | zero | w2f | 3x transpose | gcn_norm ---
// grid 12732 = 8192 + 1792 + 56 + 2048 + 512 + 128 + 4, block 256.
__device__ __forceinline__ void prep_transpose(
    const float* __restrict__ W, ushort_t* __restrict__ out,
    int K, int N, int n0, int k0, int t, float (*tile)[33])
{
  const int tx = t & 31, ty = t >> 5;
#pragma unroll
  for (int i = 0; i < 4; ++i) {
    const int k = k0 + ty + i * 8;
    tile[ty + i * 8][tx] = W[(size_t)k * N + n0 + tx];
  }
  __syncthreads();
#pragma unroll
  for (int i = 0; i < 4; ++i) {
    const int n = n0 + ty + i * 8;
    out[(size_t)n * K + k0 + tx] = f2bf(tile[tx][ty + i * 8]);
  }
}

__global__ __launch_bounds__(256) void k_prep(
    const float* __restrict__ x, ushort_t* __restrict__ xb16,
    float* __restrict__ zr,
    const float* __restrict__ w2, ushort_t* __restrict__ w2f,
    const float* __restrict__ wg1, ushort_t* __restrict__ wg1T,
    const float* __restrict__ wg2, ushort_t* __restrict__ wg2T,
    const float* __restrict__ wg3, ushort_t* __restrict__ wg3T,
    const int* __restrict__ adj, float* __restrict__ An)
{
  __shared__ float tile[32][33];
  __shared__ float dinv[64];
  __shared__ int part[256];
  int b = blockIdx.x;
  const int t = threadIdx.x;
  if (b < 8192) {                       // x -> bf16
    const int tid = b * 256 + t;
    const float4 v = ((const float4*)x)[tid];
    const unsigned lo = (unsigned)f2bf(v.x) | ((unsigned)f2bf(v.y) << 16);
    const unsigned hi = (unsigned)f2bf(v.z) | ((unsigned)f2bf(v.w) << 16);
    ((uint2*)xb16)[tid] = make_uint2(lo, hi);
    return;
  }
  b -= 8192;
  if (b < 1792) {                       // zero t1..t3
    zr[b * 256 + t] = 0.f;
    return;
  }
  b -= 1792;
  if (b < 56) {                         // conv2 weight frags
    const int tid = b * 256 + t;
    if (tid < 14336) {
      const int nt = tid / 7168, rem = tid % 7168;
      const int kk = rem / 512, rem2 = rem % 512;
      const int l = rem2 >> 3, j = rem2 & 7;
      const int n = nt * 16 + (l & 15);
      const int k = (l >> 4) * 8 + kk * 32 + j;
      float v = 0.f;
      if (k < 432) v = w2[n * 432 + k];
      w2f[tid] = f2bf(v);
    }
    return;
  }
  b -= 56;
  if (b < 2048) { prep_transpose(wg1, wg1T, 2048, 1024, (b & 31) << 5, (b >> 5) << 5, t, tile); return; }
  b -= 2048;
  if (b < 512)  { prep_transpose(wg2, wg2T, 1024, 512,  (b & 15) << 5, (b >> 4) << 5, t, tile); return; }
  b -= 512;
  if (b < 128)  { prep_transpose(wg3, wg3T, 512,  256,  (b & 7)  << 5, (b >> 3) << 5, t, tile); return; }
  b -= 128;
  {                                     // gcn_norm, b in [0,4)
    const int i = t >> 2, q = t & 3;
    const int* ab = adj + b * 4096 + i * 64 + q * 16;
    int d = 0;
#pragma unroll
    for (int j = 0; j < 16; ++j) d += (ab[j] != 0) ? 1 : 0;
    part[t] = d;
    __syncthreads();
    if (q == 0)
      dinv[i] = rsqrtf((float)(1 + part[t] + part[t + 1] + part[t + 2] + part[t + 3]));
    __syncthreads();
    for (int idx = t; idx < 4096; idx += 256) {
      const int ii = idx >> 6, jj = idx & 63;
      const float a = (ii == jj) ? 1.f : ((adj[b * 4096 + idx] != 0) ? 1.f : 0.f);
      An[b * 4096 + idx] = a * dinv[ii] * dinv[jj];
    }
  }
}

// ---------------- K1: conv1 + maxpool3 as bf16 MFMA "pooled-direct" --------
__global__ __launch_bounds__(256) void k_conv1_mfma(
    const ushort_t* __restrict__ xb16, const float* __restrict__ wc,
    const float* __restrict__ bc, ushort_t* __restrict__ h1)
{
  __shared__ ushort_t L[2 * 34 * 76];
  char* Lb = (char*)L;
  const int bn = blockIdx.x >> 3, zg = blockIdx.x & 7;
  const int t = threadIdx.x;
  const int w = t >> 6, l = t & 63;
  const int grp = l >> 4, m = l & 15, ch = l & 15;
  const float NINF = -1e30f;

  union { short s[8]; bf16x8 v; } uA, uB;
#pragma unroll
  for (int j = 0; j < 8; ++j) {
    const int k = grp * 8 + j;
    float wA = 0.f, wB = 0.f;
    if (k < 12) {
      const int dx = k >> 2, dz = k & 3;
      if (dz < 3) { wA = wc[ch*27 + dz*9 + 0 + dx]; wB = wc[ch*27 + dz*9 + 6 + dx]; }
    } else if (k >= 16 && k < 28) {
      const int kk = k - 16, dx = kk >> 2, dz = kk & 3;
      if (dz < 3) wA = wc[ch*27 + dz*9 + 3 + dx];
    }
    uA.s[j] = (short)f2bf(wA);
    uB.s[j] = (short)f2bf(wB);
  }

  int aX1[3], aX2[3];
#pragma unroll
  for (int s = 0; s < 3; ++s) {
    const int Q1 = 2*m + s + 2*(grp & 1);
    const int Q2 = Q1 + 1;
    aX1[s] = (Q1 & 1) * 5168 + (Q1 >> 1) * 8;
    aX2[s] = (Q2 & 1) * 5168 + (Q2 >> 1) * 8;
  }
  const int rsel = (grp >> 1) * 152;

  for (int u = t; u < 200; u += 256) {
    int addr;
    if (u < 72) {
      const int rr = (u < 36) ? 0 : 33;
      const int s = (u < 36) ? u : u - 36;
      const int pp = s / 18, slot = s - pp * 18;
      addr = pp * 5168 + rr * 152 + slot * 8;
    } else {
      const int v = u - 72;
      const int rr = 1 + (v >> 2);
      const int pp = (v >> 1) & 1;
      const int slot = (v & 1) * 17;
      addr = pp * 5168 + rr * 152 + slot * 8;
    }
    *(unsigned long long*)(Lb + addr) = 0ull;
  }

  f32x4 accZ[4][2];
#pragma unroll
  for (int j = 0; j < 4; ++j)
#pragma unroll
    for (int p = 0; p < 2; ++p) accZ[j][p] = (f32x4){NINF, NINF, NINF, NINF};

  const ushort_t* xb = xb16 + (size_t)bn * 32768;

#pragma unroll 1
  for (int ci = 0; ci < 5; ++ci) {
    const int cz = 4*zg - 1 + ci;
    if (cz < 0) continue;
    if (t < 128) {
      const int r = 1 + (t >> 2), g = t & 3;
      const ushort_t* xrow = xb + (r - 1) * 32 + g * 8;
      uint4 u0 = make_uint4(0u, 0u, 0u, 0u), u2 = make_uint4(0u, 0u, 0u, 0u);
      if (cz > 0)  u0 = *(const uint4*)(xrow + (cz - 1) * 1024);
      const uint4 u1 = *(const uint4*)(xrow + cz * 1024);
      if (cz < 31) u2 = *(const uint4*)(xrow + (cz + 1) * 1024);
      char* b0 = Lb + r * 152 + (4 * g + 1) * 8;
      char* b1 = Lb + 5168 + r * 152 + (4 * g + 1) * 8;
      const unsigned* p0 = (const unsigned*)&u0;
      const unsigned* p1 = (const unsigned*)&u1;
      const unsigned* p2 = (const unsigned*)&u2;
#pragma unroll
      for (int e = 0; e < 4; ++e) {
        const unsigned w0 = p0[e], w1 = p1[e], w2v = p2[e];
        const unsigned lo_e = (w0 & 0xFFFFu) | (w1 << 16);
        const unsigned hi_e = (w2v & 0xFFFFu);
        const unsigned lo_o = (w0 >> 16) | (w1 & 0xFFFF0000u);
        const unsigned hi_o = (w2v >> 16);
        *(unsigned long long*)(b0 + e * 8) =
            (unsigned long long)lo_e | ((unsigned long long)hi_e << 32);
        *(unsigned long long*)(b1 + e * 8) =
            (unsigned long long)lo_o | ((unsigned long long)hi_o << 32);
      }
    }
    __syncthreads();
    f32x4 accP0 = (f32x4){NINF, NINF, NINF, NINF};
    f32x4 accP1 = (f32x4){NINF, NINF, NINF, NINF};
#pragma unroll
    for (int yy = 0; yy < 9; ++yy) {
      if (yy == 0 && w == 0) continue;
      const int y = 8 * w - 1 + yy;
      const int rbA = y * 152 + rsel;
      const int rbB = (y + 2) * 152;
      f32x4 Cy;
#pragma unroll
      for (int s = 0; s < 3; ++s) {
        union { unsigned long long u[2]; bf16x8 v; } fA, fB;
        fA.u[0] = *(const unsigned long long*)(Lb + aX1[s] + rbA);
        fA.u[1] = *(const unsigned long long*)(Lb + aX2[s] + rbA);
        fB.u[0] = *(const unsigned long long*)(Lb + aX1[s] + rbB);
        fB.u[1] = *(const unsigned long long*)(Lb + aX2[s] + rbB);
        f32x4 acc = (f32x4){0.f, 0.f, 0.f, 0.f};
        acc = __builtin_amdgcn_mfma_f32_16x16x32_bf16(fA.v, uA.v, acc, 0, 0, 0);
        acc = __builtin_amdgcn_mfma_f32_16x16x32_bf16(fB.v, uB.v, acc, 0, 0, 0);
        if (s == 0) acc[0] = (l < 16) ? NINF : acc[0];
        Cy = (s == 0) ? acc : max4(Cy, acc);
      }
      if (yy & 1) {
        const int c = (yy - 1) / 2;
        if ((c & 1) == 0) accP0 = max4(accP0, Cy); else accP1 = max4(accP1, Cy);
      } else {
        const int cl = yy / 2 - 1;
        const int chh = yy / 2;
        if (cl >= 0) {
          if ((cl & 1) == 0) {
            accP0 = max4(accP0, Cy);
            if (ci <= 2) accZ[cl][0] = max4(accZ[cl][0], accP0);
            if (ci >= 2) accZ[cl][1] = max4(accZ[cl][1], accP0);
            accP0 = (f32x4){NINF, NINF, NINF, NINF};
          } else {
            accP1 = max4(accP1, Cy);
            if (ci <= 2) accZ[cl][0] = max4(accZ[cl][0], accP1);
            if (ci >= 2) accZ[cl][1] = max4(accZ[cl][1], accP1);
            accP1 = (f32x4){NINF, NINF, NINF, NINF};
          }
        }
        if (chh <= 3) {
          if ((chh & 1) == 0) accP0 = max4(accP0, Cy); else accP1 = max4(accP1, Cy);
        }
      }
    }
    __syncthreads();
  }

  const float biasv = bc[ch];
#pragma unroll
  for (int j = 0; j < 4; ++j) {
    const int py = 4 * w + j;
#pragma unroll
    for (int p = 0; p < 2; ++p) {
      const int pz = 2 * zg + p;
      const f32x4 v = accZ[j][p];
      const unsigned lo = (unsigned)f2bf(fmaxf(v[0] + biasv, 0.f)) |
                          ((unsigned)f2bf(fmaxf(v[1] + biasv, 0.f)) << 16);
      const unsigned hi = (unsigned)f2bf(fmaxf(v[2] + biasv, 0.f)) |
                          ((unsigned)f2bf(fmaxf(v[3] + biasv, 0.f)) << 16);
      ushort_t* dst = h1 + (((size_t)(bn * 16 + ch) * 16 + pz) << 8) + py * 16 + grp * 4;
      *(uint2*)dst = make_uint2(lo, hi);
    }
  }
}

// ---------------- K2: conv2 as bf16 MFMA implicit GEMM, quarter-plane ------
// grid 8192 = (bn, oz, yg); block 128 (2 waves; wave = ch-halves). 16 output
// positions (oy = 2yg..2yg+1, ox 0..7). Staging uses dword-pair loads: per
// (ic,dz,dy) two dwords give the 3 taps. LDS 14.6 KB -> ~11 blocks/CU.
__global__ __launch_bounds__(128) void k_conv2(
    const ushort_t* __restrict__ h1, const ushort_t* __restrict__ w2f,
    float* __restrict__ c2)
{
  __shared__ ushort_t As[16 * 456];
  const int b = blockIdx.x;
  const int bn = b >> 5, oz = (b >> 2) & 7, yg = b & 3;
  const int t = threadIdx.x;
  const ushort_t* hb = h1 + ((size_t)bn << 16);
  const int w = t >> 6, l = t & 63;

  bf16x8 bfr[14];
#pragma unroll
  for (int kk = 0; kk < 14; ++kk)
    bfr[kk] = *(const bf16x8*)(const void*)&w2f[(((w * 14) + kk) * 64 + l) * 8];

  for (int idx = t; idx < 256; idx += 128) {
    const int r = idx >> 4, k = 432 + (idx & 15);
    As[r * 456 + k] = 0;
  }

  const int m = t >> 3, sub = t & 7;
  const int oy = 2 * yg + (m >> 3), ox = m & 7;
  ushort_t tv[54];
  int j = 0;
#pragma unroll
  for (int ic2 = 0; ic2 < 2; ++ic2) {
    const ushort_t* icp = hb + ((sub * 2 + ic2) << 12);
#pragma unroll
    for (int dz = 0; dz < 3; ++dz) {
      const int iz = 2 * oz - 1 + dz;
      const bool zok = (unsigned)iz < 16u;
      const unsigned* zp = (const unsigned*)(icp + (iz << 8));
#pragma unroll
      for (int dy = 0; dy < 3; ++dy) {
        const int iy = 2 * oy - 1 + dy;
        const bool yok = zok && ((unsigned)iy < 16u);
        const unsigned* ydw = zp + (iy << 3);
        const unsigned d0 = (yok && ox > 0) ? ydw[ox - 1] : 0u;
        const unsigned d1 = yok ? ydw[ox] : 0u;
        tv[j]     = (ushort_t)(d0 >> 16);       // ix = 2ox-1
        tv[j + 1] = (ushort_t)(d1 & 0xFFFFu);   // ix = 2ox
        tv[j + 2] = (ushort_t)(d1 >> 16);       // ix = 2ox+1
        j += 3;
      }
    }
  }
  {
    unsigned* Aw = (unsigned*)As;
    const int wbase = m * 228 + sub * 27;
#pragma unroll
    for (int p = 0; p < 27; ++p)
      Aw[wbase + p] = (unsigned)tv[2 * p] | ((unsigned)tv[2 * p + 1] << 16);
  }
  __syncthreads();
  f32x4 acc = {0.f, 0.f, 0.f, 0.f};
  const ushort_t* arow = &As[(l & 15) * 456 + ((l >> 4) << 3)];
#pragma unroll
  for (int kk = 0; kk < 14; ++kk) {
    const bf16x8 af = *(const bf16x8*)(const void*)&arow[kk * 32];
    acc = __builtin_amdgcn_mfma_f32_16x16x32_bf16(af, bfr[kk], acc, 0, 0, 0);
  }
  const int n = w * 16 + (l & 15);
  const int m0 = (l >> 4) << 2;
  float* cb = c2 + (((size_t)(bn * 32 + n) * 8) + oz) * 64 + yg * 16 + m0;
  *(float4*)cb = make_float4(acc[0], acc[1], acc[2], acc[3]);
}

// ---------------- K2b: maxpool3 s2 p1 + bias + relu -> feat (bf16) ---------
__global__ __launch_bounds__(256) void k_pool2(
    const float* __restrict__ c2, const float* __restrict__ bc2,
    ushort_t* __restrict__ featb)
{
  const int tid = blockIdx.x * 256 + threadIdx.x;  // 131072
  const int bn = tid >> 9, r = tid & 511;
  const int ch = r >> 4, pz = (r >> 2) & 3, py = r & 3;
  const float* base = c2 + ((size_t)(bn * 32 + ch) << 9);
  float m0 = -1e30f, m1 = -1e30f, m2 = -1e30f, m3 = -1e30f;
#pragma unroll
  for (int dz = 0; dz < 3; ++dz) {
    const int oz = 2 * pz - 1 + dz;
    if ((unsigned)oz >= 8u) continue;
#pragma unroll
    for (int dy = 0; dy < 3; ++dy) {
      const int oy = 2 * py - 1 + dy;
      if ((unsigned)oy >= 8u) continue;
      const float* row = base + (oz << 6) + (oy << 3);
      const float4 a = ((const float4*)row)[0];
      const float4 b = ((const float4*)row)[1];
      m0 = fmaxf(m0, fmaxf(a.x, a.y));
      m1 = fmaxf(m1, fmaxf(a.y, fmaxf(a.z, a.w)));
      m2 = fmaxf(m2, fmaxf(a.w, fmaxf(b.x, b.y)));
      m3 = fmaxf(m3, fmaxf(b.y, fmaxf(b.z, b.w)));
    }
  }
  const float bb = bc2[ch];
  const unsigned lo = (unsigned)f2bf(fmaxf(m0 + bb, 0.f)) |
                      ((unsigned)f2bf(fmaxf(m1 + bb, 0.f)) << 16);
  const unsigned hi = (unsigned)f2bf(fmaxf(m2 + bb, 0.f)) |
                      ((unsigned)f2bf(fmaxf(m3 + bb, 0.f)) << 16);
  *(uint2*)(featb + (size_t)bn * 2048 + r * 4) = make_uint2(lo, hi);
}

// ---------------- bf16 MFMA GEMM, 64x64 tile, K-split + fp32 atomics -------
__global__ __launch_bounds__(256) void k_gemm_bf16(
    const ushort_t* __restrict__ A, const ushort_t* __restrict__ BT,
    float* __restrict__ C, int M, int N, int K, int klen)
{
  (void)M;
  __shared__ ushort_t As[64 * 72];
  __shared__ ushort_t Bs[64 * 72];
  const int jb = blockIdx.x << 6, ib = blockIdx.y << 6;
  const int k0 = blockIdx.z * klen;
  const int t = threadIdx.x, w = t >> 6, l = t & 63;
  const int r0 = t >> 3, kc0 = t & 7;
  f32x4 acc[4];
#pragma unroll
  for (int nt = 0; nt < 4; ++nt) acc[nt] = (f32x4){0.f, 0.f, 0.f, 0.f};

#pragma unroll 1
  for (int kt = 0; kt < klen; kt += 64) {
    __syncthreads();
#pragma unroll
    for (int h = 0; h < 2; ++h) {
      const int row = r0 + h * 32;
      const uint4 va = *(const uint4*)&A[(size_t)(ib + row) * K + k0 + kt + kc0 * 8];
      *(uint4*)&As[row * 72 + kc0 * 8] = va;
      const uint4 vb = *(const uint4*)&BT[(size_t)(jb + row) * K + k0 + kt + kc0 * 8];
      *(uint4*)&Bs[row * 72 + kc0 * 8] = vb;
    }
    __syncthreads();
#pragma unroll
    for (int ks = 0; ks < 2; ++ks) {
      const bf16x8 af = *(const bf16x8*)(const void*)
          &As[(16 * w + (l & 15)) * 72 + ks * 32 + ((l >> 4) << 3)];
#pragma unroll
      for (int nt = 0; nt < 4; ++nt) {
        const bf16x8 bf = *(const bf16x8*)(const void*)
            &Bs[(nt * 16 + (l & 15)) * 72 + ks * 32 + ((l >> 4) << 3)];
        acc[nt] = __builtin_amdgcn_mfma_f32_16x16x32_bf16(af, bf, acc[nt], 0, 0, 0);
      }
    }
  }
  const int mrow = ib + 16 * w + ((l >> 4) << 2);
#pragma unroll
  for (int nt = 0; nt < 4; ++nt) {
    const int col = jb + nt * 16 + (l & 15);
#pragma unroll
    for (int r = 0; r < 4; ++r)
      atomicAdd(&C[(size_t)(mrow + r) * N + col], acc[nt][r]);
  }
}

// ---------------- G = (An_b @ T_b) + bias; bf16 out if Gb, else fp32 -------
__global__ __launch_bounds__(256) void k_graph_mm(
    const float* __restrict__ An, const float* __restrict__ T,
    const float* __restrict__ bias, float* __restrict__ Gf,
    ushort_t* __restrict__ Gb, int F, int relu)
{
  const int b = blockIdx.y;
  const int f0 = blockIdx.x << 6;
  __shared__ float Ans[64 * 65];
  __shared__ float Ts[64 * 64];
  const int t = threadIdx.x;
  for (int idx = t; idx < 4096; idx += 256)
    Ans[(idx >> 6) * 65 + (idx & 63)] = An[b * 4096 + idx];
  for (int idx = t; idx < 1024; idx += 256) {
    const int j = idx >> 4, q = idx & 15;
    *(float4*)&Ts[j * 64 + 4 * q] = *(const float4*)&T[(size_t)(b * 64 + j) * F + f0 + 4 * q];
  }
  __syncthreads();
  const int i = t >> 2, fq = t & 3;
  float4 a0 = {0,0,0,0}, a1 = {0,0,0,0}, a2 = {0,0,0,0}, a3 = {0,0,0,0};
#pragma unroll 1
  for (int j = 0; j < 64; ++j) {
    const float aij = Ans[i * 65 + j];
    const float4* tr = (const float4*)&Ts[j * 64 + fq * 16];
    const float4 v0 = tr[0], v1 = tr[1], v2 = tr[2], v3 = tr[3];
    a0.x += aij * v0.x; a0.y += aij * v0.y; a0.z += aij * v0.z; a0.w += aij * v0.w;
    a1.x += aij * v1.x; a1.y += aij * v1.y; a1.z += aij * v1.z; a1.w += aij * v1.w;
    a2.x += aij * v2.x; a2.y += aij * v2.y; a2.z += aij * v2.z; a2.w += aij * v2.w;
    a3.x += aij * v3.x; a3.y += aij * v3.y; a3.z += aij * v3.z; a3.w += aij * v3.w;
  }
  float acc[16];
  *(float4*)&acc[0] = a0; *(float4*)&acc[4] = a1;
  *(float4*)&acc[8] = a2; *(float4*)&acc[12] = a3;
  const float* br = bias + f0 + fq * 16;
  if (Gb) {
    ushort_t* gr = Gb + (size_t)(b * 64 + i) * F + f0 + fq * 16;
#pragma unroll
    for (int u = 0; u < 16; ++u) {
      float v = acc[u] + br[u];
      if (relu) v = fmaxf(v, 0.f);
      gr[u] = f2bf(v);
    }
  } else {
    float* gr = Gf + (size_t)(b * 64 + i) * F + f0 + fq * 16;
#pragma unroll
    for (int u = 0; u < 16; ++u) {
      float v = acc[u] + br[u];
      if (relu) v = fmaxf(v, 0.f);
      gr[u] = v;
    }
  }
}

// ---------------- head: chunk-max + fc1 + relu + fc2 + softmax -------------
__global__ __launch_bounds__(256) void k_head(
    const float* __restrict__ g3, const float* __restrict__ w1, const float* __restrict__ b1,
    const float* __restrict__ w2, const float* __restrict__ b2, float* __restrict__ out)
{
  const int b = blockIdx.x, t = threadIdx.x;
  __shared__ float sp[256];
  __shared__ float sh[512];
  __shared__ float sl[4];
  {
    const int n = t >> 2, c = t & 3;
    const float* gr = g3 + (size_t)(b * 64 + n) * 256 + c * 64;
    float mx = -1e30f;
    for (int f = 0; f < 64; ++f) mx = fmaxf(mx, gr[f]);
    sp[t] = mx;
  }
  __syncthreads();
  for (int jj = t; jj < 512; jj += 256) {
    float s = b1[jj];
    for (int k = 0; k < 256; ++k) s += sp[k] * w1[k * 512 + jj];
    sh[jj] = fmaxf(s, 0.f);
  }
  __syncthreads();
  if (t < 4) {
    float s = b2[t];
    for (int k = 0; k < 512; ++k) s += sh[k] * w2[k * 4 + t];
    sl[t] = s;
  }
  __syncthreads();
  if (t == 0) {
    const float mm = fmaxf(fmaxf(sl[0], sl[1]), fmaxf(sl[2], sl[3]));
    const float e0 = expf(sl[0] - mm), e1 = expf(sl[1] - mm);
    const float e2 = expf(sl[2] - mm), e3 = expf(sl[3] - mm);
    const float inv = 1.f / (e0 + e1 + e2 + e3);
    out[b * 4 + 0] = e0 * inv;
    out[b * 4 + 1] = e1 * inv;
    out[b * 4 + 2] = e2 * inv;
    out[b * 4 + 3] = e3 * inv;
  }
}

// ---------------------------------------------------------------------------
extern "C" void kernel_launch(void* const* d_in, const int* in_sizes, int n_in,
                              void* d_out, int out_size, void* d_ws, size_t ws_size,
                              hipStream_t stream)
{
  (void)in_sizes; (void)n_in; (void)out_size; (void)ws_size;
  const float* x   = (const float*)d_in[0];
  const int*   adj = (const int*)d_in[1];
  const float* wc1 = (const float*)d_in[3];
  const float* bc1 = (const float*)d_in[4];
  const float* wc2 = (const float*)d_in[5];
  const float* bc2 = (const float*)d_in[6];
  const float* wg1 = (const float*)d_in[7];
  const float* bg1 = (const float*)d_in[8];
  const float* wg2 = (const float*)d_in[9];
  const float* bg2 = (const float*)d_in[10];
  const float* wg3 = (const float*)d_in[11];
  const float* bg3 = (const float*)d_in[12];
  const float* wf1 = (const float*)d_in[13];
  const float* bf1 = (const float*)d_in[14];
  const float* wf2 = (const float*)d_in[15];
  const float* bf2 = (const float*)d_in[16];

  float* ws    = (float*)d_ws;
  ushort_t* h1 = (ushort_t*)d_ws;
  ushort_t* w2f   = (ushort_t*)(ws + 8388608);
  ushort_t* wg1Tb = (ushort_t*)(ws + 8395776);
  ushort_t* wg2Tb = (ushort_t*)(ws + 9444352);
  ushort_t* wg3Tb = (ushort_t*)(ws + 9706496);
  ushort_t* featb = (ushort_t*)(ws + 9772032);
  ushort_t* g1b   = (ushort_t*)(ws + 10034176);
  ushort_t* g2b   = (ushort_t*)(ws + 10165248);
  float* c2    = ws + 16777216;
  ushort_t* xb16 = (ushort_t*)(ws + 16777216);   // aliases c2 (consumed pre-conv2)
  float* An   = ws + 21495808;
  float* t1   = ws + 21512192;
  float* t2   = ws + 21774336;
  float* t3   = ws + 21905408;
  float* g3   = ws + 22364160;
  float* outp = (float*)d_out;

  hipLaunchKernelGGL(k_prep,        dim3(12732),    dim3(256), 0, stream,
                     x, xb16, t1, wc2, w2f, wg1, wg1Tb, wg2, wg2Tb, wg3, wg3Tb, adj, An);
  hipLaunchKernelGGL(k_conv1_mfma,  dim3(2048),     dim3(256), 0, stream, xb16, wc1, bc1, h1);
  hipLaunchKernelGGL(k_conv2,       dim3(8192),     dim3(128), 0, stream, h1, w2f, c2);
  hipLaunchKernelGGL(k_pool2,       dim3(512),      dim3(256), 0, stream, c2, bc2, featb);
  hipLaunchKernelGGL(k_gemm_bf16,   dim3(16,4,4),   dim3(256), 0, stream, featb, wg1Tb, t1, 256, 1024, 2048, 512);
  hipLaunchKernelGGL(k_graph_mm,    dim3(16,4),     dim3(256), 0, stream, An, t1, bg1, (float*)nullptr, g1b, 1024, 1);
  hipLaunchKernelGGL(k_gemm_bf16,   dim3(8,4,4),    dim3(256), 0, stream, g1b, wg2Tb, t2, 256, 512, 1024, 256);
  hipLaunchKernelGGL(k_graph_mm,    dim3(8,4),      dim3(256), 0, stream, An, t2, bg2, (float*)nullptr, g2b, 512, 1);
  hipLaunchKernelGGL(k_gemm_bf16,   dim3(4,4,4),    dim3(256), 0, stream, g2b, wg3Tb, t3, 256, 256, 512, 128);
  hipLaunchKernelGGL(k_graph_mm,    dim3(4,4),      dim3(256), 0, stream, An, t3, bg3, g3, (ushort_t*)nullptr, 256, 0);
  hipLaunchKernelGGL(k_head,        dim3(4),        dim3(256), 0, stream, g3, wf1, bf1, wf2, bf2, outp);
}

// Round 8
// 288.676 us; speedup vs baseline: 3.9945x; 1.0677x over previous
//
#include <hip/hip_runtime.h>

typedef unsigned short ushort_t;
typedef __attribute__((ext_vector_type(8))) short bf16x8;
typedef __attribute__((ext_vector_type(4))) float f32x4;

static __device__ __forceinline__ unsigned short f2bf(float f) {
  unsigned u = __float_as_uint(f);
  u = (u + 0x7FFFu + ((u >> 16) & 1u)) >> 16;
  return (unsigned short)u;
}

static __device__ __forceinline__ f32x4 max4(f32x4 a, f32x4 b) {
  f32x4 r;
  r[0] = fmaxf(a[0], b[0]); r[1] = fmaxf(a[1], b[1]);
  r[2] = fmaxf(a[2], b[2]); r[3] = fmaxf(a[3], b[3]);
  return r;
}

// ---------------------------------------------------------------------------
// Workspace layout (fp32-element offsets):
//   h1    @ 0          : 16777216 ushorts
//   w2f   @ 8388608    : 14336 ushorts (conv2 weight frags)
//   wg1Tb @ 8395776    : 1024x2048 ushorts
//   wg2Tb @ 9444352    : 512x1024 ushorts
//   wg3Tb @ 9706496    : 256x512 ushorts
//   featb @ 9772032    : 256x2048 ushorts
//   g1b   @ 10034176   : 256x1024 ushorts
//   g2b   @ 10165248   : 256x512 ushorts
//   c2    @ 16777216   : 4194304 floats   (ALIASED: xb16, consumed pre-conv2)
//   An    @ 21495808   : 4*64*64
//   g3    @ 22364160   : 256*256
// ---------------------------------------------------------------------------

// ---------------- fused prep: x2bf | w2f | 3x transpose | gcn_norm ---------
// grid 10940 = 8192 + 56 + 2048 + 512 + 128 + 4, block 256.
__device__ __forceinline__ void prep_transpose(
    const float* __restrict__ W, ushort_t* __restrict__ out,
    int K, int N, int n0, int k0, int t, float (*tile)[33])
{
  const int tx = t & 31, ty = t >> 5;
#pragma unroll
  for (int i = 0; i < 4; ++i) {
    const int k = k0 + ty + i * 8;
    tile[ty + i * 8][tx] = W[(size_t)k * N + n0 + tx];
  }
  __syncthreads();
#pragma unroll
  for (int i = 0; i < 4; ++i) {
    const int n = n0 + ty + i * 8;
    out[(size_t)n * K + k0 + tx] = f2bf(tile[tx][ty + i * 8]);
  }
}

__global__ __launch_bounds__(256) void k_prep(
    const float* __restrict__ x, ushort_t* __restrict__ xb16,
    const float* __restrict__ w2, ushort_t* __restrict__ w2f,
    const float* __restrict__ wg1, ushort_t* __restrict__ wg1T,
    const float* __restrict__ wg2, ushort_t* __restrict__ wg2T,
    const float* __restrict__ wg3, ushort_t* __restrict__ wg3T,
    const int* __restrict__ adj, float* __restrict__ An)
{
  __shared__ float tile[32][33];
  __shared__ float dinv[64];
  __shared__ int part[256];
  int b = blockIdx.x;
  const int t = threadIdx.x;
  if (b < 8192) {                       // x -> bf16
    const int tid = b * 256 + t;
    const float4 v = ((const float4*)x)[tid];
    const unsigned lo = (unsigned)f2bf(v.x) | ((unsigned)f2bf(v.y) << 16);
    const unsigned hi = (unsigned)f2bf(v.z) | ((unsigned)f2bf(v.w) << 16);
    ((uint2*)xb16)[tid] = make_uint2(lo, hi);
    return;
  }
  b -= 8192;
  if (b < 56) {                         // conv2 weight frags
    const int tid = b * 256 + t;
    if (tid < 14336) {
      const int nt = tid / 7168, rem = tid % 7168;
      const int kk = rem / 512, rem2 = rem % 512;
      const int l = rem2 >> 3, j = rem2 & 7;
      const int n = nt * 16 + (l & 15);
      const int k = (l >> 4) * 8 + kk * 32 + j;
      float v = 0.f;
      if (k < 432) v = w2[n * 432 + k];
      w2f[tid] = f2bf(v);
    }
    return;
  }
  b -= 56;
  if (b < 2048) { prep_transpose(wg1, wg1T, 2048, 1024, (b & 31) << 5, (b >> 5) << 5, t, tile); return; }
  b -= 2048;
  if (b < 512)  { prep_transpose(wg2, wg2T, 1024, 512,  (b & 15) << 5, (b >> 4) << 5, t, tile); return; }
  b -= 512;
  if (b < 128)  { prep_transpose(wg3, wg3T, 512,  256,  (b & 7)  << 5, (b >> 3) << 5, t, tile); return; }
  b -= 128;
  {                                     // gcn_norm, b in [0,4)
    const int i = t >> 2, q = t & 3;
    const int* ab = adj + b * 4096 + i * 64 + q * 16;
    int d = 0;
#pragma unroll
    for (int j = 0; j < 16; ++j) d += (ab[j] != 0) ? 1 : 0;
    part[t] = d;
    __syncthreads();
    if (q == 0)
      dinv[i] = rsqrtf((float)(1 + part[t] + part[t + 1] + part[t + 2] + part[t + 3]));
    __syncthreads();
    for (int idx = t; idx < 4096; idx += 256) {
      const int ii = idx >> 6, jj = idx & 63;
      const float a = (ii == jj) ? 1.f : ((adj[b * 4096 + idx] != 0) ? 1.f : 0.f);
      An[b * 4096 + idx] = a * dinv[ii] * dinv[jj];
    }
  }
}

// ---------------- K1: conv1 + maxpool3 as bf16 MFMA "pooled-direct" --------
__global__ __launch_bounds__(256) void k_conv1_mfma(
    const ushort_t* __restrict__ xb16, const float* __restrict__ wc,
    const float* __restrict__ bc, ushort_t* __restrict__ h1)
{
  __shared__ ushort_t L[2 * 34 * 76];
  char* Lb = (char*)L;
  const int bn = blockIdx.x >> 3, zg = blockIdx.x & 7;
  const int t = threadIdx.x;
  const int w = t >> 6, l = t & 63;
  const int grp = l >> 4, m = l & 15, ch = l & 15;
  const float NINF = -1e30f;

  union { short s[8]; bf16x8 v; } uA, uB;
#pragma unroll
  for (int j = 0; j < 8; ++j) {
    const int k = grp * 8 + j;
    float wA = 0.f, wB = 0.f;
    if (k < 12) {
      const int dx = k >> 2, dz = k & 3;
      if (dz < 3) { wA = wc[ch*27 + dz*9 + 0 + dx]; wB = wc[ch*27 + dz*9 + 6 + dx]; }
    } else if (k >= 16 && k < 28) {
      const int kk = k - 16, dx = kk >> 2, dz = kk & 3;
      if (dz < 3) wA = wc[ch*27 + dz*9 + 3 + dx];
    }
    uA.s[j] = (short)f2bf(wA);
    uB.s[j] = (short)f2bf(wB);
  }

  int aX1[3], aX2[3];
#pragma unroll
  for (int s = 0; s < 3; ++s) {
    const int Q1 = 2*m + s + 2*(grp & 1);
    const int Q2 = Q1 + 1;
    aX1[s] = (Q1 & 1) * 5168 + (Q1 >> 1) * 8;
    aX2[s] = (Q2 & 1) * 5168 + (Q2 >> 1) * 8;
  }
  const int rsel = (grp >> 1) * 152;

  for (int u = t; u < 200; u += 256) {
    int addr;
    if (u < 72) {
      const int rr = (u < 36) ? 0 : 33;
      const int s = (u < 36) ? u : u - 36;
      const int pp = s / 18, slot = s - pp * 18;
      addr = pp * 5168 + rr * 152 + slot * 8;
    } else {
      const int v = u - 72;
      const int rr = 1 + (v >> 2);
      const int pp = (v >> 1) & 1;
      const int slot = (v & 1) * 17;
      addr = pp * 5168 + rr * 152 + slot * 8;
    }
    *(unsigned long long*)(Lb + addr) = 0ull;
  }

  f32x4 accZ[4][2];
#pragma unroll
  for (int j = 0; j < 4; ++j)
#pragma unroll
    for (int p = 0; p < 2; ++p) accZ[j][p] = (f32x4){NINF, NINF, NINF, NINF};

  const ushort_t* xb = xb16 + (size_t)bn * 32768;

#pragma unroll 1
  for (int ci = 0; ci < 5; ++ci) {
    const int cz = 4*zg - 1 + ci;
    if (cz < 0) continue;
    if (t < 128) {
      const int r = 1 + (t >> 2), g = t & 3;
      const ushort_t* xrow = xb + (r - 1) * 32 + g * 8;
      uint4 u0 = make_uint4(0u, 0u, 0u, 0u), u2 = make_uint4(0u, 0u, 0u, 0u);
      if (cz > 0)  u0 = *(const uint4*)(xrow + (cz - 1) * 1024);
      const uint4 u1 = *(const uint4*)(xrow + cz * 1024);
      if (cz < 31) u2 = *(const uint4*)(xrow + (cz + 1) * 1024);
      char* b0 = Lb + r * 152 + (4 * g + 1) * 8;
      char* b1 = Lb + 5168 + r * 152 + (4 * g + 1) * 8;
      const unsigned* p0 = (const unsigned*)&u0;
      const unsigned* p1 = (const unsigned*)&u1;
      const unsigned* p2 = (const unsigned*)&u2;
#pragma unroll
      for (int e = 0; e < 4; ++e) {
        const unsigned w0 = p0[e], w1 = p1[e], w2v = p2[e];
        const unsigned lo_e = (w0 & 0xFFFFu) | (w1 << 16);
        const unsigned hi_e = (w2v & 0xFFFFu);
        const unsigned lo_o = (w0 >> 16) | (w1 & 0xFFFF0000u);
        const unsigned hi_o = (w2v >> 16);
        *(unsigned long long*)(b0 + e * 8) =
            (unsigned long long)lo_e | ((unsigned long long)hi_e << 32);
        *(unsigned long long*)(b1 + e * 8) =
            (unsigned long long)lo_o | ((unsigned long long)hi_o << 32);
      }
    }
    __syncthreads();
    f32x4 accP0 = (f32x4){NINF, NINF, NINF, NINF};
    f32x4 accP1 = (f32x4){NINF, NINF, NINF, NINF};
#pragma unroll
    for (int yy = 0; yy < 9; ++yy) {
      if (yy == 0 && w == 0) continue;
      const int y = 8 * w - 1 + yy;
      const int rbA = y * 152 + rsel;
      const int rbB = (y + 2) * 152;
      f32x4 Cy;
#pragma unroll
      for (int s = 0; s < 3; ++s) {
        union { unsigned long long u[2]; bf16x8 v; } fA, fB;
        fA.u[0] = *(const unsigned long long*)(Lb + aX1[s] + rbA);
        fA.u[1] = *(const unsigned long long*)(Lb + aX2[s] + rbA);
        fB.u[0] = *(const unsigned long long*)(Lb + aX1[s] + rbB);
        fB.u[1] = *(const unsigned long long*)(Lb + aX2[s] + rbB);
        f32x4 acc = (f32x4){0.f, 0.f, 0.f, 0.f};
        acc = __builtin_amdgcn_mfma_f32_16x16x32_bf16(fA.v, uA.v, acc, 0, 0, 0);
        acc = __builtin_amdgcn_mfma_f32_16x16x32_bf16(fB.v, uB.v, acc, 0, 0, 0);
        if (s == 0) acc[0] = (l < 16) ? NINF : acc[0];
        Cy = (s == 0) ? acc : max4(Cy, acc);
      }
      if (yy & 1) {
        const int c = (yy - 1) / 2;
        if ((c & 1) == 0) accP0 = max4(accP0, Cy); else accP1 = max4(accP1, Cy);
      } else {
        const int cl = yy / 2 - 1;
        const int chh = yy / 2;
        if (cl >= 0) {
          if ((cl & 1) == 0) {
            accP0 = max4(accP0, Cy);
            if (ci <= 2) accZ[cl][0] = max4(accZ[cl][0], accP0);
            if (ci >= 2) accZ[cl][1] = max4(accZ[cl][1], accP0);
            accP0 = (f32x4){NINF, NINF, NINF, NINF};
          } else {
            accP1 = max4(accP1, Cy);
            if (ci <= 2) accZ[cl][0] = max4(accZ[cl][0], accP1);
            if (ci >= 2) accZ[cl][1] = max4(accZ[cl][1], accP1);
            accP1 = (f32x4){NINF, NINF, NINF, NINF};
          }
        }
        if (chh <= 3) {
          if ((chh & 1) == 0) accP0 = max4(accP0, Cy); else accP1 = max4(accP1, Cy);
        }
      }
    }
    __syncthreads();
  }

  const float biasv = bc[ch];
#pragma unroll
  for (int j = 0; j < 4; ++j) {
    const int py = 4 * w + j;
#pragma unroll
    for (int p = 0; p < 2; ++p) {
      const int pz = 2 * zg + p;
      const f32x4 v = accZ[j][p];
      const unsigned lo = (unsigned)f2bf(fmaxf(v[0] + biasv, 0.f)) |
                          ((unsigned)f2bf(fmaxf(v[1] + biasv, 0.f)) << 16);
      const unsigned hi = (unsigned)f2bf(fmaxf(v[2] + biasv, 0.f)) |
                          ((unsigned)f2bf(fmaxf(v[3] + biasv, 0.f)) << 16);
      ushort_t* dst = h1 + (((size_t)(bn * 16 + ch) * 16 + pz) << 8) + py * 16 + grp * 4;
      *(uint2*)dst = make_uint2(lo, hi);
    }
  }
}

// ---------------- K2: conv2 as bf16 MFMA implicit GEMM, quarter-plane ------
__global__ __launch_bounds__(128) void k_conv2(
    const ushort_t* __restrict__ h1, const ushort_t* __restrict__ w2f,
    float* __restrict__ c2)
{
  __shared__ ushort_t As[16 * 456];
  const int b = blockIdx.x;
  const int bn = b >> 5, oz = (b >> 2) & 7, yg = b & 3;
  const int t = threadIdx.x;
  const ushort_t* hb = h1 + ((size_t)bn << 16);
  const int w = t >> 6, l = t & 63;

  bf16x8 bfr[14];
#pragma unroll
  for (int kk = 0; kk < 14; ++kk)
    bfr[kk] = *(const bf16x8*)(const void*)&w2f[(((w * 14) + kk) * 64 + l) * 8];

  for (int idx = t; idx < 256; idx += 128) {
    const int r = idx >> 4, k = 432 + (idx & 15);
    As[r * 456 + k] = 0;
  }

  const int m = t >> 3, sub = t & 7;
  const int oy = 2 * yg + (m >> 3), ox = m & 7;
  ushort_t tv[54];
  int j = 0;
#pragma unroll
  for (int ic2 = 0; ic2 < 2; ++ic2) {
    const ushort_t* icp = hb + ((sub * 2 + ic2) << 12);
#pragma unroll
    for (int dz = 0; dz < 3; ++dz) {
      const int iz = 2 * oz - 1 + dz;
      const bool zok = (unsigned)iz < 16u;
      const unsigned* zp = (const unsigned*)(icp + (iz << 8));
#pragma unroll
      for (int dy = 0; dy < 3; ++dy) {
        const int iy = 2 * oy - 1 + dy;
        const bool yok = zok && ((unsigned)iy < 16u);
        const unsigned* ydw = zp + (iy << 3);
        const unsigned d0 = (yok && ox > 0) ? ydw[ox - 1] : 0u;
        const unsigned d1 = yok ? ydw[ox] : 0u;
        tv[j]     = (ushort_t)(d0 >> 16);
        tv[j + 1] = (ushort_t)(d1 & 0xFFFFu);
        tv[j + 2] = (ushort_t)(d1 >> 16);
        j += 3;
      }
    }
  }
  {
    unsigned* Aw = (unsigned*)As;
    const int wbase = m * 228 + sub * 27;
#pragma unroll
    for (int p = 0; p < 27; ++p)
      Aw[wbase + p] = (unsigned)tv[2 * p] | ((unsigned)tv[2 * p + 1] << 16);
  }
  __syncthreads();
  f32x4 acc = {0.f, 0.f, 0.f, 0.f};
  const ushort_t* arow = &As[(l & 15) * 456 + ((l >> 4) << 3)];
#pragma unroll
  for (int kk = 0; kk < 14; ++kk) {
    const bf16x8 af = *(const bf16x8*)(const void*)&arow[kk * 32];
    acc = __builtin_amdgcn_mfma_f32_16x16x32_bf16(af, bfr[kk], acc, 0, 0, 0);
  }
  const int n = w * 16 + (l & 15);
  const int m0 = (l >> 4) << 2;
  float* cb = c2 + (((size_t)(bn * 32 + n) * 8) + oz) * 64 + yg * 16 + m0;
  *(float4*)cb = make_float4(acc[0], acc[1], acc[2], acc[3]);
}

// ---------------- K2b: maxpool3 s2 p1 + bias + relu -> feat (bf16) ---------
__global__ __launch_bounds__(256) void k_pool2(
    const float* __restrict__ c2, const float* __restrict__ bc2,
    ushort_t* __restrict__ featb)
{
  const int tid = blockIdx.x * 256 + threadIdx.x;  // 131072
  const int bn = tid >> 9, r = tid & 511;
  const int ch = r >> 4, pz = (r >> 2) & 3, py = r & 3;
  const float* base = c2 + ((size_t)(bn * 32 + ch) << 9);
  float m0 = -1e30f, m1 = -1e30f, m2 = -1e30f, m3 = -1e30f;
#pragma unroll
  for (int dz = 0; dz < 3; ++dz) {
    const int oz = 2 * pz - 1 + dz;
    if ((unsigned)oz >= 8u) continue;
#pragma unroll
    for (int dy = 0; dy < 3; ++dy) {
      const int oy = 2 * py - 1 + dy;
      if ((unsigned)oy >= 8u) continue;
      const float* row = base + (oz << 6) + (oy << 3);
      const float4 a = ((const float4*)row)[0];
      const float4 b = ((const float4*)row)[1];
      m0 = fmaxf(m0, fmaxf(a.x, a.y));
      m1 = fmaxf(m1, fmaxf(a.y, fmaxf(a.z, a.w)));
      m2 = fmaxf(m2, fmaxf(a.w, fmaxf(b.x, b.y)));
      m3 = fmaxf(m3, fmaxf(b.y, fmaxf(b.z, b.w)));
    }
  }
  const float bb = bc2[ch];
  const unsigned lo = (unsigned)f2bf(fmaxf(m0 + bb, 0.f)) |
                      ((unsigned)f2bf(fmaxf(m1 + bb, 0.f)) << 16);
  const unsigned hi = (unsigned)f2bf(fmaxf(m2 + bb, 0.f)) |
                      ((unsigned)f2bf(fmaxf(m3 + bb, 0.f)) << 16);
  *(uint2*)(featb + (size_t)bn * 2048 + r * 4) = make_uint2(lo, hi);
}

// ---------------- fused GCN layer: out = [relu](A_norm @ (X W) + b) --------
// grid (N/64, 4 graphs); block 256 (4 waves). Phase 1: full-K P = X[b]@W
// (64x64 tile, MFMA). Phase 2: P -> LDS transposed bf16, A_norm-frags from
// global, 2 chained MFMAs per ntile, bias/relu fused store (bf16 or fp32).
__global__ __launch_bounds__(256) void k_gcn_layer(
    const ushort_t* __restrict__ Xb, const ushort_t* __restrict__ WT,
    const float* __restrict__ bias, const float* __restrict__ An,
    ushort_t* __restrict__ Ob, float* __restrict__ Of, int K, int N, int relu)
{
  __shared__ ushort_t As[64 * 72];
  __shared__ ushort_t Bs[64 * 72];
  __shared__ ushort_t Ps[64 * 72];   // P transposed: Ps[n][k-node]
  const int b = blockIdx.y, jb = blockIdx.x << 6;
  const int t = threadIdx.x, w = t >> 6, l = t & 63;
  const int r0 = t >> 3, kc0 = t & 7;
  const int lm = l & 15, lg = l >> 4;

  // A_norm fragments for out-rows 16w..16w+15 (m = lm), K=64 in 2 chunks
  union { short s[8]; bf16x8 v; } afr[2];
  {
    const float* ap = An + b * 4096 + (16 * w + lm) * 64 + (lg << 3);
#pragma unroll
    for (int kc = 0; kc < 2; ++kc) {
      const float4 v0 = *(const float4*)(ap + kc * 32);
      const float4 v1 = *(const float4*)(ap + kc * 32 + 4);
      afr[kc].s[0] = (short)f2bf(v0.x); afr[kc].s[1] = (short)f2bf(v0.y);
      afr[kc].s[2] = (short)f2bf(v0.z); afr[kc].s[3] = (short)f2bf(v0.w);
      afr[kc].s[4] = (short)f2bf(v1.x); afr[kc].s[5] = (short)f2bf(v1.y);
      afr[kc].s[6] = (short)f2bf(v1.z); afr[kc].s[7] = (short)f2bf(v1.w);
    }
  }

  f32x4 acc[4];
#pragma unroll
  for (int nt = 0; nt < 4; ++nt) acc[nt] = (f32x4){0.f, 0.f, 0.f, 0.f};

  // ---- Phase 1: P = X[b] @ W[:, jb:jb+64], full K ----
#pragma unroll 1
  for (int kt = 0; kt < K; kt += 64) {
    __syncthreads();
#pragma unroll
    for (int h = 0; h < 2; ++h) {
      const int row = r0 + h * 32;
      const uint4 va = *(const uint4*)&Xb[(size_t)(b * 64 + row) * K + kt + kc0 * 8];
      *(uint4*)&As[row * 72 + kc0 * 8] = va;
      const uint4 vb = *(const uint4*)&WT[(size_t)(jb + row) * K + kt + kc0 * 8];
      *(uint4*)&Bs[row * 72 + kc0 * 8] = vb;
    }
    __syncthreads();
#pragma unroll
    for (int ks = 0; ks < 2; ++ks) {
      const bf16x8 af = *(const bf16x8*)(const void*)
          &As[(16 * w + lm) * 72 + ks * 32 + (lg << 3)];
#pragma unroll
      for (int nt = 0; nt < 4; ++nt) {
        const bf16x8 bf = *(const bf16x8*)(const void*)
            &Bs[(nt * 16 + lm) * 72 + ks * 32 + (lg << 3)];
        acc[nt] = __builtin_amdgcn_mfma_f32_16x16x32_bf16(af, bf, acc[nt], 0, 0, 0);
      }
    }
  }

  // ---- P -> Ps (transposed, bf16): Ps[n][node] ----
  const int m0 = lg << 2;
#pragma unroll
  for (int nt = 0; nt < 4; ++nt) {
    const int n = nt * 16 + lm;
    const unsigned lo = (unsigned)f2bf(acc[nt][0]) | ((unsigned)f2bf(acc[nt][1]) << 16);
    const unsigned hi = (unsigned)f2bf(acc[nt][2]) | ((unsigned)f2bf(acc[nt][3]) << 16);
    *(uint2*)&Ps[n * 72 + 16 * w + m0] = make_uint2(lo, hi);
  }
  __syncthreads();

  // ---- Phase 2: out = A @ P (+bias, relu) ----
#pragma unroll
  for (int nt = 0; nt < 4; ++nt) {
    const bf16x8 b0 = *(const bf16x8*)(const void*)&Ps[(nt * 16 + lm) * 72 + (lg << 3)];
    const bf16x8 b1 = *(const bf16x8*)(const void*)&Ps[(nt * 16 + lm) * 72 + 32 + (lg << 3)];
    f32x4 a2 = (f32x4){0.f, 0.f, 0.f, 0.f};
    a2 = __builtin_amdgcn_mfma_f32_16x16x32_bf16(afr[0].v, b0, a2, 0, 0, 0);
    a2 = __builtin_amdgcn_mfma_f32_16x16x32_bf16(afr[1].v, b1, a2, 0, 0, 0);
    const int col = jb + nt * 16 + lm;
    const float bv = bias[col];
#pragma unroll
    for (int r = 0; r < 4; ++r) {
      const int row = b * 64 + 16 * w + m0 + r;
      float v = a2[r] + bv;
      if (relu) v = fmaxf(v, 0.f);
      if (Ob) Ob[(size_t)row * N + col] = f2bf(v);
      else    Of[(size_t)row * N + col] = v;
    }
  }
}

// ---------------- head: chunk-max + fc1 + relu + fc2 + softmax -------------
__global__ __launch_bounds__(256) void k_head(
    const float* __restrict__ g3, const float* __restrict__ w1, const float* __restrict__ b1,
    const float* __restrict__ w2, const float* __restrict__ b2, float* __restrict__ out)
{
  const int b = blockIdx.x, t = threadIdx.x;
  __shared__ float sp[256];
  __shared__ float sh[512];
  __shared__ float sl[4];
  {
    const int n = t >> 2, c = t & 3;
    const float* gr = g3 + (size_t)(b * 64 + n) * 256 + c * 64;
    float mx = -1e30f;
    for (int f = 0; f < 64; ++f) mx = fmaxf(mx, gr[f]);
    sp[t] = mx;
  }
  __syncthreads();
  for (int jj = t; jj < 512; jj += 256) {
    float s = b1[jj];
    for (int k = 0; k < 256; ++k) s += sp[k] * w1[k * 512 + jj];
    sh[jj] = fmaxf(s, 0.f);
  }
  __syncthreads();
  if (t < 4) {
    float s = b2[t];
    for (int k = 0; k < 512; ++k) s += sh[k] * w2[k * 4 + t];
    sl[t] = s;
  }
  __syncthreads();
  if (t == 0) {
    const float mm = fmaxf(fmaxf(sl[0], sl[1]), fmaxf(sl[2], sl[3]));
    const float e0 = expf(sl[0] - mm), e1 = expf(sl[1] - mm);
    const float e2 = expf(sl[2] - mm), e3 = expf(sl[3] - mm);
    const float inv = 1.f / (e0 + e1 + e2 + e3);
    out[b * 4 + 0] = e0 * inv;
    out[b * 4 + 1] = e1 * inv;
    out[b * 4 + 2] = e2 * inv;
    out[b * 4 + 3] = e3 * inv;
  }
}

// ---------------------------------------------------------------------------
extern "C" void kernel_launch(void* const* d_in, const int* in_sizes, int n_in,
                              void* d_out, int out_size, void* d_ws, size_t ws_size,
                              hipStream_t stream)
{
  (void)in_sizes; (void)n_in; (void)out_size; (void)ws_size;
  const float* x   = (const float*)d_in[0];
  const int*   adj = (const int*)d_in[1];
  const float* wc1 = (const float*)d_in[3];
  const float* bc1 = (const float*)d_in[4];
  const float* wc2 = (const float*)d_in[5];
  const float* bc2 = (const float*)d_in[6];
  const float* wg1 = (const float*)d_in[7];
  const float* bg1 = (const float*)d_in[8];
  const float* wg2 = (const float*)d_in[9];
  const float* bg2 = (const float*)d_in[10];
  const float* wg3 = (const float*)d_in[11];
  const float* bg3 = (const float*)d_in[12];
  const float* wf1 = (const float*)d_in[13];
  const float* bf1 = (const float*)d_in[14];
  const float* wf2 = (const float*)d_in[15];
  const float* bf2 = (const float*)d_in[16];

  float* ws    = (float*)d_ws;
  ushort_t* h1 = (ushort_t*)d_ws;
  ushort_t* w2f   = (ushort_t*)(ws + 8388608);
  ushort_t* wg1Tb = (ushort_t*)(ws + 8395776);
  ushort_t* wg2Tb = (ushort_t*)(ws + 9444352);
  ushort_t* wg3Tb = (ushort_t*)(ws + 9706496);
  ushort_t* featb = (ushort_t*)(ws + 9772032);
  ushort_t* g1b   = (ushort_t*)(ws + 10034176);
  ushort_t* g2b   = (ushort_t*)(ws + 10165248);
  float* c2    = ws + 16777216;
  ushort_t* xb16 = (ushort_t*)(ws + 16777216);   // aliases c2 (consumed pre-conv2)
  float* An   = ws + 21495808;
  float* g3   = ws + 22364160;
  float* outp = (float*)d_out;

  hipLaunchKernelGGL(k_prep,        dim3(10940),    dim3(256), 0, stream,
                     x, xb16, wc2, w2f, wg1, wg1Tb, wg2, wg2Tb, wg3, wg3Tb, adj, An);
  hipLaunchKernelGGL(k_conv1_mfma,  dim3(2048),     dim3(256), 0, stream, xb16, wc1, bc1, h1);
  hipLaunchKernelGGL(k_conv2,       dim3(8192),     dim3(128), 0, stream, h1, w2f, c2);
  hipLaunchKernelGGL(k_pool2,       dim3(512),      dim3(256), 0, stream, c2, bc2, featb);
  hipLaunchKernelGGL(k_gcn_layer,   dim3(16,4),     dim3(256), 0, stream,
                     featb, wg1Tb, bg1, An, g1b, (float*)nullptr, 2048, 1024, 1);
  hipLaunchKernelGGL(k_gcn_layer,   dim3(8,4),      dim3(256), 0, stream,
                     g1b, wg2Tb, bg2, An, g2b, (float*)nullptr, 1024, 512, 1);
  hipLaunchKernelGGL(k_gcn_layer,   dim3(4,4),      dim3(256), 0, stream,
                     g2b, wg3Tb, bg3, An, (ushort_t*)nullptr, g3, 512, 256, 0);
  hipLaunchKernelGGL(k_head,        dim3(4),        dim3(256), 0, stream, g3, wf1, bf1, wf2, bf2, outp);
}

// Round 9
// 280.033 us; speedup vs baseline: 4.1178x; 1.0309x over previous
//
#include <hip/hip_runtime.h>

typedef unsigned short ushort_t;
typedef unsigned long long ull_t;
typedef __attribute__((ext_vector_type(8))) short bf16x8;
typedef __attribute__((ext_vector_type(4))) float f32x4;

static __device__ __forceinline__ unsigned short f2bf(float f) {
  unsigned u = __float_as_uint(f);
  u = (u + 0x7FFFu + ((u >> 16) & 1u)) >> 16;
  return (unsigned short)u;
}

static __device__ __forceinline__ f32x4 max4(f32x4 a, f32x4 b) {
  f32x4 r;
  r[0] = fmaxf(a[0], b[0]); r[1] = fmaxf(a[1], b[1]);
  r[2] = fmaxf(a[2], b[2]); r[3] = fmaxf(a[3], b[3]);
  return r;
}

// ---------------------------------------------------------------------------
// Workspace layout (fp32-element offsets):
//   h1    @ 0          : 16777216 ushorts
//   w2f   @ 8388608    : 14336 ushorts (conv2 weight frags)
//   wg1Tb @ 8395776    : 1024x2048 ushorts
//   wg2Tb @ 9444352    : 512x1024 ushorts
//   wg3Tb @ 9706496    : 256x512 ushorts
//   featb @ 9772032    : 256x2048 ushorts
//   g1b   @ 10034176   : 256x1024 ushorts
//   g2b   @ 10165248   : 256x512 ushorts
//   c2    @ 16777216   : 4194304 floats   (ALIASED: xb16, consumed pre-conv2)
//   An    @ 21495808   : 4*64*64
//   g3    @ 22364160   : 256*256
// ---------------------------------------------------------------------------

// ---------------- fused prep: x2bf | w2f | 3x transpose | gcn_norm ---------
__device__ __forceinline__ void prep_transpose(
    const float* __restrict__ W, ushort_t* __restrict__ out,
    int K, int N, int n0, int k0, int t, float (*tile)[33])
{
  const int tx = t & 31, ty = t >> 5;
#pragma unroll
  for (int i = 0; i < 4; ++i) {
    const int k = k0 + ty + i * 8;
    tile[ty + i * 8][tx] = W[(size_t)k * N + n0 + tx];
  }
  __syncthreads();
#pragma unroll
  for (int i = 0; i < 4; ++i) {
    const int n = n0 + ty + i * 8;
    out[(size_t)n * K + k0 + tx] = f2bf(tile[tx][ty + i * 8]);
  }
}

__global__ __launch_bounds__(256) void k_prep(
    const float* __restrict__ x, ushort_t* __restrict__ xb16,
    const float* __restrict__ w2, ushort_t* __restrict__ w2f,
    const float* __restrict__ wg1, ushort_t* __restrict__ wg1T,
    const float* __restrict__ wg2, ushort_t* __restrict__ wg2T,
    const float* __restrict__ wg3, ushort_t* __restrict__ wg3T,
    const int* __restrict__ adj, float* __restrict__ An)
{
  __shared__ float tile[32][33];
  __shared__ float dinv[64];
  __shared__ int part[256];
  int b = blockIdx.x;
  const int t = threadIdx.x;
  if (b < 8192) {                       // x -> bf16
    const int tid = b * 256 + t;
    const float4 v = ((const float4*)x)[tid];
    const unsigned lo = (unsigned)f2bf(v.x) | ((unsigned)f2bf(v.y) << 16);
    const unsigned hi = (unsigned)f2bf(v.z) | ((unsigned)f2bf(v.w) << 16);
    ((uint2*)xb16)[tid] = make_uint2(lo, hi);
    return;
  }
  b -= 8192;
  if (b < 56) {                         // conv2 weight frags
    const int tid = b * 256 + t;
    if (tid < 14336) {
      const int nt = tid / 7168, rem = tid % 7168;
      const int kk = rem / 512, rem2 = rem % 512;
      const int l = rem2 >> 3, j = rem2 & 7;
      const int n = nt * 16 + (l & 15);
      const int k = (l >> 4) * 8 + kk * 32 + j;
      float v = 0.f;
      if (k < 432) v = w2[n * 432 + k];
      w2f[tid] = f2bf(v);
    }
    return;
  }
  b -= 56;
  if (b < 2048) { prep_transpose(wg1, wg1T, 2048, 1024, (b & 31) << 5, (b >> 5) << 5, t, tile); return; }
  b -= 2048;
  if (b < 512)  { prep_transpose(wg2, wg2T, 1024, 512,  (b & 15) << 5, (b >> 4) << 5, t, tile); return; }
  b -= 512;
  if (b < 128)  { prep_transpose(wg3, wg3T, 512,  256,  (b & 7)  << 5, (b >> 3) << 5, t, tile); return; }
  b -= 128;
  {                                     // gcn_norm, b in [0,4)
    const int i = t >> 2, q = t & 3;
    const int* ab = adj + b * 4096 + i * 64 + q * 16;
    int d = 0;
#pragma unroll
    for (int j = 0; j < 16; ++j) d += (ab[j] != 0) ? 1 : 0;
    part[t] = d;
    __syncthreads();
    if (q == 0)
      dinv[i] = rsqrtf((float)(1 + part[t] + part[t + 1] + part[t + 2] + part[t + 3]));
    __syncthreads();
    for (int idx = t; idx < 4096; idx += 256) {
      const int ii = idx >> 6, jj = idx & 63;
      const float a = (ii == jj) ? 1.f : ((adj[b * 4096 + idx] != 0) ? 1.f : 0.f);
      An[b * 4096 + idx] = a * dinv[ii] * dinv[jj];
    }
  }
}

// ---------------- K1: conv1 + maxpool3 as bf16 MFMA "pooled-direct" --------
// Fragment reads now use 12 precomputed per-lane LDS base pointers; the row
// term yy*152 folds into the ds_read immediate (zero per-iter address VALU).
__global__ __launch_bounds__(256) void k_conv1_mfma(
    const ushort_t* __restrict__ xb16, const float* __restrict__ wc,
    const float* __restrict__ bc, ushort_t* __restrict__ h1)
{
  __shared__ ushort_t L[2 * 34 * 76];
  char* Lb = (char*)L;
  const int bn = blockIdx.x >> 3, zg = blockIdx.x & 7;
  const int t = threadIdx.x;
  const int w = t >> 6, l = t & 63;
  const int grp = l >> 4, m = l & 15, ch = l & 15;
  const float NINF = -1e30f;

  union { short s[8]; bf16x8 v; } uA, uB;
#pragma unroll
  for (int j = 0; j < 8; ++j) {
    const int k = grp * 8 + j;
    float wA = 0.f, wB = 0.f;
    if (k < 12) {
      const int dx = k >> 2, dz = k & 3;
      if (dz < 3) { wA = wc[ch*27 + dz*9 + 0 + dx]; wB = wc[ch*27 + dz*9 + 6 + dx]; }
    } else if (k >= 16 && k < 28) {
      const int kk = k - 16, dx = kk >> 2, dz = kk & 3;
      if (dz < 3) wA = wc[ch*27 + dz*9 + 3 + dx];
    }
    uA.s[j] = (short)f2bf(wA);
    uB.s[j] = (short)f2bf(wB);
  }

  // 12 base pointers: fA rows start at y=8w-1 (+rsel dy select), fB at y+2.
  const char* baseA[3][2];
  const char* baseB[3][2];
  {
    const int rsel = (grp >> 1) * 152;
    const int rowA = (8 * w - 1) * 152 + rsel;
    const int rowB = (8 * w + 1) * 152;
#pragma unroll
    for (int s = 0; s < 3; ++s) {
      const int Q1 = 2*m + s + 2*(grp & 1);
      const int Q2 = Q1 + 1;
      const int aX1 = (Q1 & 1) * 5168 + (Q1 >> 1) * 8;
      const int aX2 = (Q2 & 1) * 5168 + (Q2 >> 1) * 8;
      baseA[s][0] = Lb + (aX1 + rowA);
      baseA[s][1] = Lb + (aX2 + rowA);
      baseB[s][0] = Lb + (aX1 + rowB);
      baseB[s][1] = Lb + (aX2 + rowB);
    }
  }

  for (int u = t; u < 200; u += 256) {
    int addr;
    if (u < 72) {
      const int rr = (u < 36) ? 0 : 33;
      const int s = (u < 36) ? u : u - 36;
      const int pp = s / 18, slot = s - pp * 18;
      addr = pp * 5168 + rr * 152 + slot * 8;
    } else {
      const int v = u - 72;
      const int rr = 1 + (v >> 2);
      const int pp = (v >> 1) & 1;
      const int slot = (v & 1) * 17;
      addr = pp * 5168 + rr * 152 + slot * 8;
    }
    *(ull_t*)(Lb + addr) = 0ull;
  }

  f32x4 accZ[4][2];
#pragma unroll
  for (int j = 0; j < 4; ++j)
#pragma unroll
    for (int p = 0; p < 2; ++p) accZ[j][p] = (f32x4){NINF, NINF, NINF, NINF};

  const ushort_t* xb = xb16 + (size_t)bn * 32768;

#pragma unroll 1
  for (int ci = 0; ci < 5; ++ci) {
    const int cz = 4*zg - 1 + ci;
    if (cz < 0) continue;
    if (t < 128) {
      const int r = 1 + (t >> 2), g = t & 3;
      const ushort_t* xrow = xb + (r - 1) * 32 + g * 8;
      uint4 u0 = make_uint4(0u, 0u, 0u, 0u), u2 = make_uint4(0u, 0u, 0u, 0u);
      if (cz > 0)  u0 = *(const uint4*)(xrow + (cz - 1) * 1024);
      const uint4 u1 = *(const uint4*)(xrow + cz * 1024);
      if (cz < 31) u2 = *(const uint4*)(xrow + (cz + 1) * 1024);
      char* b0 = Lb + r * 152 + (4 * g + 1) * 8;
      char* b1 = Lb + 5168 + r * 152 + (4 * g + 1) * 8;
      const unsigned* p0 = (const unsigned*)&u0;
      const unsigned* p1 = (const unsigned*)&u1;
      const unsigned* p2 = (const unsigned*)&u2;
#pragma unroll
      for (int e = 0; e < 4; ++e) {
        const unsigned w0 = p0[e], w1 = p1[e], w2v = p2[e];
        const unsigned lo_e = (w0 & 0xFFFFu) | (w1 << 16);
        const unsigned hi_e = (w2v & 0xFFFFu);
        const unsigned lo_o = (w0 >> 16) | (w1 & 0xFFFF0000u);
        const unsigned hi_o = (w2v >> 16);
        *(ull_t*)(b0 + e * 8) = (ull_t)lo_e | ((ull_t)hi_e << 32);
        *(ull_t*)(b1 + e * 8) = (ull_t)lo_o | ((ull_t)hi_o << 32);
      }
    }
    __syncthreads();
    f32x4 accP0 = (f32x4){NINF, NINF, NINF, NINF};
    f32x4 accP1 = (f32x4){NINF, NINF, NINF, NINF};
#pragma unroll
    for (int yy = 0; yy < 9; ++yy) {
      if (yy == 0 && w == 0) continue;
      f32x4 Cy;
#pragma unroll
      for (int s = 0; s < 3; ++s) {
        union { ull_t u[2]; bf16x8 v; } fA, fB;
        fA.u[0] = *(const ull_t*)(baseA[s][0] + yy * 152);
        fA.u[1] = *(const ull_t*)(baseA[s][1] + yy * 152);
        fB.u[0] = *(const ull_t*)(baseB[s][0] + yy * 152);
        fB.u[1] = *(const ull_t*)(baseB[s][1] + yy * 152);
        f32x4 acc = (f32x4){0.f, 0.f, 0.f, 0.f};
        acc = __builtin_amdgcn_mfma_f32_16x16x32_bf16(fA.v, uA.v, acc, 0, 0, 0);
        acc = __builtin_amdgcn_mfma_f32_16x16x32_bf16(fB.v, uB.v, acc, 0, 0, 0);
        if (s == 0) acc[0] = (l < 16) ? NINF : acc[0];
        Cy = (s == 0) ? acc : max4(Cy, acc);
      }
      if (yy & 1) {
        const int c = (yy - 1) / 2;
        if ((c & 1) == 0) accP0 = max4(accP0, Cy); else accP1 = max4(accP1, Cy);
      } else {
        const int cl = yy / 2 - 1;
        const int chh = yy / 2;
        if (cl >= 0) {
          if ((cl & 1) == 0) {
            accP0 = max4(accP0, Cy);
            if (ci <= 2) accZ[cl][0] = max4(accZ[cl][0], accP0);
            if (ci >= 2) accZ[cl][1] = max4(accZ[cl][1], accP0);
            accP0 = (f32x4){NINF, NINF, NINF, NINF};
          } else {
            accP1 = max4(accP1, Cy);
            if (ci <= 2) accZ[cl][0] = max4(accZ[cl][0], accP1);
            if (ci >= 2) accZ[cl][1] = max4(accZ[cl][1], accP1);
            accP1 = (f32x4){NINF, NINF, NINF, NINF};
          }
        }
        if (chh <= 3) {
          if ((chh & 1) == 0) accP0 = max4(accP0, Cy); else accP1 = max4(accP1, Cy);
        }
      }
    }
    __syncthreads();
  }

  const float biasv = bc[ch];
  const int grp4 = grp * 4;
#pragma unroll
  for (int j = 0; j < 4; ++j) {
    const int py = 4 * w + j;
#pragma unroll
    for (int p = 0; p < 2; ++p) {
      const int pz = 2 * zg + p;
      const f32x4 v = accZ[j][p];
      const unsigned lo = (unsigned)f2bf(fmaxf(v[0] + biasv, 0.f)) |
                          ((unsigned)f2bf(fmaxf(v[1] + biasv, 0.f)) << 16);
      const unsigned hi = (unsigned)f2bf(fmaxf(v[2] + biasv, 0.f)) |
                          ((unsigned)f2bf(fmaxf(v[3] + biasv, 0.f)) << 16);
      ushort_t* dst = h1 + (((size_t)(bn * 16 + ch) * 16 + pz) << 8) + py * 16 + grp4;
      *(uint2*)dst = make_uint2(lo, hi);
    }
  }
}

// ---------------- K2: conv2 as bf16 MFMA implicit GEMM, quarter-plane ------
__global__ __launch_bounds__(128) void k_conv2(
    const ushort_t* __restrict__ h1, const ushort_t* __restrict__ w2f,
    float* __restrict__ c2)
{
  __shared__ ushort_t As[16 * 456];
  const int b = blockIdx.x;
  const int bn = b >> 5, oz = (b >> 2) & 7, yg = b & 3;
  const int t = threadIdx.x;
  const ushort_t* hb = h1 + ((size_t)bn << 16);
  const int w = t >> 6, l = t & 63;

  bf16x8 bfr[14];
#pragma unroll
  for (int kk = 0; kk < 14; ++kk)
    bfr[kk] = *(const bf16x8*)(const void*)&w2f[(((w * 14) + kk) * 64 + l) * 8];

  for (int idx = t; idx < 256; idx += 128) {
    const int r = idx >> 4, k = 432 + (idx & 15);
    As[r * 456 + k] = 0;
  }

  const int m = t >> 3, sub = t & 7;
  const int oy = 2 * yg + (m >> 3), ox = m & 7;
  ushort_t tv[54];
  int j = 0;
#pragma unroll
  for (int ic2 = 0; ic2 < 2; ++ic2) {
    const ushort_t* icp = hb + ((sub * 2 + ic2) << 12);
#pragma unroll
    for (int dz = 0; dz < 3; ++dz) {
      const int iz = 2 * oz - 1 + dz;
      const bool zok = (unsigned)iz < 16u;
      const unsigned* zp = (const unsigned*)(icp + (iz << 8));
#pragma unroll
      for (int dy = 0; dy < 3; ++dy) {
        const int iy = 2 * oy - 1 + dy;
        const bool yok = zok && ((unsigned)iy < 16u);
        const unsigned* ydw = zp + (iy << 3);
        const unsigned d0 = (yok && ox > 0) ? ydw[ox - 1] : 0u;
        const unsigned d1 = yok ? ydw[ox] : 0u;
        tv[j]     = (ushort_t)(d0 >> 16);
        tv[j + 1] = (ushort_t)(d1 & 0xFFFFu);
        tv[j + 2] = (ushort_t)(d1 >> 16);
        j += 3;
      }
    }
  }
  {
    unsigned* Aw = (unsigned*)As;
    const int wbase = m * 228 + sub * 27;
#pragma unroll
    for (int p = 0; p < 27; ++p)
      Aw[wbase + p] = (unsigned)tv[2 * p] | ((unsigned)tv[2 * p + 1] << 16);
  }
  __syncthreads();
  f32x4 acc = {0.f, 0.f, 0.f, 0.f};
  const ushort_t* arow = &As[(l & 15) * 456 + ((l >> 4) << 3)];
#pragma unroll
  for (int kk = 0; kk < 14; ++kk) {
    const bf16x8 af = *(const bf16x8*)(const void*)&arow[kk * 32];
    acc = __builtin_amdgcn_mfma_f32_16x16x32_bf16(af, bfr[kk], acc, 0, 0, 0);
  }
  const int n = w * 16 + (l & 15);
  const int m0 = (l >> 4) << 2;
  float* cb = c2 + (((size_t)(bn * 32 + n) * 8) + oz) * 64 + yg * 16 + m0;
  *(float4*)cb = make_float4(acc[0], acc[1], acc[2], acc[3]);
}

// ---------------- K2b: maxpool3 s2 p1 + bias + relu -> feat (bf16) ---------
__global__ __launch_bounds__(256) void k_pool2(
    const float* __restrict__ c2, const float* __restrict__ bc2,
    ushort_t* __restrict__ featb)
{
  const int tid = blockIdx.x * 256 + threadIdx.x;  // 131072
  const int bn = tid >> 9, r = tid & 511;
  const int ch = r >> 4, pz = (r >> 2) & 3, py = r & 3;
  const float* base = c2 + ((size_t)(bn * 32 + ch) << 9);
  float m0 = -1e30f, m1 = -1e30f, m2 = -1e30f, m3 = -1e30f;
#pragma unroll
  for (int dz = 0; dz < 3; ++dz) {
    const int oz = 2 * pz - 1 + dz;
    if ((unsigned)oz >= 8u) continue;
#pragma unroll
    for (int dy = 0; dy < 3; ++dy) {
      const int oy = 2 * py - 1 + dy;
      if ((unsigned)oy >= 8u) continue;
      const float* row = base + (oz << 6) + (oy << 3);
      const float4 a = ((const float4*)row)[0];
      const float4 b = ((const float4*)row)[1];
      m0 = fmaxf(m0, fmaxf(a.x, a.y));
      m1 = fmaxf(m1, fmaxf(a.y, fmaxf(a.z, a.w)));
      m2 = fmaxf(m2, fmaxf(a.w, fmaxf(b.x, b.y)));
      m3 = fmaxf(m3, fmaxf(b.y, fmaxf(b.z, b.w)));
    }
  }
  const float bb = bc2[ch];
  const unsigned lo = (unsigned)f2bf(fmaxf(m0 + bb, 0.f)) |
                      ((unsigned)f2bf(fmaxf(m1 + bb, 0.f)) << 16);
  const unsigned hi = (unsigned)f2bf(fmaxf(m2 + bb, 0.f)) |
                      ((unsigned)f2bf(fmaxf(m3 + bb, 0.f)) << 16);
  *(uint2*)(featb + (size_t)bn * 2048 + r * 4) = make_uint2(lo, hi);
}

// ---------------- fused GCN layer: out = [relu](A_norm @ (X W) + b) --------
// Double-buffered LDS + register prefetch; one barrier per K-iteration.
__global__ __launch_bounds__(256) void k_gcn_layer(
    const ushort_t* __restrict__ Xb, const ushort_t* __restrict__ WT,
    const float* __restrict__ bias, const float* __restrict__ An,
    ushort_t* __restrict__ Ob, float* __restrict__ Of, int K, int N, int relu)
{
  __shared__ ushort_t As[2][64 * 72];
  __shared__ ushort_t Bs[2][64 * 72];
  __shared__ ushort_t Ps[64 * 72];   // P transposed: Ps[n][node]
  const int b = blockIdx.y, jb = blockIdx.x << 6;
  const int t = threadIdx.x, w = t >> 6, l = t & 63;
  const int r0 = t >> 3, kc0 = t & 7;
  const int lm = l & 15, lg = l >> 4;

  // A_norm fragments for out-rows 16w..16w+15
  union { short s[8]; bf16x8 v; } afr[2];
  {
    const float* ap = An + b * 4096 + (16 * w + lm) * 64 + (lg << 3);
#pragma unroll
    for (int kc = 0; kc < 2; ++kc) {
      const float4 v0 = *(const float4*)(ap + kc * 32);
      const float4 v1 = *(const float4*)(ap + kc * 32 + 4);
      afr[kc].s[0] = (short)f2bf(v0.x); afr[kc].s[1] = (short)f2bf(v0.y);
      afr[kc].s[2] = (short)f2bf(v0.z); afr[kc].s[3] = (short)f2bf(v0.w);
      afr[kc].s[4] = (short)f2bf(v1.x); afr[kc].s[5] = (short)f2bf(v1.y);
      afr[kc].s[6] = (short)f2bf(v1.z); afr[kc].s[7] = (short)f2bf(v1.w);
    }
  }

  f32x4 acc[4];
#pragma unroll
  for (int nt = 0; nt < 4; ++nt) acc[nt] = (f32x4){0.f, 0.f, 0.f, 0.f};

  const ushort_t* arow0 = &Xb[(size_t)(b * 64 + r0) * K + kc0 * 8];
  const ushort_t* arow1 = &Xb[(size_t)(b * 64 + r0 + 32) * K + kc0 * 8];
  const ushort_t* brow0 = &WT[(size_t)(jb + r0) * K + kc0 * 8];
  const ushort_t* brow1 = &WT[(size_t)(jb + r0 + 32) * K + kc0 * 8];

  uint4 va0 = *(const uint4*)arow0;
  uint4 va1 = *(const uint4*)arow1;
  uint4 vb0 = *(const uint4*)brow0;
  uint4 vb1 = *(const uint4*)brow1;

  int buf = 0;
#pragma unroll 1
  for (int kt = 0; kt < K; kt += 64) {
    *(uint4*)&As[buf][r0 * 72 + kc0 * 8]        = va0;
    *(uint4*)&As[buf][(r0 + 32) * 72 + kc0 * 8] = va1;
    *(uint4*)&Bs[buf][r0 * 72 + kc0 * 8]        = vb0;
    *(uint4*)&Bs[buf][(r0 + 32) * 72 + kc0 * 8] = vb1;
    __syncthreads();
    if (kt + 64 < K) {
      va0 = *(const uint4*)(arow0 + kt + 64);
      va1 = *(const uint4*)(arow1 + kt + 64);
      vb0 = *(const uint4*)(brow0 + kt + 64);
      vb1 = *(const uint4*)(brow1 + kt + 64);
    }
#pragma unroll
    for (int ks = 0; ks < 2; ++ks) {
      const bf16x8 af = *(const bf16x8*)(const void*)
          &As[buf][(16 * w + lm) * 72 + ks * 32 + (lg << 3)];
#pragma unroll
      for (int nt = 0; nt < 4; ++nt) {
        const bf16x8 bf = *(const bf16x8*)(const void*)
            &Bs[buf][(nt * 16 + lm) * 72 + ks * 32 + (lg << 3)];
        acc[nt] = __builtin_amdgcn_mfma_f32_16x16x32_bf16(af, bf, acc[nt], 0, 0, 0);
      }
    }
    buf ^= 1;
  }

  // ---- P -> Ps (transposed, bf16) ----
  __syncthreads();
  const int m0 = lg << 2;
#pragma unroll
  for (int nt = 0; nt < 4; ++nt) {
    const int n = nt * 16 + lm;
    const unsigned lo = (unsigned)f2bf(acc[nt][0]) | ((unsigned)f2bf(acc[nt][1]) << 16);
    const unsigned hi = (unsigned)f2bf(acc[nt][2]) | ((unsigned)f2bf(acc[nt][3]) << 16);
    *(uint2*)&Ps[n * 72 + 16 * w + m0] = make_uint2(lo, hi);
  }
  __syncthreads();

  // ---- Phase 2: out = A @ P (+bias, relu) ----
#pragma unroll
  for (int nt = 0; nt < 4; ++nt) {
    const bf16x8 b0 = *(const bf16x8*)(const void*)&Ps[(nt * 16 + lm) * 72 + (lg << 3)];
    const bf16x8 b1 = *(const bf16x8*)(const void*)&Ps[(nt * 16 + lm) * 72 + 32 + (lg << 3)];
    f32x4 a2 = (f32x4){0.f, 0.f, 0.f, 0.f};
    a2 = __builtin_amdgcn_mfma_f32_16x16x32_bf16(afr[0].v, b0, a2, 0, 0, 0);
    a2 = __builtin_amdgcn_mfma_f32_16x16x32_bf16(afr[1].v, b1, a2, 0, 0, 0);
    const int col = jb + nt * 16 + lm;
    const float bv = bias[col];
#pragma unroll
    for (int r = 0; r < 4; ++r) {
      const int row = b * 64 + 16 * w + m0 + r;
      float v = a2[r] + bv;
      if (relu) v = fmaxf(v, 0.f);
      if (Ob) Ob[(size_t)row * N + col] = f2bf(v);
      else    Of[(size_t)row * N + col] = v;
    }
  }
}

// ---------------- head: chunk-max + fc1 + relu + fc2 + softmax -------------
__global__ __launch_bounds__(256) void k_head(
    const float* __restrict__ g3, const float* __restrict__ w1, const float* __restrict__ b1,
    const float* __restrict__ w2, const float* __restrict__ b2, float* __restrict__ out)
{
  const int b = blockIdx.x, t = threadIdx.x;
  __shared__ float sp[256];
  __shared__ float sh[512];
  __shared__ float sl[4];
  {
    const int n = t >> 2, c = t & 3;
    const float* gr = g3 + (size_t)(b * 64 + n) * 256 + c * 64;
    float mx = -1e30f;
    for (int f = 0; f < 64; ++f) mx = fmaxf(mx, gr[f]);
    sp[t] = mx;
  }
  __syncthreads();
  for (int jj = t; jj < 512; jj += 256) {
    float s = b1[jj];
    for (int k = 0; k < 256; ++k) s += sp[k] * w1[k * 512 + jj];
    sh[jj] = fmaxf(s, 0.f);
  }
  __syncthreads();
  if (t < 4) {
    float s = b2[t];
    for (int k = 0; k < 512; ++k) s += sh[k] * w2[k * 4 + t];
    sl[t] = s;
  }
  __syncthreads();
  if (t == 0) {
    const float mm = fmaxf(fmaxf(sl[0], sl[1]), fmaxf(sl[2], sl[3]));
    const float e0 = expf(sl[0] - mm), e1 = expf(sl[1] - mm);
    const float e2 = expf(sl[2] - mm), e3 = expf(sl[3] - mm);
    const float inv = 1.f / (e0 + e1 + e2 + e3);
    out[b * 4 + 0] = e0 * inv;
    out[b * 4 + 1] = e1 * inv;
    out[b * 4 + 2] = e2 * inv;
    out[b * 4 + 3] = e3 * inv;
  }
}

// ---------------------------------------------------------------------------
extern "C" void kernel_launch(void* const* d_in, const int* in_sizes, int n_in,
                              void* d_out, int out_size, void* d_ws, size_t ws_size,
                              hipStream_t stream)
{
  (void)in_sizes; (void)n_in; (void)out_size; (void)ws_size;
  const float* x   = (const float*)d_in[0];
  const int*   adj = (const int*)d_in[1];
  const float* wc1 = (const float*)d_in[3];
  const float* bc1 = (const float*)d_in[4];
  const float* wc2 = (const float*)d_in[5];
  const float* bc2 = (const float*)d_in[6];
  const float* wg1 = (const float*)d_in[7];
  const float* bg1 = (const float*)d_in[8];
  const float* wg2 = (const float*)d_in[9];
  const float* bg2 = (const float*)d_in[10];
  const float* wg3 = (const float*)d_in[11];
  const float* bg3 = (const float*)d_in[12];
  const float* wf1 = (const float*)d_in[13];
  const float* bf1 = (const float*)d_in[14];
  const float* wf2 = (const float*)d_in[15];
  const float* bf2 = (const float*)d_in[16];

  float* ws    = (float*)d_ws;
  ushort_t* h1 = (ushort_t*)d_ws;
  ushort_t* w2f   = (ushort_t*)(ws + 8388608);
  ushort_t* wg1Tb = (ushort_t*)(ws + 8395776);
  ushort_t* wg2Tb = (ushort_t*)(ws + 9444352);
  ushort_t* wg3Tb = (ushort_t*)(ws + 9706496);
  ushort_t* featb = (ushort_t*)(ws + 9772032);
  ushort_t* g1b   = (ushort_t*)(ws + 10034176);
  ushort_t* g2b   = (ushort_t*)(ws + 10165248);
  float* c2    = ws + 16777216;
  ushort_t* xb16 = (ushort_t*)(ws + 16777216);   // aliases c2 (consumed pre-conv2)
  float* An   = ws + 21495808;
  float* g3   = ws + 22364160;
  float* outp = (float*)d_out;

  hipLaunchKernelGGL(k_prep,        dim3(10940),    dim3(256), 0, stream,
                     x, xb16, wc2, w2f, wg1, wg1Tb, wg2, wg2Tb, wg3, wg3Tb, adj, An);
  hipLaunchKernelGGL(k_conv1_mfma,  dim3(2048),     dim3(256), 0, stream, xb16, wc1, bc1, h1);
  hipLaunchKernelGGL(k_conv2,       dim3(8192),     dim3(128), 0, stream, h1, w2f, c2);
  hipLaunchKernelGGL(k_pool2,       dim3(512),      dim3(256), 0, stream, c2, bc2, featb);
  hipLaunchKernelGGL(k_gcn_layer,   dim3(16,4),     dim3(256), 0, stream,
                     featb, wg1Tb, bg1, An, g1b, (float*)nullptr, 2048, 1024, 1);
  hipLaunchKernelGGL(k_gcn_layer,   dim3(8,4),      dim3(256), 0, stream,
                     g1b, wg2Tb, bg2, An, g2b, (float*)nullptr, 1024, 512, 1);
  hipLaunchKernelGGL(k_gcn_layer,   dim3(4,4),      dim3(256), 0, stream,
                     g2b, wg3Tb, bg3, An, (ushort_t*)nullptr, g3, 512, 256, 0);
  hipLaunchKernelGGL(k_head,        dim3(4),        dim3(256), 0, stream, g3, wf1, bf1, wf2, bf2, outp);
}

// Round 10
// 268.930 us; speedup vs baseline: 4.2878x; 1.0413x over previous
//
#include <hip/hip_runtime.h>

typedef unsigned short ushort_t;
typedef unsigned long long ull_t;
typedef __attribute__((ext_vector_type(8))) short bf16x8;
typedef __attribute__((ext_vector_type(4))) float f32x4;

static __device__ __forceinline__ unsigned short f2bf(float f) {
  unsigned u = __float_as_uint(f);
  u = (u + 0x7FFFu + ((u >> 16) & 1u)) >> 16;
  return (unsigned short)u;
}

static __device__ __forceinline__ f32x4 max4(f32x4 a, f32x4 b) {
  f32x4 r;
  r[0] = fmaxf(a[0], b[0]); r[1] = fmaxf(a[1], b[1]);
  r[2] = fmaxf(a[2], b[2]); r[3] = fmaxf(a[3], b[3]);
  return r;
}

// ---------------------------------------------------------------------------
// Workspace layout (fp32-element offsets):
//   h1    @ 0          : 16777216 ushorts
//   w2f   @ 8388608    : 14336 ushorts (conv2 weight frags)
//   wg1Tb @ 8395776    : 1024x2048 ushorts
//   wg2Tb @ 9444352    : 512x1024 ushorts
//   wg3Tb @ 9706496    : 256x512 ushorts
//   featb @ 9772032    : 256x2048 ushorts
//   g1b   @ 10034176   : 256x1024 ushorts
//   g2b   @ 10165248   : 256x512 ushorts
//   c2    @ 16777216   : 4194304 floats   (ALIASED: xb16, consumed pre-conv2)
//   An    @ 21495808   : 4*64*64
//   g3    @ 22364160   : 256*256
// ---------------------------------------------------------------------------

// ---------------- fused prep: x2bf | w2f | 3x transpose | gcn_norm ---------
__device__ __forceinline__ void prep_transpose(
    const float* __restrict__ W, ushort_t* __restrict__ out,
    int K, int N, int n0, int k0, int t, float (*tile)[33])
{
  const int tx = t & 31, ty = t >> 5;
#pragma unroll
  for (int i = 0; i < 4; ++i) {
    const int k = k0 + ty + i * 8;
    tile[ty + i * 8][tx] = W[(size_t)k * N + n0 + tx];
  }
  __syncthreads();
#pragma unroll
  for (int i = 0; i < 4; ++i) {
    const int n = n0 + ty + i * 8;
    out[(size_t)n * K + k0 + tx] = f2bf(tile[tx][ty + i * 8]);
  }
}

__global__ __launch_bounds__(256) void k_prep(
    const float* __restrict__ x, ushort_t* __restrict__ xb16,
    const float* __restrict__ w2, ushort_t* __restrict__ w2f,
    const float* __restrict__ wg1, ushort_t* __restrict__ wg1T,
    const float* __restrict__ wg2, ushort_t* __restrict__ wg2T,
    const float* __restrict__ wg3, ushort_t* __restrict__ wg3T,
    const int* __restrict__ adj, float* __restrict__ An)
{
  __shared__ float tile[32][33];
  __shared__ float dinv[64];
  __shared__ int part[256];
  int b = blockIdx.x;
  const int t = threadIdx.x;
  if (b < 8192) {                       // x -> bf16
    const int tid = b * 256 + t;
    const float4 v = ((const float4*)x)[tid];
    const unsigned lo = (unsigned)f2bf(v.x) | ((unsigned)f2bf(v.y) << 16);
    const unsigned hi = (unsigned)f2bf(v.z) | ((unsigned)f2bf(v.w) << 16);
    ((uint2*)xb16)[tid] = make_uint2(lo, hi);
    return;
  }
  b -= 8192;
  if (b < 56) {                         // conv2 weight frags
    const int tid = b * 256 + t;
    if (tid < 14336) {
      const int nt = tid / 7168, rem = tid % 7168;
      const int kk = rem / 512, rem2 = rem % 512;
      const int l = rem2 >> 3, j = rem2 & 7;
      const int n = nt * 16 + (l & 15);
      const int k = (l >> 4) * 8 + kk * 32 + j;
      float v = 0.f;
      if (k < 432) v = w2[n * 432 + k];
      w2f[tid] = f2bf(v);
    }
    return;
  }
  b -= 56;
  if (b < 2048) { prep_transpose(wg1, wg1T, 2048, 1024, (b & 31) << 5, (b >> 5) << 5, t, tile); return; }
  b -= 2048;
  if (b < 512)  { prep_transpose(wg2, wg2T, 1024, 512,  (b & 15) << 5, (b >> 4) << 5, t, tile); return; }
  b -= 512;
  if (b < 128)  { prep_transpose(wg3, wg3T, 512,  256,  (b & 7)  << 5, (b >> 3) << 5, t, tile); return; }
  b -= 128;
  {                                     // gcn_norm, b in [0,4)
    const int i = t >> 2, q = t & 3;
    const int* ab = adj + b * 4096 + i * 64 + q * 16;
    int d = 0;
#pragma unroll
    for (int j = 0; j < 16; ++j) d += (ab[j] != 0) ? 1 : 0;
    part[t] = d;
    __syncthreads();
    if (q == 0)
      dinv[i] = rsqrtf((float)(1 + part[t] + part[t + 1] + part[t + 2] + part[t + 3]));
    __syncthreads();
    for (int idx = t; idx < 4096; idx += 256) {
      const int ii = idx >> 6, jj = idx & 63;
      const float a = (ii == jj) ? 1.f : ((adj[b * 4096 + idx] != 0) ? 1.f : 0.f);
      An[b * 4096 + idx] = a * dinv[ii] * dinv[jj];
    }
  }
}

// ---------------- K1: conv1 + maxpool3 as bf16 MFMA "pooled-direct" --------
// (R8 form — measured best at 56.2 us; R9 base-pointer variant regressed.)
__global__ __launch_bounds__(256) void k_conv1_mfma(
    const ushort_t* __restrict__ xb16, const float* __restrict__ wc,
    const float* __restrict__ bc, ushort_t* __restrict__ h1)
{
  __shared__ ushort_t L[2 * 34 * 76];
  char* Lb = (char*)L;
  const int bn = blockIdx.x >> 3, zg = blockIdx.x & 7;
  const int t = threadIdx.x;
  const int w = t >> 6, l = t & 63;
  const int grp = l >> 4, m = l & 15, ch = l & 15;
  const float NINF = -1e30f;

  union { short s[8]; bf16x8 v; } uA, uB;
#pragma unroll
  for (int j = 0; j < 8; ++j) {
    const int k = grp * 8 + j;
    float wA = 0.f, wB = 0.f;
    if (k < 12) {
      const int dx = k >> 2, dz = k & 3;
      if (dz < 3) { wA = wc[ch*27 + dz*9 + 0 + dx]; wB = wc[ch*27 + dz*9 + 6 + dx]; }
    } else if (k >= 16 && k < 28) {
      const int kk = k - 16, dx = kk >> 2, dz = kk & 3;
      if (dz < 3) wA = wc[ch*27 + dz*9 + 3 + dx];
    }
    uA.s[j] = (short)f2bf(wA);
    uB.s[j] = (short)f2bf(wB);
  }

  int aX1[3], aX2[3];
#pragma unroll
  for (int s = 0; s < 3; ++s) {
    const int Q1 = 2*m + s + 2*(grp & 1);
    const int Q2 = Q1 + 1;
    aX1[s] = (Q1 & 1) * 5168 + (Q1 >> 1) * 8;
    aX2[s] = (Q2 & 1) * 5168 + (Q2 >> 1) * 8;
  }
  const int rsel = (grp >> 1) * 152;

  for (int u = t; u < 200; u += 256) {
    int addr;
    if (u < 72) {
      const int rr = (u < 36) ? 0 : 33;
      const int s = (u < 36) ? u : u - 36;
      const int pp = s / 18, slot = s - pp * 18;
      addr = pp * 5168 + rr * 152 + slot * 8;
    } else {
      const int v = u - 72;
      const int rr = 1 + (v >> 2);
      const int pp = (v >> 1) & 1;
      const int slot = (v & 1) * 17;
      addr = pp * 5168 + rr * 152 + slot * 8;
    }
    *(ull_t*)(Lb + addr) = 0ull;
  }

  f32x4 accZ[4][2];
#pragma unroll
  for (int j = 0; j < 4; ++j)
#pragma unroll
    for (int p = 0; p < 2; ++p) accZ[j][p] = (f32x4){NINF, NINF, NINF, NINF};

  const ushort_t* xb = xb16 + (size_t)bn * 32768;

#pragma unroll 1
  for (int ci = 0; ci < 5; ++ci) {
    const int cz = 4*zg - 1 + ci;
    if (cz < 0) continue;
    if (t < 128) {
      const int r = 1 + (t >> 2), g = t & 3;
      const ushort_t* xrow = xb + (r - 1) * 32 + g * 8;
      uint4 u0 = make_uint4(0u, 0u, 0u, 0u), u2 = make_uint4(0u, 0u, 0u, 0u);
      if (cz > 0)  u0 = *(const uint4*)(xrow + (cz - 1) * 1024);
      const uint4 u1 = *(const uint4*)(xrow + cz * 1024);
      if (cz < 31) u2 = *(const uint4*)(xrow + (cz + 1) * 1024);
      char* b0 = Lb + r * 152 + (4 * g + 1) * 8;
      char* b1 = Lb + 5168 + r * 152 + (4 * g + 1) * 8;
      const unsigned* p0 = (const unsigned*)&u0;
      const unsigned* p1 = (const unsigned*)&u1;
      const unsigned* p2 = (const unsigned*)&u2;
#pragma unroll
      for (int e = 0; e < 4; ++e) {
        const unsigned w0 = p0[e], w1 = p1[e], w2v = p2[e];
        const unsigned lo_e = (w0 & 0xFFFFu) | (w1 << 16);
        const unsigned hi_e = (w2v & 0xFFFFu);
        const unsigned lo_o = (w0 >> 16) | (w1 & 0xFFFF0000u);
        const unsigned hi_o = (w2v >> 16);
        *(ull_t*)(b0 + e * 8) = (ull_t)lo_e | ((ull_t)hi_e << 32);
        *(ull_t*)(b1 + e * 8) = (ull_t)lo_o | ((ull_t)hi_o << 32);
      }
    }
    __syncthreads();
    f32x4 accP0 = (f32x4){NINF, NINF, NINF, NINF};
    f32x4 accP1 = (f32x4){NINF, NINF, NINF, NINF};
#pragma unroll
    for (int yy = 0; yy < 9; ++yy) {
      if (yy == 0 && w == 0) continue;
      const int y = 8 * w - 1 + yy;
      const int rbA = y * 152 + rsel;
      const int rbB = (y + 2) * 152;
      f32x4 Cy;
#pragma unroll
      for (int s = 0; s < 3; ++s) {
        union { ull_t u[2]; bf16x8 v; } fA, fB;
        fA.u[0] = *(const ull_t*)(Lb + aX1[s] + rbA);
        fA.u[1] = *(const ull_t*)(Lb + aX2[s] + rbA);
        fB.u[0] = *(const ull_t*)(Lb + aX1[s] + rbB);
        fB.u[1] = *(const ull_t*)(Lb + aX2[s] + rbB);
        f32x4 acc = (f32x4){0.f, 0.f, 0.f, 0.f};
        acc = __builtin_amdgcn_mfma_f32_16x16x32_bf16(fA.v, uA.v, acc, 0, 0, 0);
        acc = __builtin_amdgcn_mfma_f32_16x16x32_bf16(fB.v, uB.v, acc, 0, 0, 0);
        if (s == 0) acc[0] = (l < 16) ? NINF : acc[0];
        Cy = (s == 0) ? acc : max4(Cy, acc);
      }
      if (yy & 1) {
        const int c = (yy - 1) / 2;
        if ((c & 1) == 0) accP0 = max4(accP0, Cy); else accP1 = max4(accP1, Cy);
      } else {
        const int cl = yy / 2 - 1;
        const int chh = yy / 2;
        if (cl >= 0) {
          if ((cl & 1) == 0) {
            accP0 = max4(accP0, Cy);
            if (ci <= 2) accZ[cl][0] = max4(accZ[cl][0], accP0);
            if (ci >= 2) accZ[cl][1] = max4(accZ[cl][1], accP0);
            accP0 = (f32x4){NINF, NINF, NINF, NINF};
          } else {
            accP1 = max4(accP1, Cy);
            if (ci <= 2) accZ[cl][0] = max4(accZ[cl][0], accP1);
            if (ci >= 2) accZ[cl][1] = max4(accZ[cl][1], accP1);
            accP1 = (f32x4){NINF, NINF, NINF, NINF};
          }
        }
        if (chh <= 3) {
          if ((chh & 1) == 0) accP0 = max4(accP0, Cy); else accP1 = max4(accP1, Cy);
        }
      }
    }
    __syncthreads();
  }

  const float biasv = bc[ch];
#pragma unroll
  for (int j = 0; j < 4; ++j) {
    const int py = 4 * w + j;
#pragma unroll
    for (int p = 0; p < 2; ++p) {
      const int pz = 2 * zg + p;
      const f32x4 v = accZ[j][p];
      const unsigned lo = (unsigned)f2bf(fmaxf(v[0] + biasv, 0.f)) |
                          ((unsigned)f2bf(fmaxf(v[1] + biasv, 0.f)) << 16);
      const unsigned hi = (unsigned)f2bf(fmaxf(v[2] + biasv, 0.f)) |
                          ((unsigned)f2bf(fmaxf(v[3] + biasv, 0.f)) << 16);
      ushort_t* dst = h1 + (((size_t)(bn * 16 + ch) * 16 + pz) << 8) + py * 16 + grp * 4;
      *(uint2*)dst = make_uint2(lo, hi);
    }
  }
}

// ---------------- K2: conv2 MFMA implicit GEMM, LDS-staged input -----------
// grid 8192 = (bn, oz, yg); block 128. Stage the block's unique h1 slab
// (16ic x 3iz x 6iy x 16ix, OOB=0) into LDS with coalesced uint2 loads
// (row stride 20 ushorts -> gather dword reads are <=2-way bank aliased),
// then im2col from LDS. Hs and As share one 14.6 KB union (10 blocks/CU).
__global__ __launch_bounds__(128) void k_conv2(
    const ushort_t* __restrict__ h1, const ushort_t* __restrict__ w2f,
    float* __restrict__ c2)
{
  __shared__ ushort_t U[16 * 456];            // 14592 B: Hs (11520 B) then As
  ushort_t* Hs = U;                           // Hs[row*20 + ix], row<288
  unsigned* Hsd = (unsigned*)U;               // dword view, stride 10
  ushort_t* As = U;                           // As[m*456 + k]
  const int b = blockIdx.x;
  const int bn = b >> 5, oz = (b >> 2) & 7, yg = b & 3;
  const int t = threadIdx.x;
  const ushort_t* hb = h1 + ((size_t)bn << 16);
  const int w = t >> 6, l = t & 63;

  bf16x8 bfr[14];
#pragma unroll
  for (int kk = 0; kk < 14; ++kk)
    bfr[kk] = *(const bf16x8*)(const void*)&w2f[(((w * 14) + kk) * 64 + l) * 8];

  // ---- stage Hs: 288 rows x 4 uint2-quads, coalesced, OOB -> 0 ----
#pragma unroll
  for (int it = 0; it < 9; ++it) {
    const int u = t + it * 128;               // 0..1151
    const int row = u >> 2, q = u & 3;
    const int ic = row / 18;
    const int r2 = row - ic * 18;
    const int izp = r2 / 6;
    const int iyp = r2 - izp * 6;
    const int iz = 2 * oz - 1 + izp;
    const int iy = 4 * yg - 1 + iyp;
    uint2 v = make_uint2(0u, 0u);
    if ((unsigned)iz < 16u && (unsigned)iy < 16u)
      v = *(const uint2*)(hb + (ic << 12) + (iz << 8) + (iy << 4) + q * 4);
    *(uint2*)&Hs[row * 20 + q * 4] = v;
  }
  __syncthreads();

  // ---- im2col gather from Hs into registers ----
  const int m = t >> 3, sub = t & 7;
  const int ox = m & 7;
  const int my = (m >> 3) * 2;                // 2*(m>>3)
  ushort_t tv[54];
  int j = 0;
#pragma unroll
  for (int ic2 = 0; ic2 < 2; ++ic2) {
    const int ic = sub * 2 + ic2;
#pragma unroll
    for (int dz = 0; dz < 3; ++dz) {
#pragma unroll
      for (int dy = 0; dy < 3; ++dy) {
        const int row = ic * 18 + dz * 6 + my + dy;
        const unsigned* rp = Hsd + row * 10;
        const unsigned d0 = (ox > 0) ? rp[ox - 1] : 0u;
        const unsigned d1 = rp[ox];
        tv[j]     = (ushort_t)(d0 >> 16);     // ix = 2ox-1
        tv[j + 1] = (ushort_t)(d1 & 0xFFFFu); // ix = 2ox
        tv[j + 2] = (ushort_t)(d1 >> 16);     // ix = 2ox+1
        j += 3;
      }
    }
  }
  __syncthreads();                            // Hs fully consumed

  // ---- write As (overwrites Hs region) + K-pad zeros ----
  {
    unsigned* Aw = (unsigned*)As;
    const int wbase = m * 228 + sub * 27;
#pragma unroll
    for (int p = 0; p < 27; ++p)
      Aw[wbase + p] = (unsigned)tv[2 * p] | ((unsigned)tv[2 * p + 1] << 16);
    Aw[(t >> 3) * 228 + 216 + (t & 7)] = 0u;  // k in [432,448)
  }
  __syncthreads();

  // ---- MFMA + store ----
  f32x4 acc = {0.f, 0.f, 0.f, 0.f};
  const ushort_t* arow = &As[(l & 15) * 456 + ((l >> 4) << 3)];
#pragma unroll
  for (int kk = 0; kk < 14; ++kk) {
    const bf16x8 af = *(const bf16x8*)(const void*)&arow[kk * 32];
    acc = __builtin_amdgcn_mfma_f32_16x16x32_bf16(af, bfr[kk], acc, 0, 0, 0);
  }
  const int n = w * 16 + (l & 15);
  const int m0 = (l >> 4) << 2;
  float* cb = c2 + (((size_t)(bn * 32 + n) * 8) + oz) * 64 + yg * 16 + m0;
  *(float4*)cb = make_float4(acc[0], acc[1], acc[2], acc[3]);
}

// ---------------- K2b: maxpool3 s2 p1 + bias + relu -> feat (bf16) ---------
__global__ __launch_bounds__(256) void k_pool2(
    const float* __restrict__ c2, const float* __restrict__ bc2,
    ushort_t* __restrict__ featb)
{
  const int tid = blockIdx.x * 256 + threadIdx.x;  // 131072
  const int bn = tid >> 9, r = tid & 511;
  const int ch = r >> 4, pz = (r >> 2) & 3, py = r & 3;
  const float* base = c2 + ((size_t)(bn * 32 + ch) << 9);
  float m0 = -1e30f, m1 = -1e30f, m2 = -1e30f, m3 = -1e30f;
#pragma unroll
  for (int dz = 0; dz < 3; ++dz) {
    const int oz = 2 * pz - 1 + dz;
    if ((unsigned)oz >= 8u) continue;
#pragma unroll
    for (int dy = 0; dy < 3; ++dy) {
      const int oy = 2 * py - 1 + dy;
      if ((unsigned)oy >= 8u) continue;
      const float* row = base + (oz << 6) + (oy << 3);
      const float4 a = ((const float4*)row)[0];
      const float4 b = ((const float4*)row)[1];
      m0 = fmaxf(m0, fmaxf(a.x, a.y));
      m1 = fmaxf(m1, fmaxf(a.y, fmaxf(a.z, a.w)));
      m2 = fmaxf(m2, fmaxf(a.w, fmaxf(b.x, b.y)));
      m3 = fmaxf(m3, fmaxf(b.y, fmaxf(b.z, b.w)));
    }
  }
  const float bb = bc2[ch];
  const unsigned lo = (unsigned)f2bf(fmaxf(m0 + bb, 0.f)) |
                      ((unsigned)f2bf(fmaxf(m1 + bb, 0.f)) << 16);
  const unsigned hi = (unsigned)f2bf(fmaxf(m2 + bb, 0.f)) |
                      ((unsigned)f2bf(fmaxf(m3 + bb, 0.f)) << 16);
  *(uint2*)(featb + (size_t)bn * 2048 + r * 4) = make_uint2(lo, hi);
}

// ---------------- fused GCN layer: out = [relu](A_norm @ (X W) + b) --------
// Double-buffered LDS + register prefetch; one barrier per K-iteration.
__global__ __launch_bounds__(256) void k_gcn_layer(
    const ushort_t* __restrict__ Xb, const ushort_t* __restrict__ WT,
    const float* __restrict__ bias, const float* __restrict__ An,
    ushort_t* __restrict__ Ob, float* __restrict__ Of, int K, int N, int relu)
{
  __shared__ ushort_t As[2][64 * 72];
  __shared__ ushort_t Bs[2][64 * 72];
  __shared__ ushort_t Ps[64 * 72];   // P transposed: Ps[n][node]
  const int b = blockIdx.y, jb = blockIdx.x << 6;
  const int t = threadIdx.x, w = t >> 6, l = t & 63;
  const int r0 = t >> 3, kc0 = t & 7;
  const int lm = l & 15, lg = l >> 4;

  union { short s[8]; bf16x8 v; } afr[2];
  {
    const float* ap = An + b * 4096 + (16 * w + lm) * 64 + (lg << 3);
#pragma unroll
    for (int kc = 0; kc < 2; ++kc) {
      const float4 v0 = *(const float4*)(ap + kc * 32);
      const float4 v1 = *(const float4*)(ap + kc * 32 + 4);
      afr[kc].s[0] = (short)f2bf(v0.x); afr[kc].s[1] = (short)f2bf(v0.y);
      afr[kc].s[2] = (short)f2bf(v0.z); afr[kc].s[3] = (short)f2bf(v0.w);
      afr[kc].s[4] = (short)f2bf(v1.x); afr[kc].s[5] = (short)f2bf(v1.y);
      afr[kc].s[6] = (short)f2bf(v1.z); afr[kc].s[7] = (short)f2bf(v1.w);
    }
  }

  f32x4 acc[4];
#pragma unroll
  for (int nt = 0; nt < 4; ++nt) acc[nt] = (f32x4){0.f, 0.f, 0.f, 0.f};

  const ushort_t* arow0 = &Xb[(size_t)(b * 64 + r0) * K + kc0 * 8];
  const ushort_t* arow1 = &Xb[(size_t)(b * 64 + r0 + 32) * K + kc0 * 8];
  const ushort_t* brow0 = &WT[(size_t)(jb + r0) * K + kc0 * 8];
  const ushort_t* brow1 = &WT[(size_t)(jb + r0 + 32) * K + kc0 * 8];

  uint4 va0 = *(const uint4*)arow0;
  uint4 va1 = *(const uint4*)arow1;
  uint4 vb0 = *(const uint4*)brow0;
  uint4 vb1 = *(const uint4*)brow1;

  int buf = 0;
#pragma unroll 1
  for (int kt = 0; kt < K; kt += 64) {
    *(uint4*)&As[buf][r0 * 72 + kc0 * 8]        = va0;
    *(uint4*)&As[buf][(r0 + 32) * 72 + kc0 * 8] = va1;
    *(uint4*)&Bs[buf][r0 * 72 + kc0 * 8]        = vb0;
    *(uint4*)&Bs[buf][(r0 + 32) * 72 + kc0 * 8] = vb1;
    __syncthreads();
    if (kt + 64 < K) {
      va0 = *(const uint4*)(arow0 + kt + 64);
      va1 = *(const uint4*)(arow1 + kt + 64);
      vb0 = *(const uint4*)(brow0 + kt + 64);
      vb1 = *(const uint4*)(brow1 + kt + 64);
    }
#pragma unroll
    for (int ks = 0; ks < 2; ++ks) {
      const bf16x8 af = *(const bf16x8*)(const void*)
          &As[buf][(16 * w + lm) * 72 + ks * 32 + (lg << 3)];
#pragma unroll
      for (int nt = 0; nt < 4; ++nt) {
        const bf16x8 bf = *(const bf16x8*)(const void*)
            &Bs[buf][(nt * 16 + lm) * 72 + ks * 32 + (lg << 3)];
        acc[nt] = __builtin_amdgcn_mfma_f32_16x16x32_bf16(af, bf, acc[nt], 0, 0, 0);
      }
    }
    buf ^= 1;
  }

  __syncthreads();
  const int m0 = lg << 2;
#pragma unroll
  for (int nt = 0; nt < 4; ++nt) {
    const int n = nt * 16 + lm;
    const unsigned lo = (unsigned)f2bf(acc[nt][0]) | ((unsigned)f2bf(acc[nt][1]) << 16);
    const unsigned hi = (unsigned)f2bf(acc[nt][2]) | ((unsigned)f2bf(acc[nt][3]) << 16);
    *(uint2*)&Ps[n * 72 + 16 * w + m0] = make_uint2(lo, hi);
  }
  __syncthreads();

#pragma unroll
  for (int nt = 0; nt < 4; ++nt) {
    const bf16x8 b0 = *(const bf16x8*)(const void*)&Ps[(nt * 16 + lm) * 72 + (lg << 3)];
    const bf16x8 b1 = *(const bf16x8*)(const void*)&Ps[(nt * 16 + lm) * 72 + 32 + (lg << 3)];
    f32x4 a2 = (f32x4){0.f, 0.f, 0.f, 0.f};
    a2 = __builtin_amdgcn_mfma_f32_16x16x32_bf16(afr[0].v, b0, a2, 0, 0, 0);
    a2 = __builtin_amdgcn_mfma_f32_16x16x32_bf16(afr[1].v, b1, a2, 0, 0, 0);
    const int col = jb + nt * 16 + lm;
    const float bv = bias[col];
#pragma unroll
    for (int r = 0; r < 4; ++r) {
      const int row = b * 64 + 16 * w + m0 + r;
      float v = a2[r] + bv;
      if (relu) v = fmaxf(v, 0.f);
      if (Ob) Ob[(size_t)row * N + col] = f2bf(v);
      else    Of[(size_t)row * N + col] = v;
    }
  }
}

// ---------------- head: chunk-max + fc1 + relu + fc2 + softmax -------------
__global__ __launch_bounds__(256) void k_head(
    const float* __restrict__ g3, const float* __restrict__ w1, const float* __restrict__ b1,
    const float* __restrict__ w2, const float* __restrict__ b2, float* __restrict__ out)
{
  const int b = blockIdx.x, t = threadIdx.x;
  __shared__ float sp[256];
  __shared__ float sh[512];
  __shared__ float sl[4];
  {
    const int n = t >> 2, c = t & 3;
    const float* gr = g3 + (size_t)(b * 64 + n) * 256 + c * 64;
    float mx = -1e30f;
    for (int f = 0; f < 64; ++f) mx = fmaxf(mx, gr[f]);
    sp[t] = mx;
  }
  __syncthreads();
  for (int jj = t; jj < 512; jj += 256) {
    float s = b1[jj];
    for (int k = 0; k < 256; ++k) s += sp[k] * w1[k * 512 + jj];
    sh[jj] = fmaxf(s, 0.f);
  }
  __syncthreads();
  if (t < 4) {
    float s = b2[t];
    for (int k = 0; k < 512; ++k) s += sh[k] * w2[k * 4 + t];
    sl[t] = s;
  }
  __syncthreads();
  if (t == 0) {
    const float mm = fmaxf(fmaxf(sl[0], sl[1]), fmaxf(sl[2], sl[3]));
    const float e0 = expf(sl[0] - mm), e1 = expf(sl[1] - mm);
    const float e2 = expf(sl[2] - mm), e3 = expf(sl[3] - mm);
    const float inv = 1.f / (e0 + e1 + e2 + e3);
    out[b * 4 + 0] = e0 * inv;
    out[b * 4 + 1] = e1 * inv;
    out[b * 4 + 2] = e2 * inv;
    out[b * 4 + 3] = e3 * inv;
  }
}

// ---------------------------------------------------------------------------
extern "C" void kernel_launch(void* const* d_in, const int* in_sizes, int n_in,
                              void* d_out, int out_size, void* d_ws, size_t ws_size,
                              hipStream_t stream)
{
  (void)in_sizes; (void)n_in; (void)out_size; (void)ws_size;
  const float* x   = (const float*)d_in[0];
  const int*   adj = (const int*)d_in[1];
  const float* wc1 = (const float*)d_in[3];
  const float* bc1 = (const float*)d_in[4];
  const float* wc2 = (const float*)d_in[5];
  const float* bc2 = (const float*)d_in[6];
  const float* wg1 = (const float*)d_in[7];
  const float* bg1 = (const float*)d_in[8];
  const float* wg2 = (const float*)d_in[9];
  const float* bg2 = (const float*)d_in[10];
  const float* wg3 = (const float*)d_in[11];
  const float* bg3 = (const float*)d_in[12];
  const float* wf1 = (const float*)d_in[13];
  const float* bf1 = (const float*)d_in[14];
  const float* wf2 = (const float*)d_in[15];
  const float* bf2 = (const float*)d_in[16];

  float* ws    = (float*)d_ws;
  ushort_t* h1 = (ushort_t*)d_ws;
  ushort_t* w2f   = (ushort_t*)(ws + 8388608);
  ushort_t* wg1Tb = (ushort_t*)(ws + 8395776);
  ushort_t* wg2Tb = (ushort_t*)(ws + 9444352);
  ushort_t* wg3Tb = (ushort_t*)(ws + 9706496);
  ushort_t* featb = (ushort_t*)(ws + 9772032);
  ushort_t* g1b   = (ushort_t*)(ws + 10034176);
  ushort_t* g2b   = (ushort_t*)(ws + 10165248);
  float* c2    = ws + 16777216;
  ushort_t* xb16 = (ushort_t*)(ws + 16777216);   // aliases c2 (consumed pre-conv2)
  float* An   = ws + 21495808;
  float* g3   = ws + 22364160;
  float* outp = (float*)d_out;

  hipLaunchKernelGGL(k_prep,        dim3(10940),    dim3(256), 0, stream,
                     x, xb16, wc2, w2f, wg1, wg1Tb, wg2, wg2Tb, wg3, wg3Tb, adj, An);
  hipLaunchKernelGGL(k_conv1_mfma,  dim3(2048),     dim3(256), 0, stream, xb16, wc1, bc1, h1);
  hipLaunchKernelGGL(k_conv2,       dim3(8192),     dim3(128), 0, stream, h1, w2f, c2);
  hipLaunchKernelGGL(k_pool2,       dim3(512),      dim3(256), 0, stream, c2, bc2, featb);
  hipLaunchKernelGGL(k_gcn_layer,   dim3(16,4),     dim3(256), 0, stream,
                     featb, wg1Tb, bg1, An, g1b, (float*)nullptr, 2048, 1024, 1);
  hipLaunchKernelGGL(k_gcn_layer,   dim3(8,4),      dim3(256), 0, stream,
                     g1b, wg2Tb, bg2, An, g2b, (float*)nullptr, 1024, 512, 1);
  hipLaunchKernelGGL(k_gcn_layer,   dim3(4,4),      dim3(256), 0, stream,
                     g2b, wg3Tb, bg3, An, (ushort_t*)nullptr, g3, 512, 256, 0);
  hipLaunchKernelGGL(k_head,        dim3(4),        dim3(256), 0, stream, g3, wf1, bf1, wf2, bf2, outp);
}